// Round 8
// baseline (361.096 us; speedup 1.0000x reference)
//
#include <hip/hip_runtime.h>

typedef __attribute__((ext_vector_type(8))) short bh8;
typedef __attribute__((ext_vector_type(4))) float f4;

#define DEVI static __device__ __forceinline__

DEVI unsigned short f2b(float f) {
  union { float f; unsigned u; } v; v.f = f;
  unsigned r = v.u + 0x7fffu + ((v.u >> 16) & 1u);
  return (unsigned short)(r >> 16);
}
DEVI float b2f(unsigned short h) {
  union { unsigned u; float f; } v; v.u = ((unsigned)h) << 16;
  return v.f;
}
DEVI f4 mfma16(bh8 a, bh8 b, f4 c) {
  return __builtin_amdgcn_mfma_f32_16x16x32_bf16(a, b, c, 0, 0, 0);
}
DEVI void gload_lds16(const unsigned short* g, unsigned short* l) {
  __builtin_amdgcn_global_load_lds(
      (const __attribute__((address_space(1))) void*)(g),
      (__attribute__((address_space(3))) void*)(l), 16, 0, 0);
}

// ============================ prep kernels ============================
__global__ __launch_bounds__(256) void prep_x_kern(
    const float* __restrict__ q, const float* __restrict__ k, const float* __restrict__ v,
    unsigned short* __restrict__ xq, unsigned short* __restrict__ xk, unsigned short* __restrict__ xv) {
  long i = ((long)blockIdx.x * 256 + threadIdx.x) * 4;
  if (i >= 8388608L) return;
  float4 a = *(const float4*)(q + i);
  float4 b = *(const float4*)(k + i);
  float4 c = *(const float4*)(v + i);
  union { unsigned short s[4]; uint2 u; } pa, pb, pc;
  pa.s[0] = f2b(a.x); pa.s[1] = f2b(a.y); pa.s[2] = f2b(a.z); pa.s[3] = f2b(a.w);
  pb.s[0] = f2b(b.x); pb.s[1] = f2b(b.y); pb.s[2] = f2b(b.z); pb.s[3] = f2b(b.w);
  pc.s[0] = f2b(c.x); pc.s[1] = f2b(c.y); pc.s[2] = f2b(c.z); pc.s[3] = f2b(c.w);
  *(uint2*)(xq + i) = pa.u;
  *(uint2*)(xk + i) = pb.u;
  *(uint2*)(xv + i) = pc.u;
}

// weight repack:
// [0,512K)      Wq  = [wq | g_in_w rows 0-511]
// [512K,1024K)  Wk  = [wk | g_in_w rows 512-1023]
// [1024K,1536K) Wv  = [wv | g_in_w rows 1024-1535]
// [1536K,1792K) Wo_ = wo (bf16, plain, A of W2-GEMM)
// [1792K,2048K) Bfin[col][k<512] = 0.7*wo[col][k]  (row stride 1024)
// [2048K,2304K) WgoT[i*512+p] = g_out_w[p*512+i]   (scalar scatter)
// [2304K,...)   Rk = rel_k
__global__ __launch_bounds__(256) void prep_w_kern(
    const float* __restrict__ wq, const float* __restrict__ wk, const float* __restrict__ wv,
    const float* __restrict__ g_in_w, const float* __restrict__ g_out_w,
    const float* __restrict__ wo, const float* __restrict__ rel_k,
    unsigned short* __restrict__ Wq, unsigned short* __restrict__ Wk, unsigned short* __restrict__ Wv,
    unsigned short* __restrict__ Wo_, unsigned short* __restrict__ WgoT,
    unsigned short* __restrict__ Bfin, unsigned short* __restrict__ Rk) {
  long i = ((long)blockIdx.x * 256 + threadIdx.x) * 4;
  if (i >= 2392128L) return;
  if (i >= 2097152L && i < 2359296L) {  // WgoT scatter
    long off = i - 2097152L;
    int ii = (int)(off >> 9), p = (int)(off & 511);
    union { unsigned short s[4]; uint2 u; } w;
#pragma unroll
    for (int tt = 0; tt < 4; tt++) w.s[tt] = f2b(g_out_w[(p + tt) * 512 + ii]);
    *(uint2*)(WgoT + off) = w.u;
    return;
  }
  const float* src; unsigned short* dst; long off; float sc = 1.0f;
  if (i < 524288L)        { dst = Wq;  off = i; src = (i < 262144L) ? wq + i : g_in_w + (i - 262144L); }
  else if (i < 1048576L)  { long j = i - 524288L;  dst = Wk;  off = j; src = (j < 262144L) ? wk + j : g_in_w + j; }
  else if (i < 1572864L)  { long j = i - 1048576L; dst = Wv;  off = j; src = (j < 262144L) ? wv + j : g_in_w + 262144L + j; }
  else if (i < 1835008L)  { long j = i - 1572864L; dst = Wo_; off = j; src = wo + j; }
  else if (i < 2097152L)  { long j = i - 1835008L; int col = (int)(j >> 9), k = (int)(j & 511);
                            dst = Bfin; off = (long)col * 1024 + k; src = wo + j; sc = 0.7f; }
  else                    { long j = i - 2359296L; dst = Rk;  off = j; src = rel_k + j; }
  float4 f = *(const float4*)src;
  union { unsigned short s[4]; uint2 u; } p;
  p.s[0] = f2b(f.x * sc); p.s[1] = f2b(f.y * sc); p.s[2] = f2b(f.z * sc); p.s[3] = f2b(f.w * sc);
  *(uint2*)(dst + off) = p.u;
}

// bias2 = bo + 0.3 * (Wo @ bgo)
__global__ __launch_bounds__(256) void bias2_kern(
    const float* __restrict__ wo, const float* __restrict__ bgo,
    const float* __restrict__ bo, float* __restrict__ bias2) {
  int o = blockIdx.x * 256 + threadIdx.x;
  if (o >= 512) return;
  const float* r = wo + (long)o * 512;
  float s = 0.f;
#pragma unroll 4
  for (int m = 0; m < 512; m += 4) {
    float4 a = *(const float4*)(r + m);
    float4 b = *(const float4*)(bgo + m);
    s += a.x * b.x + a.y * b.y + a.z * b.z + a.w * b.w;
  }
  bias2[o] = bo[o] + 0.3f * s;
}

// ============================ GEMM ============================
// C[row,col] = sum_k A[row,k]*Bw[col,k]; A stride LDA, Bw stride KD, K=KD.
// GRIDM>0: plain grid mapping (rb = n%GRIDM). EPI:
//  0: +bias -> outb [M][NB*128] bf16
//  3: +bias -> V transposed-per-head (uint2-packed stores)
//  2: +bias0 -> outf [M][512] f32
//  5: 0.3*v -> Bfin[row*1024 + 512 + col] bf16  (W2 product)
template <int NB, int EPI, int KD, int LDA, int GRIDM>
__global__ __launch_bounds__(256) void gemm_bf16_kern(
    const unsigned short* __restrict__ A, const unsigned short* __restrict__ Bw,
    const float* __restrict__ bias0, const float* __restrict__ bias1,
    unsigned short* __restrict__ outb, unsigned short* __restrict__ outb2,
    float* __restrict__ outf) {
  __shared__ unsigned short lsA[128 * 32];
  __shared__ unsigned short lsB[128 * 32];
  const int t = threadIdx.x;
  const int lane = t & 63, w = t >> 6;
  const int l15 = lane & 15, g8 = (lane >> 4) * 8, g4 = (lane >> 4) * 4;
  int n = blockIdx.x;
  int rb, cb;
  if constexpr (GRIDM > 0) {
    rb = (n % GRIDM) * 128; cb = (n / GRIDM) * 128;
  } else {
    int x = n >> 3, c = n & 7;
    rb = (c * 16 + (x & 15)) * 128;
    cb = (x >> 4) * 128;
  }
  const int wr = (w >> 1) * 64, wc = (w & 1) * 64;
  const int e0 = t * 8, e1 = 2048 + t * 8;
  const int r0 = e0 >> 5, k0i = e0 & 31;
  const int r1 = e1 >> 5, k1i = e1 & 31;

  const unsigned short* pa0 = A + (long)(rb + r0) * LDA + k0i;
  const unsigned short* pa1 = A + (long)(rb + r1) * LDA + k1i;
  const unsigned short* pb0 = Bw + (long)(cb + r0) * KD + k0i;
  const unsigned short* pb1 = Bw + (long)(cb + r1) * KD + k1i;
  unsigned short* dA0 = lsA + w * 512;
  unsigned short* dA1 = lsA + 2048 + w * 512;
  unsigned short* dB0 = lsB + w * 512;
  unsigned short* dB1 = lsB + 2048 + w * 512;

  f4 acc[4][4] = {};
  for (int k0 = 0; k0 < KD; k0 += 32) {
    __syncthreads();
    gload_lds16(pa0 + k0, dA0);
    gload_lds16(pa1 + k0, dA1);
    gload_lds16(pb0 + k0, dB0);
    gload_lds16(pb1 + k0, dB1);
    __syncthreads();
    bh8 af[4], bf[4];
#pragma unroll
    for (int m = 0; m < 4; m++) af[m] = *(const bh8*)(lsA + (wr + m * 16 + l15) * 32 + g8);
#pragma unroll
    for (int nn = 0; nn < 4; nn++) bf[nn] = *(const bh8*)(lsB + (wc + nn * 16 + l15) * 32 + g8);
#pragma unroll
    for (int m = 0; m < 4; m++)
#pragma unroll
      for (int nn = 0; nn < 4; nn++)
        acc[m][nn] = mfma16(af[m], bf[nn], acc[m][nn]);
  }
#pragma unroll
  for (int m = 0; m < 4; m++) {
#pragma unroll
    for (int nn = 0; nn < 4; nn++) {
      if constexpr (EPI == 3) {
        int col = cb + wc + nn * 16 + l15;
        float bsv = (col < 512) ? bias0[col] : bias1[col - 512];
        unsigned r[4];
#pragma unroll
        for (int j = 0; j < 4; j++) {
          union { float f; unsigned u; } v; v.f = acc[m][nn][j] + bsv;
          r[j] = v.u + 0x7fffu + ((v.u >> 16) & 1u);
        }
        unsigned lo = (r[0] >> 16) | (r[1] & 0xffff0000u);
        unsigned hi = (r[2] >> 16) | (r[3] & 0xffff0000u);
        int row0 = rb + wr + m * 16 + g4;
        int bb = row0 >> 9, s = row0 & 511;
        if (col < 512) {
          int hh = col >> 6, d = col & 63;
          *(uint2*)(outb + (((long)(bb * 8 + hh) * 64 + d) << 9) + s) = make_uint2(lo, hi);
        } else {
          int c2 = col - 512, hg = c2 >> 7, dg = c2 & 127;
          *(uint2*)(outb2 + (((long)(bb * 4 + hg) * 128 + dg) << 9) + s) = make_uint2(lo, hi);
        }
      } else {
#pragma unroll
        for (int j = 0; j < 4; j++) {
          int row = rb + wr + m * 16 + g4 + j;
          int col = cb + wc + nn * 16 + l15;
          float v = acc[m][nn][j];
          if constexpr (EPI == 0) {
            v += (col < 512) ? bias0[col] : bias1[col - 512];
            outb[(long)row * (NB * 128) + col] = f2b(v);
          } else if constexpr (EPI == 5) {
            outb[(long)row * 1024 + 512 + col] = f2b(0.3f * v);
          } else {
            v += bias0[col];
            outf[(long)row * 512 + col] = v;
          }
        }
      }
    }
  }
}

// ============================ local attention v6 (R7, proven) ============================
// Output now goes to CAT [16384][1024], cols 0-511.
__global__ __launch_bounds__(512, 4) void attn_local_kern(
    const unsigned short* __restrict__ Yq, const unsigned short* __restrict__ Yk,
    const unsigned short* __restrict__ Yvt, const unsigned short* __restrict__ relk,
    unsigned short* __restrict__ outC) {
  __shared__ unsigned short kv[2][8192];
  __shared__ unsigned short buf[32 * 524];
  __shared__ float redbuf[8][32];

  const int t = threadIdx.x, lane = t & 63, w = t >> 6;
  const int l15 = lane & 15, g = lane >> 4, g8 = g * 8;
  int n = blockIdx.x;
  int bid = (n & 7) * 512 + (n >> 3);
  const int qt = bid & 15;
  const int h = (bid >> 4) & 7;
  const int b = bid >> 7;
  const int qb = qt * 32;
  const long base = ((long)(b * 512)) * 1024 + h * 64;
  const long vbase = ((long)(b * 8 + h)) * 64 * 512;

#define STAGE_K(ROFF, BUF) { \
    const int c_ = t & 7; \
    _Pragma("unroll") \
    for (int it = 0; it < 2; it++) { \
      int rr = it * 64 + (t >> 3); \
      gload_lds16(Yk + base + (long)((ROFF) + rr) * 1024 + ((c_ ^ (rr & 7)) * 8), \
                  kv[BUF] + it * 4096 + w * 512); \
    } }
#define STAGE_V(COFF, BUF) { \
    const int c_ = t & 15; \
    _Pragma("unroll") \
    for (int it = 0; it < 2; it++) { \
      int dd_ = it * 32 + (t >> 4); \
      gload_lds16(Yvt + vbase + (long)dd_ * 512 + (COFF) + ((c_ ^ (dd_ & 15)) * 8), \
                  kv[BUF] + it * 4096 + w * 512); \
    } }
#define QK(CH) { \
    int rl = w * 16 + l15; \
    const unsigned short* kb_ = kv[(CH) & 1]; \
    bh8 k0 = *(const bh8*)(kb_ + rl * 64 + ((g ^ (rl & 7)) * 8)); \
    bh8 k1 = *(const bh8*)(kb_ + rl * 64 + (((g + 4) ^ (rl & 7)) * 8)); \
    _Pragma("unroll") \
    for (int mm = 0; mm < 2; mm++) { \
      f4 a = {}; \
      a = mfma16(qf[mm][0], k0, a); \
      a = mfma16(qf[mm][1], k1, a); \
      sc[mm][CH] = a; \
    } }
#define GATHER(CH) { \
    _Pragma("unroll") \
    for (int mm = 0; mm < 2; mm++) \
    _Pragma("unroll") \
    for (int j = 0; j < 4; j++) { \
      int lr = mm * 16 + g * 4 + j; \
      int rowb = lr * 524; \
      int idx = rowb + 256 - (qb + lr) + (CH) * 128 + w * 16 + l15; \
      idx = idx < rowb ? rowb : idx; \
      idx = idx > rowb + 512 ? rowb + 512 : idx; \
      float p = exp2f(fmaf(sc[mm][CH][j], 0.18033688011112042f, b2f(buf[idx]))); \
      sc[mm][CH][j] = p; \
      rs[mm][j] += p; \
    } }

  STAGE_K(0, 0);

  bh8 qf[2][2];
#pragma unroll
  for (int mm = 0; mm < 2; mm++) {
    const unsigned short* qp = Yq + base + (long)(qb + mm * 16 + l15) * 1024 + g8;
    qf[mm][0] = *(const bh8*)(qp);
    qf[mm][1] = *(const bh8*)(qp + 32);
  }

  for (int tt = w; tt < 33; tt += 8) {
    int ri = tt * 16 + l15; if (ri > 512) ri = 512;
    const unsigned short* rp = relk + ri * 64 + g8;
    bh8 rf0 = *(const bh8*)(rp), rf1 = *(const bh8*)(rp + 32);
    int col = tt * 16 + l15;
#pragma unroll
    for (int mm = 0; mm < 2; mm++) {
      f4 a = {};
      a = mfma16(qf[mm][0], rf0, a);
      a = mfma16(qf[mm][1], rf1, a);
      if (col < 524) {
#pragma unroll
        for (int j = 0; j < 4; j++)
          buf[(mm * 16 + g * 4 + j) * 524 + col] = f2b(a[j] * 1.4426950408889634f);
      }
    }
  }
  __syncthreads();

  f4 sc[2][4];
  float rs[2][4] = {};

#pragma unroll
  for (int c = 0; c < 4; c++) {
    if (c < 3) { STAGE_K((c + 1) * 128, (c + 1) & 1); }
    else       { STAGE_V(0, 0); }
    __builtin_amdgcn_s_setprio(1);
    QK(c);
    __builtin_amdgcn_s_setprio(0);
    GATHER(c);
    __syncthreads();
  }

#pragma unroll
  for (int mm = 0; mm < 2; mm++)
#pragma unroll
    for (int j = 0; j < 4; j++) {
      int lr = mm * 16 + g * 4 + j;
      float s = rs[mm][j];
      for (int d = 1; d < 16; d <<= 1) s += __shfl_xor(s, d, 64);
      if (l15 == 0) redbuf[w][lr] = s;
    }
#pragma unroll
  for (int mm = 0; mm < 2; mm++)
#pragma unroll
    for (int ch = 0; ch < 4; ch++) {
      int col = ch * 128 + w * 16 + l15;
#pragma unroll
      for (int j = 0; j < 4; j++)
        buf[(mm * 16 + g * 4 + j) * 524 + col] = f2b(sc[mm][ch][j]);
    }
  __syncthreads();

  const int mmw = w >> 2, dt = w & 3;
  const int dd = dt * 16 + l15;
  float rinvj[4];
#pragma unroll
  for (int j = 0; j < 4; j++) {
    int lr = mmw * 16 + g * 4 + j;
    float s = 0.f;
#pragma unroll
    for (int ww = 0; ww < 8; ww++) s += redbuf[ww][lr];
    rinvj[j] = __builtin_amdgcn_rcpf(s);
  }

  f4 accO = {};
#pragma unroll
  for (int d = 0; d < 4; d++) {
    if (d < 3) { STAGE_V((d + 1) * 128, (d + 1) & 1); }
    const unsigned short* vb_ = kv[d & 1];
    __builtin_amdgcn_s_setprio(1);
#pragma unroll
    for (int ks2 = 0; ks2 < 4; ks2++) {
      union { uint2 u[2]; bh8 v; } pa;
      const unsigned short* pp = buf + (mmw * 16 + l15) * 524 + (d * 4 + ks2) * 32 + g8;
      pa.u[0] = *(const uint2*)(pp);
      pa.u[1] = *(const uint2*)(pp + 4);
      bh8 vv = *(const bh8*)(vb_ + dd * 128 + (((ks2 * 4 + g) ^ (dd & 15)) * 8));
      accO = mfma16(pa.v, vv, accO);
    }
    __builtin_amdgcn_s_setprio(0);
    if (d < 3) __syncthreads();
  }
#pragma unroll
  for (int j = 0; j < 4; j++) {
    int row = qb + mmw * 16 + g * 4 + j;
    outC[((long)(b * 512 + row)) * 1024 + h * 64 + dt * 16 + l15] = f2b(accO[j] * rinvj[j]);
  }
#undef STAGE_K
#undef STAGE_V
#undef QK
#undef GATHER
}

// ============================ global attention v2 (R7, proven) ============================
// Output -> CAT cols 512-1023.
__global__ __launch_bounds__(512) void attn_glob_kern(
    const unsigned short* __restrict__ Yq, const unsigned short* __restrict__ Yk,
    const unsigned short* __restrict__ Yvt, unsigned short* __restrict__ outC) {
  __shared__ unsigned short buf[32 * 520];
  __shared__ float redbuf[8][32];

  const int t = threadIdx.x, lane = t & 63, w = t >> 6;
  const int l15 = lane & 15, g = lane >> 4, g8 = g * 8;
  int n = blockIdx.x;
  int bid = (n & 7) * 256 + (n >> 3);
  const int qt = bid & 15;
  const int hg = (bid >> 4) & 3;
  const int b = bid >> 6;
  const int qb = qt * 32;
  const long base = ((long)(b * 512)) * 1024 + 512 + hg * 128;

  bh8 qf[2][4];
#pragma unroll
  for (int mm = 0; mm < 2; mm++) {
    const unsigned short* qp = Yq + base + (long)(qb + mm * 16 + l15) * 1024 + g8;
#pragma unroll
    for (int ks = 0; ks < 4; ks++) qf[mm][ks] = *(const bh8*)(qp + ks * 32);
  }

  f4 sc[2][4];
  __builtin_amdgcn_s_setprio(1);
#pragma unroll
  for (int ct = 0; ct < 4; ct++) {
    int r = w * 64 + ct * 16 + l15;
    const unsigned short* kp = Yk + base + (long)r * 1024 + g8;
    bh8 kf[4];
#pragma unroll
    for (int ks = 0; ks < 4; ks++) kf[ks] = *(const bh8*)(kp + ks * 32);
#pragma unroll
    for (int mm = 0; mm < 2; mm++) {
      f4 a = {};
#pragma unroll
      for (int ks = 0; ks < 4; ks++) a = mfma16(qf[mm][ks], kf[ks], a);
      sc[mm][ct] = a;
    }
  }
  __builtin_amdgcn_s_setprio(0);

#pragma unroll
  for (int mm = 0; mm < 2; mm++) {
#pragma unroll
    for (int j = 0; j < 4; j++) {
      int lr = mm * 16 + g * 4 + j;
      float s = 0.f;
#pragma unroll
      for (int ct = 0; ct < 4; ct++) {
        float p = exp2f(sc[mm][ct][j] * 0.12751745334f);
        sc[mm][ct][j] = p;
        s += p;
      }
      for (int d = 1; d < 16; d <<= 1) s += __shfl_xor(s, d, 64);
      if (l15 == 0) redbuf[w][lr] = s;
    }
  }
#pragma unroll
  for (int mm = 0; mm < 2; mm++)
#pragma unroll
    for (int ct = 0; ct < 4; ct++) {
      int col = w * 64 + ct * 16 + l15;
#pragma unroll
      for (int j = 0; j < 4; j++)
        buf[(mm * 16 + g * 4 + j) * 520 + col] = f2b(sc[mm][ct][j]);
    }
  __syncthreads();

  float rinv[2][4];
#pragma unroll
  for (int mm = 0; mm < 2; mm++)
#pragma unroll
    for (int j = 0; j < 4; j++) {
      int lr = mm * 16 + g * 4 + j;
      float s = 0.f;
#pragma unroll
      for (int ww = 0; ww < 8; ww++) s += redbuf[ww][lr];
      rinv[mm][j] = __builtin_amdgcn_rcpf(s);
    }

  f4 accO[2] = {};
  const unsigned short* vr = Yvt + ((long)(b * 4 + hg) * 128 + w * 16 + l15) * 512;
  __builtin_amdgcn_s_setprio(1);
#pragma unroll
  for (int ks = 0; ks < 16; ks++) {
    bh8 vb = *(const bh8*)(vr + ks * 32 + g8);
#pragma unroll
    for (int mm = 0; mm < 2; mm++) {
      union { uint2 u[2]; bh8 v; } pa;
      const unsigned short* pp = buf + (mm * 16 + l15) * 520 + ks * 32 + g8;
      pa.u[0] = *(const uint2*)(pp);
      pa.u[1] = *(const uint2*)(pp + 4);
      accO[mm] = mfma16(pa.v, vb, accO[mm]);
    }
  }
  __builtin_amdgcn_s_setprio(0);
#pragma unroll
  for (int mm = 0; mm < 2; mm++)
#pragma unroll
    for (int j = 0; j < 4; j++) {
      int row = qb + mm * 16 + g * 4 + j;
      outC[((long)(b * 512 + row)) * 1024 + 512 + hg * 128 + w * 16 + l15] = f2b(accO[mm][j] * rinv[mm][j]);
    }
}

// ============================ launch ============================
extern "C" void kernel_launch(void* const* d_in, const int* in_sizes, int n_in,
                              void* d_out, int out_size, void* d_ws, size_t ws_size,
                              hipStream_t stream) {
  const float* query = (const float*)d_in[0];
  const float* key   = (const float*)d_in[1];
  const float* value = (const float*)d_in[2];
  const float* wq = (const float*)d_in[3];   const float* bq = (const float*)d_in[4];
  const float* wk = (const float*)d_in[5];   const float* bk = (const float*)d_in[6];
  const float* wv = (const float*)d_in[7];   const float* bv = (const float*)d_in[8];
  const float* wo = (const float*)d_in[9];   const float* bo = (const float*)d_in[10];
  const float* rel_k = (const float*)d_in[11];
  const float* g_in_w = (const float*)d_in[12];  const float* g_in_b = (const float*)d_in[13];
  const float* g_out_w = (const float*)d_in[14]; const float* g_out_b = (const float*)d_in[15];

  unsigned short* p = (unsigned short*)d_ws;
  unsigned short* Xq = p;            p += 8388608;   // CAT rows (cols 0-1023) spans Xq+Xk
  unsigned short* Xk = p;            p += 8388608;
  unsigned short* Xv = p;            p += 8388608;
  unsigned short* Yq = p;            p += 16777216;  // [16384][1024]
  unsigned short* Yk = p;            p += 16777216;
  unsigned short* Yvt_l = p;         p += 8388608;   // [b][h][64][512]
  unsigned short* Yvt_g = p;         p += 8388608;   // [b][hg][128][512]
  unsigned short* Wq = p;            p += 524288;
  unsigned short* Wk = p;            p += 524288;
  unsigned short* Wv = p;            p += 524288;
  unsigned short* Wo_ = p;           p += 262144;
  unsigned short* WgoT = p;          p += 262144;
  unsigned short* Bfin = p;          p += 524288;    // [512][1024]
  unsigned short* Rk = p;            p += 32832;
  float* bias2 = (float*)p;          p += 1024;
  unsigned short* CAT = Xq;                          // [16384][1024]

  prep_x_kern<<<8192, 256, 0, stream>>>(query, key, value, Xq, Xk, Xv);
  prep_w_kern<<<2337, 256, 0, stream>>>(wq, wk, wv, g_in_w, g_out_w, wo, rel_k,
                                        Wq, Wk, Wv, Wo_, WgoT, Bfin, Rk);
  bias2_kern<<<2, 256, 0, stream>>>(wo, g_out_b, bo, bias2);

  // W2 = Wo @ Wgo -> Bfin cols 512-1023 (scaled by 0.3)
  gemm_bf16_kern<4, 5, 512, 512, 4><<<16, 256, 0, stream>>>(
      Wo_, WgoT, nullptr, nullptr, Bfin, nullptr, nullptr);

  gemm_bf16_kern<8, 0, 512, 512, 0><<<1024, 256, 0, stream>>>(Xq, Wq, bq, g_in_b, Yq, nullptr, nullptr);
  gemm_bf16_kern<8, 0, 512, 512, 0><<<1024, 256, 0, stream>>>(Xk, Wk, bk, g_in_b + 512, Yk, nullptr, nullptr);
  gemm_bf16_kern<8, 3, 512, 512, 0><<<1024, 256, 0, stream>>>(Xv, Wv, bv, g_in_b + 1024, Yvt_l, Yvt_g, nullptr);

  attn_local_kern<<<4096, 512, 0, stream>>>(Yq, Yk, Yvt_l, Rk, CAT);
  attn_glob_kern<<<2048, 512, 0, stream>>>(Yq, Yk, Yvt_g, CAT);

  // out = CAT @ Bfin^T + bias2
  gemm_bf16_kern<4, 2, 1024, 1024, 0><<<512, 256, 0, stream>>>(
      CAT, Bfin, bias2, nullptr, nullptr, nullptr, (float*)d_out);
}

// Round 9
// 356.055 us; speedup vs baseline: 1.0142x; 1.0142x over previous
//
#include <hip/hip_runtime.h>

typedef __attribute__((ext_vector_type(8))) short bh8;
typedef __attribute__((ext_vector_type(4))) float f4;

#define DEVI static __device__ __forceinline__

DEVI unsigned short f2b(float f) {
  union { float f; unsigned u; } v; v.f = f;
  unsigned r = v.u + 0x7fffu + ((v.u >> 16) & 1u);
  return (unsigned short)(r >> 16);
}
DEVI float b2f(unsigned short h) {
  union { unsigned u; float f; } v; v.u = ((unsigned)h) << 16;
  return v.f;
}
DEVI f4 mfma16(bh8 a, bh8 b, f4 c) {
  return __builtin_amdgcn_mfma_f32_16x16x32_bf16(a, b, c, 0, 0, 0);
}
DEVI void gload_lds16(const unsigned short* g, unsigned short* l) {
  __builtin_amdgcn_global_load_lds(
      (const __attribute__((address_space(1))) void*)(g),
      (__attribute__((address_space(3))) void*)(l), 16, 0, 0);
}

// ============================ prep kernels ============================
__global__ __launch_bounds__(256) void prep_x_kern(
    const float* __restrict__ q, const float* __restrict__ k, const float* __restrict__ v,
    unsigned short* __restrict__ xq, unsigned short* __restrict__ xk, unsigned short* __restrict__ xv) {
  long i = ((long)blockIdx.x * 256 + threadIdx.x) * 4;
  if (i >= 8388608L) return;
  float4 a = *(const float4*)(q + i);
  float4 b = *(const float4*)(k + i);
  float4 c = *(const float4*)(v + i);
  union { unsigned short s[4]; uint2 u; } pa, pb, pc;
  pa.s[0] = f2b(a.x); pa.s[1] = f2b(a.y); pa.s[2] = f2b(a.z); pa.s[3] = f2b(a.w);
  pb.s[0] = f2b(b.x); pb.s[1] = f2b(b.y); pb.s[2] = f2b(b.z); pb.s[3] = f2b(b.w);
  pc.s[0] = f2b(c.x); pc.s[1] = f2b(c.y); pc.s[2] = f2b(c.z); pc.s[3] = f2b(c.w);
  *(uint2*)(xq + i) = pa.u;
  *(uint2*)(xk + i) = pb.u;
  *(uint2*)(xv + i) = pc.u;
}

// weight repack (blocks < 2337) + bias2 fold (blocks 2337-2338):
// bias2 = bo + 0.3 * (Wo @ bgo)
__global__ __launch_bounds__(256) void prep_w_kern(
    const float* __restrict__ wq, const float* __restrict__ wk, const float* __restrict__ wv,
    const float* __restrict__ g_in_w, const float* __restrict__ g_out_w,
    const float* __restrict__ wo, const float* __restrict__ rel_k,
    const float* __restrict__ bgo, const float* __restrict__ bo,
    unsigned short* __restrict__ Wq, unsigned short* __restrict__ Wk, unsigned short* __restrict__ Wv,
    unsigned short* __restrict__ Wo_, unsigned short* __restrict__ WgoT,
    unsigned short* __restrict__ Bfin, unsigned short* __restrict__ Rk,
    float* __restrict__ bias2) {
  if (blockIdx.x >= 2337) {
    int o = (blockIdx.x - 2337) * 256 + threadIdx.x;
    if (o < 512) {
      const float* r = wo + (long)o * 512;
      float s = 0.f;
#pragma unroll 4
      for (int m = 0; m < 512; m += 4) {
        float4 a = *(const float4*)(r + m);
        float4 b = *(const float4*)(bgo + m);
        s += a.x * b.x + a.y * b.y + a.z * b.z + a.w * b.w;
      }
      bias2[o] = bo[o] + 0.3f * s;
    }
    return;
  }
  long i = ((long)blockIdx.x * 256 + threadIdx.x) * 4;
  if (i >= 2392128L) return;
  if (i >= 2097152L && i < 2359296L) {  // WgoT scatter
    long off = i - 2097152L;
    int ii = (int)(off >> 9), p = (int)(off & 511);
    union { unsigned short s[4]; uint2 u; } w;
#pragma unroll
    for (int tt = 0; tt < 4; tt++) w.s[tt] = f2b(g_out_w[(p + tt) * 512 + ii]);
    *(uint2*)(WgoT + off) = w.u;
    return;
  }
  const float* src; unsigned short* dst; long off; float sc = 1.0f;
  if (i < 524288L)        { dst = Wq;  off = i; src = (i < 262144L) ? wq + i : g_in_w + (i - 262144L); }
  else if (i < 1048576L)  { long j = i - 524288L;  dst = Wk;  off = j; src = (j < 262144L) ? wk + j : g_in_w + j; }
  else if (i < 1572864L)  { long j = i - 1048576L; dst = Wv;  off = j; src = (j < 262144L) ? wv + j : g_in_w + 262144L + j; }
  else if (i < 1835008L)  { long j = i - 1572864L; dst = Wo_; off = j; src = wo + j; }
  else if (i < 2097152L)  { long j = i - 1835008L; int col = (int)(j >> 9), k = (int)(j & 511);
                            dst = Bfin; off = (long)col * 1024 + k; src = wo + j; sc = 0.7f; }
  else                    { long j = i - 2359296L; dst = Rk;  off = j; src = rel_k + j; }
  float4 f = *(const float4*)src;
  union { unsigned short s[4]; uint2 u; } p;
  p.s[0] = f2b(f.x * sc); p.s[1] = f2b(f.y * sc); p.s[2] = f2b(f.z * sc); p.s[3] = f2b(f.w * sc);
  *(uint2*)(dst + off) = p.u;
}

// ============================ GEMM ============================
// Single-barrier double-buffered pipeline (T3-min): per k-step
// {ds_read frags(cur) -> issue DMA(next -> alt) -> MFMA -> syncthreads}.
// W2JOB=1: blocks >= 1024 compute W2 = A2 @ B2^T -> outb2[row*1024+512+col]*0.3.
template <int NB, int EPI, int KD, int LDA, int GRIDM, int W2JOB>
__global__ __launch_bounds__(256) void gemm_bf16_kern(
    const unsigned short* __restrict__ A, const unsigned short* __restrict__ Bw,
    const float* __restrict__ bias0, const float* __restrict__ bias1,
    unsigned short* __restrict__ outb, unsigned short* __restrict__ outb2,
    float* __restrict__ outf,
    const unsigned short* __restrict__ A2, const unsigned short* __restrict__ B2) {
  __shared__ unsigned short lsA[2][4096];
  __shared__ unsigned short lsB[2][4096];
  const int t = threadIdx.x;
  const int lane = t & 63, w = t >> 6;
  const int l15 = lane & 15, g8 = (lane >> 4) * 8, g4 = (lane >> 4) * 4;
  int n = blockIdx.x;
  bool w2 = false;
  int rb, cb;
  if constexpr (GRIDM > 0) {
    rb = (n % GRIDM) * 128; cb = (n / GRIDM) * 128;
  } else {
    int x = n >> 3, c = n & 7;
    rb = (c * 16 + (x & 15)) * 128;
    cb = (x >> 4) * 128;
  }
  const unsigned short* Ap = A;
  const unsigned short* Bp = Bw;
  if constexpr (W2JOB) {
    if (n >= 1024) {
      w2 = true;
      int m2 = n - 1024;
      rb = (m2 & 3) * 128; cb = (m2 >> 2) * 128;
      Ap = A2; Bp = B2;
    }
  }
  const int wr = (w >> 1) * 64, wc = (w & 1) * 64;
  const int e0 = t * 8, e1 = 2048 + t * 8;
  const int r0 = e0 >> 5, k0i = e0 & 31;
  const int r1 = e1 >> 5, k1i = e1 & 31;

  const unsigned short* pa0 = Ap + (long)(rb + r0) * LDA + k0i;
  const unsigned short* pa1 = Ap + (long)(rb + r1) * LDA + k1i;
  const unsigned short* pb0 = Bp + (long)(cb + r0) * KD + k0i;
  const unsigned short* pb1 = Bp + (long)(cb + r1) * KD + k1i;

#define GSTAGE(KK, BUF) { \
    gload_lds16(pa0 + (KK), lsA[BUF] + w * 512); \
    gload_lds16(pa1 + (KK), lsA[BUF] + 2048 + w * 512); \
    gload_lds16(pb0 + (KK), lsB[BUF] + w * 512); \
    gload_lds16(pb1 + (KK), lsB[BUF] + 2048 + w * 512); }

  GSTAGE(0, 0);
  __syncthreads();

  f4 acc[4][4] = {};
  int cur = 0;
  for (int k0 = 0; k0 < KD; k0 += 32) {
    bh8 af[4], bf[4];
#pragma unroll
    for (int m = 0; m < 4; m++) af[m] = *(const bh8*)(lsA[cur] + (wr + m * 16 + l15) * 32 + g8);
#pragma unroll
    for (int nn = 0; nn < 4; nn++) bf[nn] = *(const bh8*)(lsB[cur] + (wc + nn * 16 + l15) * 32 + g8);
    if (k0 + 32 < KD) GSTAGE(k0 + 32, cur ^ 1);
    __builtin_amdgcn_s_setprio(1);
#pragma unroll
    for (int m = 0; m < 4; m++)
#pragma unroll
      for (int nn = 0; nn < 4; nn++)
        acc[m][nn] = mfma16(af[m], bf[nn], acc[m][nn]);
    __builtin_amdgcn_s_setprio(0);
    __syncthreads();
    cur ^= 1;
  }
#undef GSTAGE

  if constexpr (W2JOB) {
    if (w2) {
#pragma unroll
      for (int m = 0; m < 4; m++)
#pragma unroll
        for (int nn = 0; nn < 4; nn++)
#pragma unroll
          for (int j = 0; j < 4; j++) {
            int row = rb + wr + m * 16 + g4 + j;
            int col = cb + wc + nn * 16 + l15;
            outb2[(long)row * 1024 + 512 + col] = f2b(0.3f * acc[m][nn][j]);
          }
      return;
    }
  }
#pragma unroll
  for (int m = 0; m < 4; m++) {
#pragma unroll
    for (int nn = 0; nn < 4; nn++) {
      if constexpr (EPI == 3) {
        int col = cb + wc + nn * 16 + l15;
        float bsv = (col < 512) ? bias0[col] : bias1[col - 512];
        unsigned r[4];
#pragma unroll
        for (int j = 0; j < 4; j++) {
          union { float f; unsigned u; } v; v.f = acc[m][nn][j] + bsv;
          r[j] = v.u + 0x7fffu + ((v.u >> 16) & 1u);
        }
        unsigned lo = (r[0] >> 16) | (r[1] & 0xffff0000u);
        unsigned hi = (r[2] >> 16) | (r[3] & 0xffff0000u);
        int row0 = rb + wr + m * 16 + g4;
        int bb = row0 >> 9, s = row0 & 511;
        if (col < 512) {
          int hh = col >> 6, d = col & 63;
          *(uint2*)(outb + (((long)(bb * 8 + hh) * 64 + d) << 9) + s) = make_uint2(lo, hi);
        } else {
          int c2 = col - 512, hg = c2 >> 7, dg = c2 & 127;
          *(uint2*)(outb2 + (((long)(bb * 4 + hg) * 128 + dg) << 9) + s) = make_uint2(lo, hi);
        }
      } else {
#pragma unroll
        for (int j = 0; j < 4; j++) {
          int row = rb + wr + m * 16 + g4 + j;
          int col = cb + wc + nn * 16 + l15;
          float v = acc[m][nn][j];
          if constexpr (EPI == 0) {
            v += (col < 512) ? bias0[col] : bias1[col - 512];
            outb[(long)row * (NB * 128) + col] = f2b(v);
          } else {
            v += bias0[col];
            outf[(long)row * 512 + col] = v;
          }
        }
      }
    }
  }
}

// ============================ local attention v6 (R7, proven) ============================
__global__ __launch_bounds__(512, 4) void attn_local_kern(
    const unsigned short* __restrict__ Yq, const unsigned short* __restrict__ Yk,
    const unsigned short* __restrict__ Yvt, const unsigned short* __restrict__ relk,
    unsigned short* __restrict__ outC) {
  __shared__ unsigned short kv[2][8192];
  __shared__ unsigned short buf[32 * 524];
  __shared__ float redbuf[8][32];

  const int t = threadIdx.x, lane = t & 63, w = t >> 6;
  const int l15 = lane & 15, g = lane >> 4, g8 = g * 8;
  int n = blockIdx.x;
  int bid = (n & 7) * 512 + (n >> 3);
  const int qt = bid & 15;
  const int h = (bid >> 4) & 7;
  const int b = bid >> 7;
  const int qb = qt * 32;
  const long base = ((long)(b * 512)) * 1024 + h * 64;
  const long vbase = ((long)(b * 8 + h)) * 64 * 512;

#define STAGE_K(ROFF, BUF) { \
    const int c_ = t & 7; \
    _Pragma("unroll") \
    for (int it = 0; it < 2; it++) { \
      int rr = it * 64 + (t >> 3); \
      gload_lds16(Yk + base + (long)((ROFF) + rr) * 1024 + ((c_ ^ (rr & 7)) * 8), \
                  kv[BUF] + it * 4096 + w * 512); \
    } }
#define STAGE_V(COFF, BUF) { \
    const int c_ = t & 15; \
    _Pragma("unroll") \
    for (int it = 0; it < 2; it++) { \
      int dd_ = it * 32 + (t >> 4); \
      gload_lds16(Yvt + vbase + (long)dd_ * 512 + (COFF) + ((c_ ^ (dd_ & 15)) * 8), \
                  kv[BUF] + it * 4096 + w * 512); \
    } }
#define QK(CH) { \
    int rl = w * 16 + l15; \
    const unsigned short* kb_ = kv[(CH) & 1]; \
    bh8 k0 = *(const bh8*)(kb_ + rl * 64 + ((g ^ (rl & 7)) * 8)); \
    bh8 k1 = *(const bh8*)(kb_ + rl * 64 + (((g + 4) ^ (rl & 7)) * 8)); \
    _Pragma("unroll") \
    for (int mm = 0; mm < 2; mm++) { \
      f4 a = {}; \
      a = mfma16(qf[mm][0], k0, a); \
      a = mfma16(qf[mm][1], k1, a); \
      sc[mm][CH] = a; \
    } }
#define GATHER(CH) { \
    _Pragma("unroll") \
    for (int mm = 0; mm < 2; mm++) \
    _Pragma("unroll") \
    for (int j = 0; j < 4; j++) { \
      int lr = mm * 16 + g * 4 + j; \
      int rowb = lr * 524; \
      int idx = rowb + 256 - (qb + lr) + (CH) * 128 + w * 16 + l15; \
      idx = idx < rowb ? rowb : idx; \
      idx = idx > rowb + 512 ? rowb + 512 : idx; \
      float p = exp2f(fmaf(sc[mm][CH][j], 0.18033688011112042f, b2f(buf[idx]))); \
      sc[mm][CH][j] = p; \
      rs[mm][j] += p; \
    } }

  STAGE_K(0, 0);

  bh8 qf[2][2];
#pragma unroll
  for (int mm = 0; mm < 2; mm++) {
    const unsigned short* qp = Yq + base + (long)(qb + mm * 16 + l15) * 1024 + g8;
    qf[mm][0] = *(const bh8*)(qp);
    qf[mm][1] = *(const bh8*)(qp + 32);
  }

  for (int tt = w; tt < 33; tt += 8) {
    int ri = tt * 16 + l15; if (ri > 512) ri = 512;
    const unsigned short* rp = relk + ri * 64 + g8;
    bh8 rf0 = *(const bh8*)(rp), rf1 = *(const bh8*)(rp + 32);
    int col = tt * 16 + l15;
#pragma unroll
    for (int mm = 0; mm < 2; mm++) {
      f4 a = {};
      a = mfma16(qf[mm][0], rf0, a);
      a = mfma16(qf[mm][1], rf1, a);
      if (col < 524) {
#pragma unroll
        for (int j = 0; j < 4; j++)
          buf[(mm * 16 + g * 4 + j) * 524 + col] = f2b(a[j] * 1.4426950408889634f);
      }
    }
  }
  __syncthreads();

  f4 sc[2][4];
  float rs[2][4] = {};

#pragma unroll
  for (int c = 0; c < 4; c++) {
    if (c < 3) { STAGE_K((c + 1) * 128, (c + 1) & 1); }
    else       { STAGE_V(0, 0); }
    __builtin_amdgcn_s_setprio(1);
    QK(c);
    __builtin_amdgcn_s_setprio(0);
    GATHER(c);
    __syncthreads();
  }

#pragma unroll
  for (int mm = 0; mm < 2; mm++)
#pragma unroll
    for (int j = 0; j < 4; j++) {
      int lr = mm * 16 + g * 4 + j;
      float s = rs[mm][j];
      for (int d = 1; d < 16; d <<= 1) s += __shfl_xor(s, d, 64);
      if (l15 == 0) redbuf[w][lr] = s;
    }
#pragma unroll
  for (int mm = 0; mm < 2; mm++)
#pragma unroll
    for (int ch = 0; ch < 4; ch++) {
      int col = ch * 128 + w * 16 + l15;
#pragma unroll
      for (int j = 0; j < 4; j++)
        buf[(mm * 16 + g * 4 + j) * 524 + col] = f2b(sc[mm][ch][j]);
    }
  __syncthreads();

  const int mmw = w >> 2, dt = w & 3;
  const int dd = dt * 16 + l15;
  float rinvj[4];
#pragma unroll
  for (int j = 0; j < 4; j++) {
    int lr = mmw * 16 + g * 4 + j;
    float s = 0.f;
#pragma unroll
    for (int ww = 0; ww < 8; ww++) s += redbuf[ww][lr];
    rinvj[j] = __builtin_amdgcn_rcpf(s);
  }

  f4 accO = {};
#pragma unroll
  for (int d = 0; d < 4; d++) {
    if (d < 3) { STAGE_V((d + 1) * 128, (d + 1) & 1); }
    const unsigned short* vb_ = kv[d & 1];
    __builtin_amdgcn_s_setprio(1);
#pragma unroll
    for (int ks2 = 0; ks2 < 4; ks2++) {
      union { uint2 u[2]; bh8 v; } pa;
      const unsigned short* pp = buf + (mmw * 16 + l15) * 524 + (d * 4 + ks2) * 32 + g8;
      pa.u[0] = *(const uint2*)(pp);
      pa.u[1] = *(const uint2*)(pp + 4);
      bh8 vv = *(const bh8*)(vb_ + dd * 128 + (((ks2 * 4 + g) ^ (dd & 15)) * 8));
      accO = mfma16(pa.v, vv, accO);
    }
    __builtin_amdgcn_s_setprio(0);
    if (d < 3) __syncthreads();
  }
#pragma unroll
  for (int j = 0; j < 4; j++) {
    int row = qb + mmw * 16 + g * 4 + j;
    outC[((long)(b * 512 + row)) * 1024 + h * 64 + dt * 16 + l15] = f2b(accO[j] * rinvj[j]);
  }
#undef STAGE_K
#undef STAGE_V
#undef QK
#undef GATHER
}

// ============================ global attention v2 (R7, proven) ============================
__global__ __launch_bounds__(512) void attn_glob_kern(
    const unsigned short* __restrict__ Yq, const unsigned short* __restrict__ Yk,
    const unsigned short* __restrict__ Yvt, unsigned short* __restrict__ outC) {
  __shared__ unsigned short buf[32 * 520];
  __shared__ float redbuf[8][32];

  const int t = threadIdx.x, lane = t & 63, w = t >> 6;
  const int l15 = lane & 15, g = lane >> 4, g8 = g * 8;
  int n = blockIdx.x;
  int bid = (n & 7) * 256 + (n >> 3);
  const int qt = bid & 15;
  const int hg = (bid >> 4) & 3;
  const int b = bid >> 6;
  const int qb = qt * 32;
  const long base = ((long)(b * 512)) * 1024 + 512 + hg * 128;

  bh8 qf[2][4];
#pragma unroll
  for (int mm = 0; mm < 2; mm++) {
    const unsigned short* qp = Yq + base + (long)(qb + mm * 16 + l15) * 1024 + g8;
#pragma unroll
    for (int ks = 0; ks < 4; ks++) qf[mm][ks] = *(const bh8*)(qp + ks * 32);
  }

  f4 sc[2][4];
  __builtin_amdgcn_s_setprio(1);
#pragma unroll
  for (int ct = 0; ct < 4; ct++) {
    int r = w * 64 + ct * 16 + l15;
    const unsigned short* kp = Yk + base + (long)r * 1024 + g8;
    bh8 kf[4];
#pragma unroll
    for (int ks = 0; ks < 4; ks++) kf[ks] = *(const bh8*)(kp + ks * 32);
#pragma unroll
    for (int mm = 0; mm < 2; mm++) {
      f4 a = {};
#pragma unroll
      for (int ks = 0; ks < 4; ks++) a = mfma16(qf[mm][ks], kf[ks], a);
      sc[mm][ct] = a;
    }
  }
  __builtin_amdgcn_s_setprio(0);

#pragma unroll
  for (int mm = 0; mm < 2; mm++) {
#pragma unroll
    for (int j = 0; j < 4; j++) {
      int lr = mm * 16 + g * 4 + j;
      float s = 0.f;
#pragma unroll
      for (int ct = 0; ct < 4; ct++) {
        float p = exp2f(sc[mm][ct][j] * 0.12751745334f);
        sc[mm][ct][j] = p;
        s += p;
      }
      for (int d = 1; d < 16; d <<= 1) s += __shfl_xor(s, d, 64);
      if (l15 == 0) redbuf[w][lr] = s;
    }
  }
#pragma unroll
  for (int mm = 0; mm < 2; mm++)
#pragma unroll
    for (int ct = 0; ct < 4; ct++) {
      int col = w * 64 + ct * 16 + l15;
#pragma unroll
      for (int j = 0; j < 4; j++)
        buf[(mm * 16 + g * 4 + j) * 520 + col] = f2b(sc[mm][ct][j]);
    }
  __syncthreads();

  float rinv[2][4];
#pragma unroll
  for (int mm = 0; mm < 2; mm++)
#pragma unroll
    for (int j = 0; j < 4; j++) {
      int lr = mm * 16 + g * 4 + j;
      float s = 0.f;
#pragma unroll
      for (int ww = 0; ww < 8; ww++) s += redbuf[ww][lr];
      rinv[mm][j] = __builtin_amdgcn_rcpf(s);
    }

  f4 accO[2] = {};
  const unsigned short* vr = Yvt + ((long)(b * 4 + hg) * 128 + w * 16 + l15) * 512;
  __builtin_amdgcn_s_setprio(1);
#pragma unroll
  for (int ks = 0; ks < 16; ks++) {
    bh8 vb = *(const bh8*)(vr + ks * 32 + g8);
#pragma unroll
    for (int mm = 0; mm < 2; mm++) {
      union { uint2 u[2]; bh8 v; } pa;
      const unsigned short* pp = buf + (mm * 16 + l15) * 520 + ks * 32 + g8;
      pa.u[0] = *(const uint2*)(pp);
      pa.u[1] = *(const uint2*)(pp + 4);
      accO[mm] = mfma16(pa.v, vb, accO[mm]);
    }
  }
  __builtin_amdgcn_s_setprio(0);
#pragma unroll
  for (int mm = 0; mm < 2; mm++)
#pragma unroll
    for (int j = 0; j < 4; j++) {
      int row = qb + mm * 16 + g * 4 + j;
      outC[((long)(b * 512 + row)) * 1024 + 512 + hg * 128 + w * 16 + l15] = f2b(accO[mm][j] * rinv[mm][j]);
    }
}

// ============================ launch ============================
extern "C" void kernel_launch(void* const* d_in, const int* in_sizes, int n_in,
                              void* d_out, int out_size, void* d_ws, size_t ws_size,
                              hipStream_t stream) {
  const float* query = (const float*)d_in[0];
  const float* key   = (const float*)d_in[1];
  const float* value = (const float*)d_in[2];
  const float* wq = (const float*)d_in[3];   const float* bq = (const float*)d_in[4];
  const float* wk = (const float*)d_in[5];   const float* bk = (const float*)d_in[6];
  const float* wv = (const float*)d_in[7];   const float* bv = (const float*)d_in[8];
  const float* wo = (const float*)d_in[9];   const float* bo = (const float*)d_in[10];
  const float* rel_k = (const float*)d_in[11];
  const float* g_in_w = (const float*)d_in[12];  const float* g_in_b = (const float*)d_in[13];
  const float* g_out_w = (const float*)d_in[14]; const float* g_out_b = (const float*)d_in[15];

  unsigned short* p = (unsigned short*)d_ws;
  unsigned short* Xq = p;            p += 8388608;   // CAT spans Xq+Xk
  unsigned short* Xk = p;            p += 8388608;
  unsigned short* Xv = p;            p += 8388608;
  unsigned short* Yq = p;            p += 16777216;  // [16384][1024]
  unsigned short* Yk = p;            p += 16777216;
  unsigned short* Yvt_l = p;         p += 8388608;   // [b][h][64][512]
  unsigned short* Yvt_g = p;         p += 8388608;   // [b][hg][128][512]
  unsigned short* Wq = p;            p += 524288;
  unsigned short* Wk = p;            p += 524288;
  unsigned short* Wv = p;            p += 524288;
  unsigned short* Wo_ = p;           p += 262144;
  unsigned short* WgoT = p;          p += 262144;
  unsigned short* Bfin = p;          p += 524288;    // [512][1024]
  unsigned short* Rk = p;            p += 32832;
  float* bias2 = (float*)p;          p += 1024;
  unsigned short* CAT = Xq;                          // [16384][1024]

  prep_x_kern<<<8192, 256, 0, stream>>>(query, key, value, Xq, Xk, Xv);
  prep_w_kern<<<2339, 256, 0, stream>>>(wq, wk, wv, g_in_w, g_out_w, wo, rel_k,
                                        g_out_b, bo,
                                        Wq, Wk, Wv, Wo_, WgoT, Bfin, Rk, bias2);

  // Yq projection + W2 product (16 extra blocks, concurrent)
  gemm_bf16_kern<8, 0, 512, 512, 0, 1><<<1040, 256, 0, stream>>>(
      Xq, Wq, bq, g_in_b, Yq, Bfin, nullptr, Wo_, WgoT);
  gemm_bf16_kern<8, 0, 512, 512, 0, 0><<<1024, 256, 0, stream>>>(
      Xk, Wk, bk, g_in_b + 512, Yk, nullptr, nullptr, nullptr, nullptr);
  gemm_bf16_kern<8, 3, 512, 512, 0, 0><<<1024, 256, 0, stream>>>(
      Xv, Wv, bv, g_in_b + 1024, Yvt_l, Yvt_g, nullptr, nullptr, nullptr);

  attn_local_kern<<<4096, 512, 0, stream>>>(Yq, Yk, Yvt_l, Rk, CAT);
  attn_glob_kern<<<2048, 512, 0, stream>>>(Yq, Yk, Yvt_g, CAT);

  // out = CAT @ Bfin^T + bias2
  gemm_bf16_kern<4, 2, 1024, 1024, 0, 0><<<512, 256, 0, stream>>>(
      CAT, Bfin, bias2, nullptr, nullptr, nullptr, (float*)d_out, nullptr, nullptr);
}

// Round 10
// 345.172 us; speedup vs baseline: 1.0461x; 1.0315x over previous
//
#include <hip/hip_runtime.h>

typedef __attribute__((ext_vector_type(8))) short bh8;
typedef __attribute__((ext_vector_type(4))) float f4;

#define DEVI static __device__ __forceinline__

DEVI unsigned short f2b(float f) {
  union { float f; unsigned u; } v; v.f = f;
  unsigned r = v.u + 0x7fffu + ((v.u >> 16) & 1u);
  return (unsigned short)(r >> 16);
}
DEVI float b2f(unsigned short h) {
  union { unsigned u; float f; } v; v.u = ((unsigned)h) << 16;
  return v.f;
}
DEVI f4 mfma16(bh8 a, bh8 b, f4 c) {
  return __builtin_amdgcn_mfma_f32_16x16x32_bf16(a, b, c, 0, 0, 0);
}
DEVI void gload_lds16(const unsigned short* g, unsigned short* l) {
  __builtin_amdgcn_global_load_lds(
      (const __attribute__((address_space(1))) void*)(g),
      (__attribute__((address_space(3))) void*)(l), 16, 0, 0);
}

// ============================ prep kernels ============================
__global__ __launch_bounds__(256) void prep_x_kern(
    const float* __restrict__ q, const float* __restrict__ k, const float* __restrict__ v,
    unsigned short* __restrict__ xq, unsigned short* __restrict__ xk, unsigned short* __restrict__ xv) {
  long i = ((long)blockIdx.x * 256 + threadIdx.x) * 4;
  if (i >= 8388608L) return;
  float4 a = *(const float4*)(q + i);
  float4 b = *(const float4*)(k + i);
  float4 c = *(const float4*)(v + i);
  union { unsigned short s[4]; uint2 u; } pa, pb, pc;
  pa.s[0] = f2b(a.x); pa.s[1] = f2b(a.y); pa.s[2] = f2b(a.z); pa.s[3] = f2b(a.w);
  pb.s[0] = f2b(b.x); pb.s[1] = f2b(b.y); pb.s[2] = f2b(b.z); pb.s[3] = f2b(b.w);
  pc.s[0] = f2b(c.x); pc.s[1] = f2b(c.y); pc.s[2] = f2b(c.z); pc.s[3] = f2b(c.w);
  *(uint2*)(xq + i) = pa.u;
  *(uint2*)(xk + i) = pb.u;
  *(uint2*)(xv + i) = pc.u;
}

// weight repack + bias2 fold (blocks 2337-2338): bias2 = bo + 0.3*(Wo @ bgo)
__global__ __launch_bounds__(256) void prep_w_kern(
    const float* __restrict__ wq, const float* __restrict__ wk, const float* __restrict__ wv,
    const float* __restrict__ g_in_w, const float* __restrict__ g_out_w,
    const float* __restrict__ wo, const float* __restrict__ rel_k,
    const float* __restrict__ bgo, const float* __restrict__ bo,
    unsigned short* __restrict__ Wq, unsigned short* __restrict__ Wk, unsigned short* __restrict__ Wv,
    unsigned short* __restrict__ Wo_, unsigned short* __restrict__ WgoT,
    unsigned short* __restrict__ Bfin, unsigned short* __restrict__ Rk,
    float* __restrict__ bias2) {
  if (blockIdx.x >= 2337) {
    int o = (blockIdx.x - 2337) * 256 + threadIdx.x;
    if (o < 512) {
      const float* r = wo + (long)o * 512;
      float s = 0.f;
#pragma unroll 4
      for (int m = 0; m < 512; m += 4) {
        float4 a = *(const float4*)(r + m);
        float4 b = *(const float4*)(bgo + m);
        s += a.x * b.x + a.y * b.y + a.z * b.z + a.w * b.w;
      }
      bias2[o] = bo[o] + 0.3f * s;
    }
    return;
  }
  long i = ((long)blockIdx.x * 256 + threadIdx.x) * 4;
  if (i >= 2392128L) return;
  if (i >= 2097152L && i < 2359296L) {  // WgoT scatter
    long off = i - 2097152L;
    int ii = (int)(off >> 9), p = (int)(off & 511);
    union { unsigned short s[4]; uint2 u; } w;
#pragma unroll
    for (int tt = 0; tt < 4; tt++) w.s[tt] = f2b(g_out_w[(p + tt) * 512 + ii]);
    *(uint2*)(WgoT + off) = w.u;
    return;
  }
  const float* src; unsigned short* dst; long off; float sc = 1.0f;
  if (i < 524288L)        { dst = Wq;  off = i; src = (i < 262144L) ? wq + i : g_in_w + (i - 262144L); }
  else if (i < 1048576L)  { long j = i - 524288L;  dst = Wk;  off = j; src = (j < 262144L) ? wk + j : g_in_w + j; }
  else if (i < 1572864L)  { long j = i - 1048576L; dst = Wv;  off = j; src = (j < 262144L) ? wv + j : g_in_w + 262144L + j; }
  else if (i < 1835008L)  { long j = i - 1572864L; dst = Wo_; off = j; src = wo + j; }
  else if (i < 2097152L)  { long j = i - 1835008L; int col = (int)(j >> 9), k = (int)(j & 511);
                            dst = Bfin; off = (long)col * 1024 + k; src = wo + j; sc = 0.7f; }
  else                    { long j = i - 2359296L; dst = Rk;  off = j; src = rel_k + j; }
  float4 f = *(const float4*)src;
  union { unsigned short s[4]; uint2 u; } p;
  p.s[0] = f2b(f.x * sc); p.s[1] = f2b(f.y * sc); p.s[2] = f2b(f.z * sc); p.s[3] = f2b(f.w * sc);
  *(uint2*)(dst + off) = p.u;
}

// ============================ merged projection GEMM ============================
// One launch: blocks [0,1024) Q-proj, [1024,2048) K-proj, [2048,3072) V-proj,
// [3072,3088) W2 = Wo @ Wgo. 2-barrier proven core; 16KB LDS -> 8 blocks/CU.
__global__ __launch_bounds__(256) void gemm3_kern(
    const unsigned short* __restrict__ Xq, const unsigned short* __restrict__ Xk,
    const unsigned short* __restrict__ Xv,
    const unsigned short* __restrict__ Wq, const unsigned short* __restrict__ Wk,
    const unsigned short* __restrict__ Wv,
    const float* __restrict__ bq, const float* __restrict__ bk, const float* __restrict__ bv,
    const float* __restrict__ g_in_b,
    unsigned short* __restrict__ Yq, unsigned short* __restrict__ Yk_,
    unsigned short* __restrict__ Yvt_l, unsigned short* __restrict__ Yvt_g,
    const unsigned short* __restrict__ Wo_, const unsigned short* __restrict__ WgoT,
    unsigned short* __restrict__ Bfin) {
  __shared__ unsigned short lsA[128 * 32];
  __shared__ unsigned short lsB[128 * 32];
  const int t = threadIdx.x;
  const int lane = t & 63, w = t >> 6;
  const int l15 = lane & 15, g8 = (lane >> 4) * 8, g4 = (lane >> 4) * 4;
  const int n = blockIdx.x;

  const unsigned short *Ap, *Bp;
  const float *b0 = nullptr, *b1 = nullptr;
  int seg, rb, cb;
  if (n < 3072) {
    seg = n >> 10;
    int m = n & 1023;
    int x = m >> 3, c = m & 7;
    rb = (c * 16 + (x & 15)) * 128;
    cb = (x >> 4) * 128;
    Ap = (seg == 0) ? Xq : (seg == 1) ? Xk : Xv;
    Bp = (seg == 0) ? Wq : (seg == 1) ? Wk : Wv;
    b0 = (seg == 0) ? bq : (seg == 1) ? bk : bv;
    b1 = g_in_b + seg * 512;
  } else {
    seg = 3;
    int m2 = n - 3072;
    rb = (m2 & 3) * 128; cb = (m2 >> 2) * 128;
    Ap = Wo_; Bp = WgoT;
  }

  const int wr = (w >> 1) * 64, wc = (w & 1) * 64;
  const int e0 = t * 8, e1 = 2048 + t * 8;
  const int r0 = e0 >> 5, k0i = e0 & 31;
  const int r1 = e1 >> 5, k1i = e1 & 31;

  const unsigned short* pa0 = Ap + (long)(rb + r0) * 512 + k0i;
  const unsigned short* pa1 = Ap + (long)(rb + r1) * 512 + k1i;
  const unsigned short* pb0 = Bp + (long)(cb + r0) * 512 + k0i;
  const unsigned short* pb1 = Bp + (long)(cb + r1) * 512 + k1i;
  unsigned short* dA0 = lsA + w * 512;
  unsigned short* dA1 = lsA + 2048 + w * 512;
  unsigned short* dB0 = lsB + w * 512;
  unsigned short* dB1 = lsB + 2048 + w * 512;

  f4 acc[4][4] = {};
  for (int k0 = 0; k0 < 512; k0 += 32) {
    __syncthreads();
    gload_lds16(pa0 + k0, dA0);
    gload_lds16(pa1 + k0, dA1);
    gload_lds16(pb0 + k0, dB0);
    gload_lds16(pb1 + k0, dB1);
    __syncthreads();
    bh8 af[4], bf[4];
#pragma unroll
    for (int m = 0; m < 4; m++) af[m] = *(const bh8*)(lsA + (wr + m * 16 + l15) * 32 + g8);
#pragma unroll
    for (int nn = 0; nn < 4; nn++) bf[nn] = *(const bh8*)(lsB + (wc + nn * 16 + l15) * 32 + g8);
    __builtin_amdgcn_s_setprio(1);
#pragma unroll
    for (int m = 0; m < 4; m++)
#pragma unroll
      for (int nn = 0; nn < 4; nn++)
        acc[m][nn] = mfma16(af[m], bf[nn], acc[m][nn]);
    __builtin_amdgcn_s_setprio(0);
  }

  if (seg == 3) {   // W2 -> Bfin cols 512+
#pragma unroll
    for (int m = 0; m < 4; m++)
#pragma unroll
      for (int nn = 0; nn < 4; nn++)
#pragma unroll
        for (int j = 0; j < 4; j++) {
          int row = rb + wr + m * 16 + g4 + j;
          int col = cb + wc + nn * 16 + l15;
          Bfin[(long)row * 1024 + 512 + col] = f2b(0.3f * acc[m][nn][j]);
        }
    return;
  }
  if (seg == 2) {   // V-proj: transposed-per-head, uint2-packed
#pragma unroll
    for (int m = 0; m < 4; m++)
#pragma unroll
      for (int nn = 0; nn < 4; nn++) {
        int col = cb + wc + nn * 16 + l15;
        float bsv = (col < 512) ? b0[col] : b1[col - 512];
        unsigned r[4];
#pragma unroll
        for (int j = 0; j < 4; j++) {
          union { float f; unsigned u; } v; v.f = acc[m][nn][j] + bsv;
          r[j] = v.u + 0x7fffu + ((v.u >> 16) & 1u);
        }
        unsigned lo = (r[0] >> 16) | (r[1] & 0xffff0000u);
        unsigned hi = (r[2] >> 16) | (r[3] & 0xffff0000u);
        int row0 = rb + wr + m * 16 + g4;
        int bb = row0 >> 9, s = row0 & 511;
        if (col < 512) {
          int hh = col >> 6, d = col & 63;
          *(uint2*)(Yvt_l + (((long)(bb * 8 + hh) * 64 + d) << 9) + s) = make_uint2(lo, hi);
        } else {
          int c2 = col - 512, hg = c2 >> 7, dg = c2 & 127;
          *(uint2*)(Yvt_g + (((long)(bb * 4 + hg) * 128 + dg) << 9) + s) = make_uint2(lo, hi);
        }
      }
    return;
  }
  unsigned short* Yo = (seg == 0) ? Yq : Yk_;
#pragma unroll
  for (int m = 0; m < 4; m++)
#pragma unroll
    for (int nn = 0; nn < 4; nn++)
#pragma unroll
      for (int j = 0; j < 4; j++) {
        int row = rb + wr + m * 16 + g4 + j;
        int col = cb + wc + nn * 16 + l15;
        float v = acc[m][nn][j] + ((col < 512) ? b0[col] : b1[col - 512]);
        Yo[(long)row * 1024 + col] = f2b(v);
      }
}

// ============================ final GEMM (2-barrier core) ============================
// out = CAT[16384][1024] @ Bfin[512][1024]^T + bias2 -> f32
__global__ __launch_bounds__(256) void gemm_fin_kern(
    const unsigned short* __restrict__ A, const unsigned short* __restrict__ Bw,
    const float* __restrict__ bias0, float* __restrict__ outf) {
  __shared__ unsigned short lsA[128 * 32];
  __shared__ unsigned short lsB[128 * 32];
  const int t = threadIdx.x;
  const int lane = t & 63, w = t >> 6;
  const int l15 = lane & 15, g8 = (lane >> 4) * 8, g4 = (lane >> 4) * 4;
  int n = blockIdx.x;
  int x = n >> 3, c = n & 7;
  const int rb = (c * 16 + (x & 15)) * 128;
  const int cb = (x >> 4) * 128;
  const int wr = (w >> 1) * 64, wc = (w & 1) * 64;
  const int e0 = t * 8, e1 = 2048 + t * 8;
  const int r0 = e0 >> 5, k0i = e0 & 31;
  const int r1 = e1 >> 5, k1i = e1 & 31;

  const unsigned short* pa0 = A + (long)(rb + r0) * 1024 + k0i;
  const unsigned short* pa1 = A + (long)(rb + r1) * 1024 + k1i;
  const unsigned short* pb0 = Bw + (long)(cb + r0) * 1024 + k0i;
  const unsigned short* pb1 = Bw + (long)(cb + r1) * 1024 + k1i;
  unsigned short* dA0 = lsA + w * 512;
  unsigned short* dA1 = lsA + 2048 + w * 512;
  unsigned short* dB0 = lsB + w * 512;
  unsigned short* dB1 = lsB + 2048 + w * 512;

  f4 acc[4][4] = {};
  for (int k0 = 0; k0 < 1024; k0 += 32) {
    __syncthreads();
    gload_lds16(pa0 + k0, dA0);
    gload_lds16(pa1 + k0, dA1);
    gload_lds16(pb0 + k0, dB0);
    gload_lds16(pb1 + k0, dB1);
    __syncthreads();
    bh8 af[4], bf[4];
#pragma unroll
    for (int m = 0; m < 4; m++) af[m] = *(const bh8*)(lsA + (wr + m * 16 + l15) * 32 + g8);
#pragma unroll
    for (int nn = 0; nn < 4; nn++) bf[nn] = *(const bh8*)(lsB + (wc + nn * 16 + l15) * 32 + g8);
    __builtin_amdgcn_s_setprio(1);
#pragma unroll
    for (int m = 0; m < 4; m++)
#pragma unroll
      for (int nn = 0; nn < 4; nn++)
        acc[m][nn] = mfma16(af[m], bf[nn], acc[m][nn]);
    __builtin_amdgcn_s_setprio(0);
  }
#pragma unroll
  for (int m = 0; m < 4; m++)
#pragma unroll
    for (int nn = 0; nn < 4; nn++)
#pragma unroll
      for (int j = 0; j < 4; j++) {
        int row = rb + wr + m * 16 + g4 + j;
        int col = cb + wc + nn * 16 + l15;
        outf[(long)row * 512 + col] = acc[m][nn][j] + bias0[col];
      }
}

// ============================ local attention v6 (R7, proven) ============================
__global__ __launch_bounds__(512, 4) void attn_local_kern(
    const unsigned short* __restrict__ Yq, const unsigned short* __restrict__ Yk,
    const unsigned short* __restrict__ Yvt, const unsigned short* __restrict__ relk,
    unsigned short* __restrict__ outC) {
  __shared__ unsigned short kv[2][8192];
  __shared__ unsigned short buf[32 * 524];
  __shared__ float redbuf[8][32];

  const int t = threadIdx.x, lane = t & 63, w = t >> 6;
  const int l15 = lane & 15, g = lane >> 4, g8 = g * 8;
  int n = blockIdx.x;
  int bid = (n & 7) * 512 + (n >> 3);
  const int qt = bid & 15;
  const int h = (bid >> 4) & 7;
  const int b = bid >> 7;
  const int qb = qt * 32;
  const long base = ((long)(b * 512)) * 1024 + h * 64;
  const long vbase = ((long)(b * 8 + h)) * 64 * 512;

#define STAGE_K(ROFF, BUF) { \
    const int c_ = t & 7; \
    _Pragma("unroll") \
    for (int it = 0; it < 2; it++) { \
      int rr = it * 64 + (t >> 3); \
      gload_lds16(Yk + base + (long)((ROFF) + rr) * 1024 + ((c_ ^ (rr & 7)) * 8), \
                  kv[BUF] + it * 4096 + w * 512); \
    } }
#define STAGE_V(COFF, BUF) { \
    const int c_ = t & 15; \
    _Pragma("unroll") \
    for (int it = 0; it < 2; it++) { \
      int dd_ = it * 32 + (t >> 4); \
      gload_lds16(Yvt + vbase + (long)dd_ * 512 + (COFF) + ((c_ ^ (dd_ & 15)) * 8), \
                  kv[BUF] + it * 4096 + w * 512); \
    } }
#define QK(CH) { \
    int rl = w * 16 + l15; \
    const unsigned short* kb_ = kv[(CH) & 1]; \
    bh8 k0 = *(const bh8*)(kb_ + rl * 64 + ((g ^ (rl & 7)) * 8)); \
    bh8 k1 = *(const bh8*)(kb_ + rl * 64 + (((g + 4) ^ (rl & 7)) * 8)); \
    _Pragma("unroll") \
    for (int mm = 0; mm < 2; mm++) { \
      f4 a = {}; \
      a = mfma16(qf[mm][0], k0, a); \
      a = mfma16(qf[mm][1], k1, a); \
      sc[mm][CH] = a; \
    } }
#define GATHER(CH) { \
    _Pragma("unroll") \
    for (int mm = 0; mm < 2; mm++) \
    _Pragma("unroll") \
    for (int j = 0; j < 4; j++) { \
      int lr = mm * 16 + g * 4 + j; \
      int rowb = lr * 524; \
      int idx = rowb + 256 - (qb + lr) + (CH) * 128 + w * 16 + l15; \
      idx = idx < rowb ? rowb : idx; \
      idx = idx > rowb + 512 ? rowb + 512 : idx; \
      float p = exp2f(fmaf(sc[mm][CH][j], 0.18033688011112042f, b2f(buf[idx]))); \
      sc[mm][CH][j] = p; \
      rs[mm][j] += p; \
    } }

  STAGE_K(0, 0);

  bh8 qf[2][2];
#pragma unroll
  for (int mm = 0; mm < 2; mm++) {
    const unsigned short* qp = Yq + base + (long)(qb + mm * 16 + l15) * 1024 + g8;
    qf[mm][0] = *(const bh8*)(qp);
    qf[mm][1] = *(const bh8*)(qp + 32);
  }

  for (int tt = w; tt < 33; tt += 8) {
    int ri = tt * 16 + l15; if (ri > 512) ri = 512;
    const unsigned short* rp = relk + ri * 64 + g8;
    bh8 rf0 = *(const bh8*)(rp), rf1 = *(const bh8*)(rp + 32);
    int col = tt * 16 + l15;
#pragma unroll
    for (int mm = 0; mm < 2; mm++) {
      f4 a = {};
      a = mfma16(qf[mm][0], rf0, a);
      a = mfma16(qf[mm][1], rf1, a);
      if (col < 524) {
#pragma unroll
        for (int j = 0; j < 4; j++)
          buf[(mm * 16 + g * 4 + j) * 524 + col] = f2b(a[j] * 1.4426950408889634f);
      }
    }
  }
  __syncthreads();

  f4 sc[2][4];
  float rs[2][4] = {};

#pragma unroll
  for (int c = 0; c < 4; c++) {
    if (c < 3) { STAGE_K((c + 1) * 128, (c + 1) & 1); }
    else       { STAGE_V(0, 0); }
    __builtin_amdgcn_s_setprio(1);
    QK(c);
    __builtin_amdgcn_s_setprio(0);
    GATHER(c);
    __syncthreads();
  }

#pragma unroll
  for (int mm = 0; mm < 2; mm++)
#pragma unroll
    for (int j = 0; j < 4; j++) {
      int lr = mm * 16 + g * 4 + j;
      float s = rs[mm][j];
      for (int d = 1; d < 16; d <<= 1) s += __shfl_xor(s, d, 64);
      if (l15 == 0) redbuf[w][lr] = s;
    }
#pragma unroll
  for (int mm = 0; mm < 2; mm++)
#pragma unroll
    for (int ch = 0; ch < 4; ch++) {
      int col = ch * 128 + w * 16 + l15;
#pragma unroll
      for (int j = 0; j < 4; j++)
        buf[(mm * 16 + g * 4 + j) * 524 + col] = f2b(sc[mm][ch][j]);
    }
  __syncthreads();

  const int mmw = w >> 2, dt = w & 3;
  const int dd = dt * 16 + l15;
  float rinvj[4];
#pragma unroll
  for (int j = 0; j < 4; j++) {
    int lr = mmw * 16 + g * 4 + j;
    float s = 0.f;
#pragma unroll
    for (int ww = 0; ww < 8; ww++) s += redbuf[ww][lr];
    rinvj[j] = __builtin_amdgcn_rcpf(s);
  }

  f4 accO = {};
#pragma unroll
  for (int d = 0; d < 4; d++) {
    if (d < 3) { STAGE_V((d + 1) * 128, (d + 1) & 1); }
    const unsigned short* vb_ = kv[d & 1];
    __builtin_amdgcn_s_setprio(1);
#pragma unroll
    for (int ks2 = 0; ks2 < 4; ks2++) {
      union { uint2 u[2]; bh8 v; } pa;
      const unsigned short* pp = buf + (mmw * 16 + l15) * 524 + (d * 4 + ks2) * 32 + g8;
      pa.u[0] = *(const uint2*)(pp);
      pa.u[1] = *(const uint2*)(pp + 4);
      bh8 vv = *(const bh8*)(vb_ + dd * 128 + (((ks2 * 4 + g) ^ (dd & 15)) * 8));
      accO = mfma16(pa.v, vv, accO);
    }
    __builtin_amdgcn_s_setprio(0);
    if (d < 3) __syncthreads();
  }
#pragma unroll
  for (int j = 0; j < 4; j++) {
    int row = qb + mmw * 16 + g * 4 + j;
    outC[((long)(b * 512 + row)) * 1024 + h * 64 + dt * 16 + l15] = f2b(accO[j] * rinvj[j]);
  }
#undef STAGE_K
#undef STAGE_V
#undef QK
#undef GATHER
}

// ============================ global attention v2 (R7, proven) ============================
__global__ __launch_bounds__(512) void attn_glob_kern(
    const unsigned short* __restrict__ Yq, const unsigned short* __restrict__ Yk,
    const unsigned short* __restrict__ Yvt, unsigned short* __restrict__ outC) {
  __shared__ unsigned short buf[32 * 520];
  __shared__ float redbuf[8][32];

  const int t = threadIdx.x, lane = t & 63, w = t >> 6;
  const int l15 = lane & 15, g = lane >> 4, g8 = g * 8;
  int n = blockIdx.x;
  int bid = (n & 7) * 256 + (n >> 3);
  const int qt = bid & 15;
  const int hg = (bid >> 4) & 3;
  const int b = bid >> 6;
  const int qb = qt * 32;
  const long base = ((long)(b * 512)) * 1024 + 512 + hg * 128;

  bh8 qf[2][4];
#pragma unroll
  for (int mm = 0; mm < 2; mm++) {
    const unsigned short* qp = Yq + base + (long)(qb + mm * 16 + l15) * 1024 + g8;
#pragma unroll
    for (int ks = 0; ks < 4; ks++) qf[mm][ks] = *(const bh8*)(qp + ks * 32);
  }

  f4 sc[2][4];
  __builtin_amdgcn_s_setprio(1);
#pragma unroll
  for (int ct = 0; ct < 4; ct++) {
    int r = w * 64 + ct * 16 + l15;
    const unsigned short* kp = Yk + base + (long)r * 1024 + g8;
    bh8 kf[4];
#pragma unroll
    for (int ks = 0; ks < 4; ks++) kf[ks] = *(const bh8*)(kp + ks * 32);
#pragma unroll
    for (int mm = 0; mm < 2; mm++) {
      f4 a = {};
#pragma unroll
      for (int ks = 0; ks < 4; ks++) a = mfma16(qf[mm][ks], kf[ks], a);
      sc[mm][ct] = a;
    }
  }
  __builtin_amdgcn_s_setprio(0);

#pragma unroll
  for (int mm = 0; mm < 2; mm++) {
#pragma unroll
    for (int j = 0; j < 4; j++) {
      int lr = mm * 16 + g * 4 + j;
      float s = 0.f;
#pragma unroll
      for (int ct = 0; ct < 4; ct++) {
        float p = exp2f(sc[mm][ct][j] * 0.12751745334f);
        sc[mm][ct][j] = p;
        s += p;
      }
      for (int d = 1; d < 16; d <<= 1) s += __shfl_xor(s, d, 64);
      if (l15 == 0) redbuf[w][lr] = s;
    }
  }
#pragma unroll
  for (int mm = 0; mm < 2; mm++)
#pragma unroll
    for (int ct = 0; ct < 4; ct++) {
      int col = w * 64 + ct * 16 + l15;
#pragma unroll
      for (int j = 0; j < 4; j++)
        buf[(mm * 16 + g * 4 + j) * 520 + col] = f2b(sc[mm][ct][j]);
    }
  __syncthreads();

  float rinv[2][4];
#pragma unroll
  for (int mm = 0; mm < 2; mm++)
#pragma unroll
    for (int j = 0; j < 4; j++) {
      int lr = mm * 16 + g * 4 + j;
      float s = 0.f;
#pragma unroll
      for (int ww = 0; ww < 8; ww++) s += redbuf[ww][lr];
      rinv[mm][j] = __builtin_amdgcn_rcpf(s);
    }

  f4 accO[2] = {};
  const unsigned short* vr = Yvt + ((long)(b * 4 + hg) * 128 + w * 16 + l15) * 512;
  __builtin_amdgcn_s_setprio(1);
#pragma unroll
  for (int ks = 0; ks < 16; ks++) {
    bh8 vb = *(const bh8*)(vr + ks * 32 + g8);
#pragma unroll
    for (int mm = 0; mm < 2; mm++) {
      union { uint2 u[2]; bh8 v; } pa;
      const unsigned short* pp = buf + (mm * 16 + l15) * 520 + ks * 32 + g8;
      pa.u[0] = *(const uint2*)(pp);
      pa.u[1] = *(const uint2*)(pp + 4);
      accO[mm] = mfma16(pa.v, vb, accO[mm]);
    }
  }
  __builtin_amdgcn_s_setprio(0);
#pragma unroll
  for (int mm = 0; mm < 2; mm++)
#pragma unroll
    for (int j = 0; j < 4; j++) {
      int row = qb + mm * 16 + g * 4 + j;
      outC[((long)(b * 512 + row)) * 1024 + 512 + hg * 128 + w * 16 + l15] = f2b(accO[mm][j] * rinv[mm][j]);
    }
}

// ============================ launch ============================
extern "C" void kernel_launch(void* const* d_in, const int* in_sizes, int n_in,
                              void* d_out, int out_size, void* d_ws, size_t ws_size,
                              hipStream_t stream) {
  const float* query = (const float*)d_in[0];
  const float* key   = (const float*)d_in[1];
  const float* value = (const float*)d_in[2];
  const float* wq = (const float*)d_in[3];   const float* bq = (const float*)d_in[4];
  const float* wk = (const float*)d_in[5];   const float* bk = (const float*)d_in[6];
  const float* wv = (const float*)d_in[7];   const float* bv = (const float*)d_in[8];
  const float* wo = (const float*)d_in[9];   const float* bo = (const float*)d_in[10];
  const float* rel_k = (const float*)d_in[11];
  const float* g_in_w = (const float*)d_in[12];  const float* g_in_b = (const float*)d_in[13];
  const float* g_out_w = (const float*)d_in[14]; const float* g_out_b = (const float*)d_in[15];

  unsigned short* p = (unsigned short*)d_ws;
  unsigned short* Xq = p;            p += 8388608;   // CAT spans Xq+Xk
  unsigned short* Xk = p;            p += 8388608;
  unsigned short* Xv = p;            p += 8388608;
  unsigned short* Yq = p;            p += 16777216;  // [16384][1024]
  unsigned short* Yk = p;            p += 16777216;
  unsigned short* Yvt_l = p;         p += 8388608;   // [b][h][64][512]
  unsigned short* Yvt_g = p;         p += 8388608;   // [b][hg][128][512]
  unsigned short* Wq = p;            p += 524288;
  unsigned short* Wk = p;            p += 524288;
  unsigned short* Wv = p;            p += 524288;
  unsigned short* Wo_ = p;           p += 262144;
  unsigned short* WgoT = p;          p += 262144;
  unsigned short* Bfin = p;          p += 524288;    // [512][1024]
  unsigned short* Rk = p;            p += 32832;
  float* bias2 = (float*)p;          p += 1024;
  unsigned short* CAT = Xq;                          // [16384][1024]

  prep_x_kern<<<8192, 256, 0, stream>>>(query, key, value, Xq, Xk, Xv);
  prep_w_kern<<<2339, 256, 0, stream>>>(wq, wk, wv, g_in_w, g_out_w, wo, rel_k,
                                        g_out_b, bo,
                                        Wq, Wk, Wv, Wo_, WgoT, Bfin, Rk, bias2);

  // all three projections + W2 in one launch (8 blocks/CU)
  gemm3_kern<<<3088, 256, 0, stream>>>(Xq, Xk, Xv, Wq, Wk, Wv, bq, bk, bv, g_in_b,
                                       Yq, Yk, Yvt_l, Yvt_g, Wo_, WgoT, Bfin);

  attn_local_kern<<<4096, 512, 0, stream>>>(Yq, Yk, Yvt_l, Rk, CAT);
  attn_glob_kern<<<2048, 512, 0, stream>>>(Yq, Yk, Yvt_g, CAT);

  // out = CAT @ Bfin^T + bias2
  gemm_fin_kern<<<512, 256, 0, stream>>>(CAT, Bfin, bias2, (float*)d_out);
}

// Round 11
// 342.357 us; speedup vs baseline: 1.0547x; 1.0082x over previous
//
#include <hip/hip_runtime.h>

typedef __attribute__((ext_vector_type(8))) short bh8;
typedef __attribute__((ext_vector_type(4))) float f4;

#define DEVI static __device__ __forceinline__

DEVI unsigned short f2b(float f) {
  union { float f; unsigned u; } v; v.f = f;
  unsigned r = v.u + 0x7fffu + ((v.u >> 16) & 1u);
  return (unsigned short)(r >> 16);
}
DEVI float b2f(unsigned short h) {
  union { unsigned u; float f; } v; v.u = ((unsigned)h) << 16;
  return v.f;
}
DEVI f4 mfma16(bh8 a, bh8 b, f4 c) {
  return __builtin_amdgcn_mfma_f32_16x16x32_bf16(a, b, c, 0, 0, 0);
}
DEVI void gload_lds16(const unsigned short* g, unsigned short* l) {
  __builtin_amdgcn_global_load_lds(
      (const __attribute__((address_space(1))) void*)(g),
      (__attribute__((address_space(3))) void*)(l), 16, 0, 0);
}

// ============================ prep kernels ============================
__global__ __launch_bounds__(256) void prep_x_kern(
    const float* __restrict__ q, const float* __restrict__ k, const float* __restrict__ v,
    unsigned short* __restrict__ xq, unsigned short* __restrict__ xk, unsigned short* __restrict__ xv) {
  long i = ((long)blockIdx.x * 256 + threadIdx.x) * 4;
  if (i >= 8388608L) return;
  float4 a = *(const float4*)(q + i);
  float4 b = *(const float4*)(k + i);
  float4 c = *(const float4*)(v + i);
  union { unsigned short s[4]; uint2 u; } pa, pb, pc;
  pa.s[0] = f2b(a.x); pa.s[1] = f2b(a.y); pa.s[2] = f2b(a.z); pa.s[3] = f2b(a.w);
  pb.s[0] = f2b(b.x); pb.s[1] = f2b(b.y); pb.s[2] = f2b(b.z); pb.s[3] = f2b(b.w);
  pc.s[0] = f2b(c.x); pc.s[1] = f2b(c.y); pc.s[2] = f2b(c.z); pc.s[3] = f2b(c.w);
  *(uint2*)(xq + i) = pa.u;
  *(uint2*)(xk + i) = pb.u;
  *(uint2*)(xv + i) = pc.u;
}

// weight repack + bias2 fold (blocks 2337-2338): bias2 = bo + 0.3*(Wo @ bgo)
__global__ __launch_bounds__(256) void prep_w_kern(
    const float* __restrict__ wq, const float* __restrict__ wk, const float* __restrict__ wv,
    const float* __restrict__ g_in_w, const float* __restrict__ g_out_w,
    const float* __restrict__ wo, const float* __restrict__ rel_k,
    const float* __restrict__ bgo, const float* __restrict__ bo,
    unsigned short* __restrict__ Wq, unsigned short* __restrict__ Wk, unsigned short* __restrict__ Wv,
    unsigned short* __restrict__ Wo_, unsigned short* __restrict__ WgoT,
    unsigned short* __restrict__ Bfin, unsigned short* __restrict__ Rk,
    float* __restrict__ bias2) {
  if (blockIdx.x >= 2337) {
    int o = (blockIdx.x - 2337) * 256 + threadIdx.x;
    if (o < 512) {
      const float* r = wo + (long)o * 512;
      float s = 0.f;
#pragma unroll 4
      for (int m = 0; m < 512; m += 4) {
        float4 a = *(const float4*)(r + m);
        float4 b = *(const float4*)(bgo + m);
        s += a.x * b.x + a.y * b.y + a.z * b.z + a.w * b.w;
      }
      bias2[o] = bo[o] + 0.3f * s;
    }
    return;
  }
  long i = ((long)blockIdx.x * 256 + threadIdx.x) * 4;
  if (i >= 2392128L) return;
  if (i >= 2097152L && i < 2359296L) {  // WgoT scatter
    long off = i - 2097152L;
    int ii = (int)(off >> 9), p = (int)(off & 511);
    union { unsigned short s[4]; uint2 u; } w;
#pragma unroll
    for (int tt = 0; tt < 4; tt++) w.s[tt] = f2b(g_out_w[(p + tt) * 512 + ii]);
    *(uint2*)(WgoT + off) = w.u;
    return;
  }
  const float* src; unsigned short* dst; long off; float sc = 1.0f;
  if (i < 524288L)        { dst = Wq;  off = i; src = (i < 262144L) ? wq + i : g_in_w + (i - 262144L); }
  else if (i < 1048576L)  { long j = i - 524288L;  dst = Wk;  off = j; src = (j < 262144L) ? wk + j : g_in_w + j; }
  else if (i < 1572864L)  { long j = i - 1048576L; dst = Wv;  off = j; src = (j < 262144L) ? wv + j : g_in_w + 262144L + j; }
  else if (i < 1835008L)  { long j = i - 1572864L; dst = Wo_; off = j; src = wo + j; }
  else if (i < 2097152L)  { long j = i - 1835008L; int col = (int)(j >> 9), k = (int)(j & 511);
                            dst = Bfin; off = (long)col * 1024 + k; src = wo + j; sc = 0.7f; }
  else                    { long j = i - 2359296L; dst = Rk;  off = j; src = rel_k + j; }
  float4 f = *(const float4*)src;
  union { unsigned short s[4]; uint2 u; } p;
  p.s[0] = f2b(f.x * sc); p.s[1] = f2b(f.y * sc); p.s[2] = f2b(f.z * sc); p.s[3] = f2b(f.w * sc);
  *(uint2*)(dst + off) = p.u;
}

// ============================ merged projection GEMM ============================
// Blocks [0,1024) Q-proj, [1024,2048) K-proj, [2048,3072) V-proj, [3072,3088) W2.
// 2-barrier core + chunk-XOR LDS swizzle (R3-proven): slot chunk c at LDS row r
// holds global k-chunk c^((r>>1)&3); read chunk g^((l15>>1)&3) -> 2-way banks.
__global__ __launch_bounds__(256) void gemm3_kern(
    const unsigned short* __restrict__ Xq, const unsigned short* __restrict__ Xk,
    const unsigned short* __restrict__ Xv,
    const unsigned short* __restrict__ Wq, const unsigned short* __restrict__ Wk,
    const unsigned short* __restrict__ Wv,
    const float* __restrict__ bq, const float* __restrict__ bk, const float* __restrict__ bv,
    const float* __restrict__ g_in_b,
    unsigned short* __restrict__ Yq, unsigned short* __restrict__ Yk_,
    unsigned short* __restrict__ Yvt_l, unsigned short* __restrict__ Yvt_g,
    const unsigned short* __restrict__ Wo_, const unsigned short* __restrict__ WgoT,
    unsigned short* __restrict__ Bfin) {
  __shared__ unsigned short lsA[128 * 32];
  __shared__ unsigned short lsB[128 * 32];
  const int t = threadIdx.x;
  const int lane = t & 63, w = t >> 6;
  const int l15 = lane & 15, g = lane >> 4, g4 = g * 4;
  const int gs8 = (g ^ ((l15 >> 1) & 3)) * 8;   // swizzled read chunk
  const int n = blockIdx.x;

  const unsigned short *Ap, *Bp;
  const float *b0 = nullptr, *b1 = nullptr;
  int seg, rb, cb;
  if (n < 3072) {
    seg = n >> 10;
    int m = n & 1023;
    int x = m >> 3, c = m & 7;
    rb = (c * 16 + (x & 15)) * 128;
    cb = (x >> 4) * 128;
    Ap = (seg == 0) ? Xq : (seg == 1) ? Xk : Xv;
    Bp = (seg == 0) ? Wq : (seg == 1) ? Wk : Wv;
    b0 = (seg == 0) ? bq : (seg == 1) ? bk : bv;
    b1 = g_in_b + seg * 512;
  } else {
    seg = 3;
    int m2 = n - 3072;
    rb = (m2 & 3) * 128; cb = (m2 >> 2) * 128;
    Ap = Wo_; Bp = WgoT;
  }

  const int wr = (w >> 1) * 64, wc = (w & 1) * 64;
  // staging: thread t -> LDS slots t*8 and 2048+t*8 (rows t>>2 and 64+(t>>2));
  // both rows share swizzle key (t>>3)&3.
  const int r0 = t >> 2, r1 = 64 + (t >> 2);
  const int k0i = ((t & 3) ^ ((t >> 3) & 3)) * 8;

  const unsigned short* pa0 = Ap + (long)(rb + r0) * 512 + k0i;
  const unsigned short* pa1 = Ap + (long)(rb + r1) * 512 + k0i;
  const unsigned short* pb0 = Bp + (long)(cb + r0) * 512 + k0i;
  const unsigned short* pb1 = Bp + (long)(cb + r1) * 512 + k0i;
  unsigned short* dA0 = lsA + w * 512;
  unsigned short* dA1 = lsA + 2048 + w * 512;
  unsigned short* dB0 = lsB + w * 512;
  unsigned short* dB1 = lsB + 2048 + w * 512;

  f4 acc[4][4] = {};
  for (int k0 = 0; k0 < 512; k0 += 32) {
    __syncthreads();
    gload_lds16(pa0 + k0, dA0);
    gload_lds16(pa1 + k0, dA1);
    gload_lds16(pb0 + k0, dB0);
    gload_lds16(pb1 + k0, dB1);
    __syncthreads();
    bh8 af[4], bf[4];
#pragma unroll
    for (int m = 0; m < 4; m++) af[m] = *(const bh8*)(lsA + (wr + m * 16 + l15) * 32 + gs8);
#pragma unroll
    for (int nn = 0; nn < 4; nn++) bf[nn] = *(const bh8*)(lsB + (wc + nn * 16 + l15) * 32 + gs8);
    __builtin_amdgcn_s_setprio(1);
#pragma unroll
    for (int m = 0; m < 4; m++)
#pragma unroll
      for (int nn = 0; nn < 4; nn++)
        acc[m][nn] = mfma16(af[m], bf[nn], acc[m][nn]);
    __builtin_amdgcn_s_setprio(0);
  }

  if (seg == 3) {   // W2 -> Bfin cols 512+
#pragma unroll
    for (int m = 0; m < 4; m++)
#pragma unroll
      for (int nn = 0; nn < 4; nn++)
#pragma unroll
        for (int j = 0; j < 4; j++) {
          int row = rb + wr + m * 16 + g4 + j;
          int col = cb + wc + nn * 16 + l15;
          Bfin[(long)row * 1024 + 512 + col] = f2b(0.3f * acc[m][nn][j]);
        }
    return;
  }
  if (seg == 2) {   // V-proj: transposed-per-head, uint2-packed
#pragma unroll
    for (int m = 0; m < 4; m++)
#pragma unroll
      for (int nn = 0; nn < 4; nn++) {
        int col = cb + wc + nn * 16 + l15;
        float bsv = (col < 512) ? b0[col] : b1[col - 512];
        unsigned r[4];
#pragma unroll
        for (int j = 0; j < 4; j++) {
          union { float f; unsigned u; } v; v.f = acc[m][nn][j] + bsv;
          r[j] = v.u + 0x7fffu + ((v.u >> 16) & 1u);
        }
        unsigned lo = (r[0] >> 16) | (r[1] & 0xffff0000u);
        unsigned hi = (r[2] >> 16) | (r[3] & 0xffff0000u);
        int row0 = rb + wr + m * 16 + g4;
        int bb = row0 >> 9, s = row0 & 511;
        if (col < 512) {
          int hh = col >> 6, d = col & 63;
          *(uint2*)(Yvt_l + (((long)(bb * 8 + hh) * 64 + d) << 9) + s) = make_uint2(lo, hi);
        } else {
          int c2 = col - 512, hg = c2 >> 7, dg = c2 & 127;
          *(uint2*)(Yvt_g + (((long)(bb * 4 + hg) * 128 + dg) << 9) + s) = make_uint2(lo, hi);
        }
      }
    return;
  }
  unsigned short* Yo = (seg == 0) ? Yq : Yk_;
#pragma unroll
  for (int m = 0; m < 4; m++)
#pragma unroll
    for (int nn = 0; nn < 4; nn++)
#pragma unroll
      for (int j = 0; j < 4; j++) {
        int row = rb + wr + m * 16 + g4 + j;
        int col = cb + wc + nn * 16 + l15;
        float v = acc[m][nn][j] + ((col < 512) ? b0[col] : b1[col - 512]);
        Yo[(long)row * 1024 + col] = f2b(v);
      }
}

// ============================ final GEMM (2-barrier + swizzle) ============================
// out = CAT[16384][1024] @ Bfin[512][1024]^T + bias2 -> f32
__global__ __launch_bounds__(256) void gemm_fin_kern(
    const unsigned short* __restrict__ A, const unsigned short* __restrict__ Bw,
    const float* __restrict__ bias0, float* __restrict__ outf) {
  __shared__ unsigned short lsA[128 * 32];
  __shared__ unsigned short lsB[128 * 32];
  const int t = threadIdx.x;
  const int lane = t & 63, w = t >> 6;
  const int l15 = lane & 15, g = lane >> 4, g4 = g * 4;
  const int gs8 = (g ^ ((l15 >> 1) & 3)) * 8;
  int n = blockIdx.x;
  int x = n >> 3, c = n & 7;
  const int rb = (c * 16 + (x & 15)) * 128;
  const int cb = (x >> 4) * 128;
  const int wr = (w >> 1) * 64, wc = (w & 1) * 64;
  const int r0 = t >> 2, r1 = 64 + (t >> 2);
  const int k0i = ((t & 3) ^ ((t >> 3) & 3)) * 8;

  const unsigned short* pa0 = A + (long)(rb + r0) * 1024 + k0i;
  const unsigned short* pa1 = A + (long)(rb + r1) * 1024 + k0i;
  const unsigned short* pb0 = Bw + (long)(cb + r0) * 1024 + k0i;
  const unsigned short* pb1 = Bw + (long)(cb + r1) * 1024 + k0i;
  unsigned short* dA0 = lsA + w * 512;
  unsigned short* dA1 = lsA + 2048 + w * 512;
  unsigned short* dB0 = lsB + w * 512;
  unsigned short* dB1 = lsB + 2048 + w * 512;

  f4 acc[4][4] = {};
  for (int k0 = 0; k0 < 1024; k0 += 32) {
    __syncthreads();
    gload_lds16(pa0 + k0, dA0);
    gload_lds16(pa1 + k0, dA1);
    gload_lds16(pb0 + k0, dB0);
    gload_lds16(pb1 + k0, dB1);
    __syncthreads();
    bh8 af[4], bf[4];
#pragma unroll
    for (int m = 0; m < 4; m++) af[m] = *(const bh8*)(lsA + (wr + m * 16 + l15) * 32 + gs8);
#pragma unroll
    for (int nn = 0; nn < 4; nn++) bf[nn] = *(const bh8*)(lsB + (wc + nn * 16 + l15) * 32 + gs8);
    __builtin_amdgcn_s_setprio(1);
#pragma unroll
    for (int m = 0; m < 4; m++)
#pragma unroll
      for (int nn = 0; nn < 4; nn++)
        acc[m][nn] = mfma16(af[m], bf[nn], acc[m][nn]);
    __builtin_amdgcn_s_setprio(0);
  }
#pragma unroll
  for (int m = 0; m < 4; m++)
#pragma unroll
    for (int nn = 0; nn < 4; nn++)
#pragma unroll
      for (int j = 0; j < 4; j++) {
        int row = rb + wr + m * 16 + g4 + j;
        int col = cb + wc + nn * 16 + l15;
        outf[(long)row * 512 + col] = acc[m][nn][j] + bias0[col];
      }
}

// ============================ local attention v6 (R7, proven) ============================
__global__ __launch_bounds__(512, 4) void attn_local_kern(
    const unsigned short* __restrict__ Yq, const unsigned short* __restrict__ Yk,
    const unsigned short* __restrict__ Yvt, const unsigned short* __restrict__ relk,
    unsigned short* __restrict__ outC) {
  __shared__ unsigned short kv[2][8192];
  __shared__ unsigned short buf[32 * 524];
  __shared__ float redbuf[8][32];

  const int t = threadIdx.x, lane = t & 63, w = t >> 6;
  const int l15 = lane & 15, g = lane >> 4, g8 = g * 8;
  int n = blockIdx.x;
  int bid = (n & 7) * 512 + (n >> 3);
  const int qt = bid & 15;
  const int h = (bid >> 4) & 7;
  const int b = bid >> 7;
  const int qb = qt * 32;
  const long base = ((long)(b * 512)) * 1024 + h * 64;
  const long vbase = ((long)(b * 8 + h)) * 64 * 512;

#define STAGE_K(ROFF, BUF) { \
    const int c_ = t & 7; \
    _Pragma("unroll") \
    for (int it = 0; it < 2; it++) { \
      int rr = it * 64 + (t >> 3); \
      gload_lds16(Yk + base + (long)((ROFF) + rr) * 1024 + ((c_ ^ (rr & 7)) * 8), \
                  kv[BUF] + it * 4096 + w * 512); \
    } }
#define STAGE_V(COFF, BUF) { \
    const int c_ = t & 15; \
    _Pragma("unroll") \
    for (int it = 0; it < 2; it++) { \
      int dd_ = it * 32 + (t >> 4); \
      gload_lds16(Yvt + vbase + (long)dd_ * 512 + (COFF) + ((c_ ^ (dd_ & 15)) * 8), \
                  kv[BUF] + it * 4096 + w * 512); \
    } }
#define QK(CH) { \
    int rl = w * 16 + l15; \
    const unsigned short* kb_ = kv[(CH) & 1]; \
    bh8 k0 = *(const bh8*)(kb_ + rl * 64 + ((g ^ (rl & 7)) * 8)); \
    bh8 k1 = *(const bh8*)(kb_ + rl * 64 + (((g + 4) ^ (rl & 7)) * 8)); \
    _Pragma("unroll") \
    for (int mm = 0; mm < 2; mm++) { \
      f4 a = {}; \
      a = mfma16(qf[mm][0], k0, a); \
      a = mfma16(qf[mm][1], k1, a); \
      sc[mm][CH] = a; \
    } }
#define GATHER(CH) { \
    _Pragma("unroll") \
    for (int mm = 0; mm < 2; mm++) \
    _Pragma("unroll") \
    for (int j = 0; j < 4; j++) { \
      int lr = mm * 16 + g * 4 + j; \
      int rowb = lr * 524; \
      int idx = rowb + 256 - (qb + lr) + (CH) * 128 + w * 16 + l15; \
      idx = idx < rowb ? rowb : idx; \
      idx = idx > rowb + 512 ? rowb + 512 : idx; \
      float p = exp2f(fmaf(sc[mm][CH][j], 0.18033688011112042f, b2f(buf[idx]))); \
      sc[mm][CH][j] = p; \
      rs[mm][j] += p; \
    } }

  STAGE_K(0, 0);

  bh8 qf[2][2];
#pragma unroll
  for (int mm = 0; mm < 2; mm++) {
    const unsigned short* qp = Yq + base + (long)(qb + mm * 16 + l15) * 1024 + g8;
    qf[mm][0] = *(const bh8*)(qp);
    qf[mm][1] = *(const bh8*)(qp + 32);
  }

  for (int tt = w; tt < 33; tt += 8) {
    int ri = tt * 16 + l15; if (ri > 512) ri = 512;
    const unsigned short* rp = relk + ri * 64 + g8;
    bh8 rf0 = *(const bh8*)(rp), rf1 = *(const bh8*)(rp + 32);
    int col = tt * 16 + l15;
#pragma unroll
    for (int mm = 0; mm < 2; mm++) {
      f4 a = {};
      a = mfma16(qf[mm][0], rf0, a);
      a = mfma16(qf[mm][1], rf1, a);
      if (col < 524) {
#pragma unroll
        for (int j = 0; j < 4; j++)
          buf[(mm * 16 + g * 4 + j) * 524 + col] = f2b(a[j] * 1.4426950408889634f);
      }
    }
  }
  __syncthreads();

  f4 sc[2][4];
  float rs[2][4] = {};

#pragma unroll
  for (int c = 0; c < 4; c++) {
    if (c < 3) { STAGE_K((c + 1) * 128, (c + 1) & 1); }
    else       { STAGE_V(0, 0); }
    __builtin_amdgcn_s_setprio(1);
    QK(c);
    __builtin_amdgcn_s_setprio(0);
    GATHER(c);
    __syncthreads();
  }

#pragma unroll
  for (int mm = 0; mm < 2; mm++)
#pragma unroll
    for (int j = 0; j < 4; j++) {
      int lr = mm * 16 + g * 4 + j;
      float s = rs[mm][j];
      for (int d = 1; d < 16; d <<= 1) s += __shfl_xor(s, d, 64);
      if (l15 == 0) redbuf[w][lr] = s;
    }
#pragma unroll
  for (int mm = 0; mm < 2; mm++)
#pragma unroll
    for (int ch = 0; ch < 4; ch++) {
      int col = ch * 128 + w * 16 + l15;
#pragma unroll
      for (int j = 0; j < 4; j++)
        buf[(mm * 16 + g * 4 + j) * 524 + col] = f2b(sc[mm][ch][j]);
    }
  __syncthreads();

  const int mmw = w >> 2, dt = w & 3;
  const int dd = dt * 16 + l15;
  float rinvj[4];
#pragma unroll
  for (int j = 0; j < 4; j++) {
    int lr = mmw * 16 + g * 4 + j;
    float s = 0.f;
#pragma unroll
    for (int ww = 0; ww < 8; ww++) s += redbuf[ww][lr];
    rinvj[j] = __builtin_amdgcn_rcpf(s);
  }

  f4 accO = {};
#pragma unroll
  for (int d = 0; d < 4; d++) {
    if (d < 3) { STAGE_V((d + 1) * 128, (d + 1) & 1); }
    const unsigned short* vb_ = kv[d & 1];
    __builtin_amdgcn_s_setprio(1);
#pragma unroll
    for (int ks2 = 0; ks2 < 4; ks2++) {
      union { uint2 u[2]; bh8 v; } pa;
      const unsigned short* pp = buf + (mmw * 16 + l15) * 524 + (d * 4 + ks2) * 32 + g8;
      pa.u[0] = *(const uint2*)(pp);
      pa.u[1] = *(const uint2*)(pp + 4);
      bh8 vv = *(const bh8*)(vb_ + dd * 128 + (((ks2 * 4 + g) ^ (dd & 15)) * 8));
      accO = mfma16(pa.v, vv, accO);
    }
    __builtin_amdgcn_s_setprio(0);
    if (d < 3) __syncthreads();
  }
#pragma unroll
  for (int j = 0; j < 4; j++) {
    int row = qb + mmw * 16 + g * 4 + j;
    outC[((long)(b * 512 + row)) * 1024 + h * 64 + dt * 16 + l15] = f2b(accO[j] * rinvj[j]);
  }
#undef STAGE_K
#undef STAGE_V
#undef QK
#undef GATHER
}

// ============================ global attention v2 (R7, proven) ============================
__global__ __launch_bounds__(512) void attn_glob_kern(
    const unsigned short* __restrict__ Yq, const unsigned short* __restrict__ Yk,
    const unsigned short* __restrict__ Yvt, unsigned short* __restrict__ outC) {
  __shared__ unsigned short buf[32 * 520];
  __shared__ float redbuf[8][32];

  const int t = threadIdx.x, lane = t & 63, w = t >> 6;
  const int l15 = lane & 15, g = lane >> 4, g8 = g * 8;
  int n = blockIdx.x;
  int bid = (n & 7) * 256 + (n >> 3);
  const int qt = bid & 15;
  const int hg = (bid >> 4) & 3;
  const int b = bid >> 6;
  const int qb = qt * 32;
  const long base = ((long)(b * 512)) * 1024 + 512 + hg * 128;

  bh8 qf[2][4];
#pragma unroll
  for (int mm = 0; mm < 2; mm++) {
    const unsigned short* qp = Yq + base + (long)(qb + mm * 16 + l15) * 1024 + g8;
#pragma unroll
    for (int ks = 0; ks < 4; ks++) qf[mm][ks] = *(const bh8*)(qp + ks * 32);
  }

  f4 sc[2][4];
  __builtin_amdgcn_s_setprio(1);
#pragma unroll
  for (int ct = 0; ct < 4; ct++) {
    int r = w * 64 + ct * 16 + l15;
    const unsigned short* kp = Yk + base + (long)r * 1024 + g8;
    bh8 kf[4];
#pragma unroll
    for (int ks = 0; ks < 4; ks++) kf[ks] = *(const bh8*)(kp + ks * 32);
#pragma unroll
    for (int mm = 0; mm < 2; mm++) {
      f4 a = {};
#pragma unroll
      for (int ks = 0; ks < 4; ks++) a = mfma16(qf[mm][ks], kf[ks], a);
      sc[mm][ct] = a;
    }
  }
  __builtin_amdgcn_s_setprio(0);

#pragma unroll
  for (int mm = 0; mm < 2; mm++) {
#pragma unroll
    for (int j = 0; j < 4; j++) {
      int lr = mm * 16 + g * 4 + j;
      float s = 0.f;
#pragma unroll
      for (int ct = 0; ct < 4; ct++) {
        float p = exp2f(sc[mm][ct][j] * 0.12751745334f);
        sc[mm][ct][j] = p;
        s += p;
      }
      for (int d = 1; d < 16; d <<= 1) s += __shfl_xor(s, d, 64);
      if (l15 == 0) redbuf[w][lr] = s;
    }
  }
#pragma unroll
  for (int mm = 0; mm < 2; mm++)
#pragma unroll
    for (int ct = 0; ct < 4; ct++) {
      int col = w * 64 + ct * 16 + l15;
#pragma unroll
      for (int j = 0; j < 4; j++)
        buf[(mm * 16 + g * 4 + j) * 520 + col] = f2b(sc[mm][ct][j]);
    }
  __syncthreads();

  float rinv[2][4];
#pragma unroll
  for (int mm = 0; mm < 2; mm++)
#pragma unroll
    for (int j = 0; j < 4; j++) {
      int lr = mm * 16 + g * 4 + j;
      float s = 0.f;
#pragma unroll
      for (int ww = 0; ww < 8; ww++) s += redbuf[ww][lr];
      rinv[mm][j] = __builtin_amdgcn_rcpf(s);
    }

  f4 accO[2] = {};
  const unsigned short* vr = Yvt + ((long)(b * 4 + hg) * 128 + w * 16 + l15) * 512;
  __builtin_amdgcn_s_setprio(1);
#pragma unroll
  for (int ks = 0; ks < 16; ks++) {
    bh8 vb = *(const bh8*)(vr + ks * 32 + g8);
#pragma unroll
    for (int mm = 0; mm < 2; mm++) {
      union { uint2 u[2]; bh8 v; } pa;
      const unsigned short* pp = buf + (mm * 16 + l15) * 520 + ks * 32 + g8;
      pa.u[0] = *(const uint2*)(pp);
      pa.u[1] = *(const uint2*)(pp + 4);
      accO[mm] = mfma16(pa.v, vb, accO[mm]);
    }
  }
  __builtin_amdgcn_s_setprio(0);
#pragma unroll
  for (int mm = 0; mm < 2; mm++)
#pragma unroll
    for (int j = 0; j < 4; j++) {
      int row = qb + mm * 16 + g * 4 + j;
      outC[((long)(b * 512 + row)) * 1024 + 512 + hg * 128 + w * 16 + l15] = f2b(accO[mm][j] * rinv[mm][j]);
    }
}

// ============================ launch ============================
extern "C" void kernel_launch(void* const* d_in, const int* in_sizes, int n_in,
                              void* d_out, int out_size, void* d_ws, size_t ws_size,
                              hipStream_t stream) {
  const float* query = (const float*)d_in[0];
  const float* key   = (const float*)d_in[1];
  const float* value = (const float*)d_in[2];
  const float* wq = (const float*)d_in[3];   const float* bq = (const float*)d_in[4];
  const float* wk = (const float*)d_in[5];   const float* bk = (const float*)d_in[6];
  const float* wv = (const float*)d_in[7];   const float* bv = (const float*)d_in[8];
  const float* wo = (const float*)d_in[9];   const float* bo = (const float*)d_in[10];
  const float* rel_k = (const float*)d_in[11];
  const float* g_in_w = (const float*)d_in[12];  const float* g_in_b = (const float*)d_in[13];
  const float* g_out_w = (const float*)d_in[14]; const float* g_out_b = (const float*)d_in[15];

  unsigned short* p = (unsigned short*)d_ws;
  unsigned short* Xq = p;            p += 8388608;   // CAT spans Xq+Xk
  unsigned short* Xk = p;            p += 8388608;
  unsigned short* Xv = p;            p += 8388608;
  unsigned short* Yq = p;            p += 16777216;  // [16384][1024]
  unsigned short* Yk = p;            p += 16777216;
  unsigned short* Yvt_l = p;         p += 8388608;   // [b][h][64][512]
  unsigned short* Yvt_g = p;         p += 8388608;   // [b][hg][128][512]
  unsigned short* Wq = p;            p += 524288;
  unsigned short* Wk = p;            p += 524288;
  unsigned short* Wv = p;            p += 524288;
  unsigned short* Wo_ = p;           p += 262144;
  unsigned short* WgoT = p;          p += 262144;
  unsigned short* Bfin = p;          p += 524288;    // [512][1024]
  unsigned short* Rk = p;            p += 32832;
  float* bias2 = (float*)p;          p += 1024;
  unsigned short* CAT = Xq;                          // [16384][1024]

  prep_x_kern<<<8192, 256, 0, stream>>>(query, key, value, Xq, Xk, Xv);
  prep_w_kern<<<2339, 256, 0, stream>>>(wq, wk, wv, g_in_w, g_out_w, wo, rel_k,
                                        g_out_b, bo,
                                        Wq, Wk, Wv, Wo_, WgoT, Bfin, Rk, bias2);

  gemm3_kern<<<3088, 256, 0, stream>>>(Xq, Xk, Xv, Wq, Wk, Wv, bq, bk, bv, g_in_b,
                                       Yq, Yk, Yvt_l, Yvt_g, Wo_, WgoT, Bfin);

  attn_local_kern<<<4096, 512, 0, stream>>>(Yq, Yk, Yvt_l, Rk, CAT);
  attn_glob_kern<<<2048, 512, 0, stream>>>(Yq, Yk, Yvt_g, CAT);

  gemm_fin_kern<<<512, 256, 0, stream>>>(CAT, Bfin, bias2, (float*)d_out);
}

// Round 12
// 341.197 us; speedup vs baseline: 1.0583x; 1.0034x over previous
//
#include <hip/hip_runtime.h>

typedef __attribute__((ext_vector_type(8))) short bh8;
typedef __attribute__((ext_vector_type(4))) float f4;

#define DEVI static __device__ __forceinline__

DEVI unsigned short f2b(float f) {
  union { float f; unsigned u; } v; v.f = f;
  unsigned r = v.u + 0x7fffu + ((v.u >> 16) & 1u);
  return (unsigned short)(r >> 16);
}
DEVI float b2f(unsigned short h) {
  union { unsigned u; float f; } v; v.u = ((unsigned)h) << 16;
  return v.f;
}
DEVI f4 mfma16(bh8 a, bh8 b, f4 c) {
  return __builtin_amdgcn_mfma_f32_16x16x32_bf16(a, b, c, 0, 0, 0);
}
DEVI void gload_lds16(const unsigned short* g, unsigned short* l) {
  __builtin_amdgcn_global_load_lds(
      (const __attribute__((address_space(1))) void*)(g),
      (__attribute__((address_space(3))) void*)(l), 16, 0, 0);
}

// ============================ merged prep ============================
// [0,8192): x->bf16 convert; [8192,10529): weight repack; [10529,10531): bias2.
__global__ __launch_bounds__(256) void prep_all_kern(
    const float* __restrict__ q, const float* __restrict__ k, const float* __restrict__ v,
    const float* __restrict__ wq, const float* __restrict__ wk, const float* __restrict__ wv,
    const float* __restrict__ g_in_w, const float* __restrict__ g_out_w,
    const float* __restrict__ wo, const float* __restrict__ rel_k,
    const float* __restrict__ bgo, const float* __restrict__ bo,
    unsigned short* __restrict__ xq, unsigned short* __restrict__ xk, unsigned short* __restrict__ xv,
    unsigned short* __restrict__ Wq, unsigned short* __restrict__ Wk, unsigned short* __restrict__ Wv,
    unsigned short* __restrict__ Wo_, unsigned short* __restrict__ WgoT,
    unsigned short* __restrict__ Bfin, unsigned short* __restrict__ Rk,
    float* __restrict__ bias2) {
  if (blockIdx.x < 8192) {
    long i = ((long)blockIdx.x * 256 + threadIdx.x) * 4;
    float4 a = *(const float4*)(q + i);
    float4 b = *(const float4*)(k + i);
    float4 c = *(const float4*)(v + i);
    union { unsigned short s[4]; uint2 u; } pa, pb, pc;
    pa.s[0] = f2b(a.x); pa.s[1] = f2b(a.y); pa.s[2] = f2b(a.z); pa.s[3] = f2b(a.w);
    pb.s[0] = f2b(b.x); pb.s[1] = f2b(b.y); pb.s[2] = f2b(b.z); pb.s[3] = f2b(b.w);
    pc.s[0] = f2b(c.x); pc.s[1] = f2b(c.y); pc.s[2] = f2b(c.z); pc.s[3] = f2b(c.w);
    *(uint2*)(xq + i) = pa.u;
    *(uint2*)(xk + i) = pb.u;
    *(uint2*)(xv + i) = pc.u;
    return;
  }
  int bw = blockIdx.x - 8192;
  if (bw >= 2337) {
    int o = (bw - 2337) * 256 + threadIdx.x;
    if (o < 512) {
      const float* r = wo + (long)o * 512;
      float s = 0.f;
#pragma unroll 4
      for (int m = 0; m < 512; m += 4) {
        float4 a = *(const float4*)(r + m);
        float4 b = *(const float4*)(bgo + m);
        s += a.x * b.x + a.y * b.y + a.z * b.z + a.w * b.w;
      }
      bias2[o] = bo[o] + 0.3f * s;
    }
    return;
  }
  long i = ((long)bw * 256 + threadIdx.x) * 4;
  if (i >= 2392128L) return;
  if (i >= 2097152L && i < 2359296L) {  // WgoT scatter
    long off = i - 2097152L;
    int ii = (int)(off >> 9), p = (int)(off & 511);
    union { unsigned short s[4]; uint2 u; } w;
#pragma unroll
    for (int tt = 0; tt < 4; tt++) w.s[tt] = f2b(g_out_w[(p + tt) * 512 + ii]);
    *(uint2*)(WgoT + off) = w.u;
    return;
  }
  const float* src; unsigned short* dst; long off; float sc = 1.0f;
  if (i < 524288L)        { dst = Wq;  off = i; src = (i < 262144L) ? wq + i : g_in_w + (i - 262144L); }
  else if (i < 1048576L)  { long j = i - 524288L;  dst = Wk;  off = j; src = (j < 262144L) ? wk + j : g_in_w + j; }
  else if (i < 1572864L)  { long j = i - 1048576L; dst = Wv;  off = j; src = (j < 262144L) ? wv + j : g_in_w + 262144L + j; }
  else if (i < 1835008L)  { long j = i - 1572864L; dst = Wo_; off = j; src = wo + j; }
  else if (i < 2097152L)  { long j = i - 1835008L; int col = (int)(j >> 9), kk = (int)(j & 511);
                            dst = Bfin; off = (long)col * 1024 + kk; src = wo + j; sc = 0.7f; }
  else                    { long j = i - 2359296L; dst = Rk;  off = j; src = rel_k + j; }
  float4 f = *(const float4*)src;
  union { unsigned short s[4]; uint2 u; } p;
  p.s[0] = f2b(f.x * sc); p.s[1] = f2b(f.y * sc); p.s[2] = f2b(f.z * sc); p.s[3] = f2b(f.w * sc);
  *(uint2*)(dst + off) = p.u;
}

// ============================ merged projection GEMM (R11 proven) ============================
__global__ __launch_bounds__(256) void gemm3_kern(
    const unsigned short* __restrict__ Xq, const unsigned short* __restrict__ Xk,
    const unsigned short* __restrict__ Xv,
    const unsigned short* __restrict__ Wq, const unsigned short* __restrict__ Wk,
    const unsigned short* __restrict__ Wv,
    const float* __restrict__ bq, const float* __restrict__ bk, const float* __restrict__ bv,
    const float* __restrict__ g_in_b,
    unsigned short* __restrict__ Yq, unsigned short* __restrict__ Yk_,
    unsigned short* __restrict__ Yvt_l, unsigned short* __restrict__ Yvt_g,
    const unsigned short* __restrict__ Wo_, const unsigned short* __restrict__ WgoT,
    unsigned short* __restrict__ Bfin) {
  __shared__ unsigned short lsA[128 * 32];
  __shared__ unsigned short lsB[128 * 32];
  const int t = threadIdx.x;
  const int lane = t & 63, w = t >> 6;
  const int l15 = lane & 15, g = lane >> 4, g4 = g * 4;
  const int gs8 = (g ^ ((l15 >> 1) & 3)) * 8;
  const int n = blockIdx.x;

  const unsigned short *Ap, *Bp;
  const float *b0 = nullptr, *b1 = nullptr;
  int seg, rb, cb;
  if (n < 3072) {
    seg = n >> 10;
    int m = n & 1023;
    int x = m >> 3, c = m & 7;
    rb = (c * 16 + (x & 15)) * 128;
    cb = (x >> 4) * 128;
    Ap = (seg == 0) ? Xq : (seg == 1) ? Xk : Xv;
    Bp = (seg == 0) ? Wq : (seg == 1) ? Wk : Wv;
    b0 = (seg == 0) ? bq : (seg == 1) ? bk : bv;
    b1 = g_in_b + seg * 512;
  } else {
    seg = 3;
    int m2 = n - 3072;
    rb = (m2 & 3) * 128; cb = (m2 >> 2) * 128;
    Ap = Wo_; Bp = WgoT;
  }

  const int wr = (w >> 1) * 64, wc = (w & 1) * 64;
  const int r0 = t >> 2, r1 = 64 + (t >> 2);
  const int k0i = ((t & 3) ^ ((t >> 3) & 3)) * 8;

  const unsigned short* pa0 = Ap + (long)(rb + r0) * 512 + k0i;
  const unsigned short* pa1 = Ap + (long)(rb + r1) * 512 + k0i;
  const unsigned short* pb0 = Bp + (long)(cb + r0) * 512 + k0i;
  const unsigned short* pb1 = Bp + (long)(cb + r1) * 512 + k0i;
  unsigned short* dA0 = lsA + w * 512;
  unsigned short* dA1 = lsA + 2048 + w * 512;
  unsigned short* dB0 = lsB + w * 512;
  unsigned short* dB1 = lsB + 2048 + w * 512;

  f4 acc[4][4] = {};
  for (int k0 = 0; k0 < 512; k0 += 32) {
    __syncthreads();
    gload_lds16(pa0 + k0, dA0);
    gload_lds16(pa1 + k0, dA1);
    gload_lds16(pb0 + k0, dB0);
    gload_lds16(pb1 + k0, dB1);
    __syncthreads();
    bh8 af[4], bf[4];
#pragma unroll
    for (int m = 0; m < 4; m++) af[m] = *(const bh8*)(lsA + (wr + m * 16 + l15) * 32 + gs8);
#pragma unroll
    for (int nn = 0; nn < 4; nn++) bf[nn] = *(const bh8*)(lsB + (wc + nn * 16 + l15) * 32 + gs8);
    __builtin_amdgcn_s_setprio(1);
#pragma unroll
    for (int m = 0; m < 4; m++)
#pragma unroll
      for (int nn = 0; nn < 4; nn++)
        acc[m][nn] = mfma16(af[m], bf[nn], acc[m][nn]);
    __builtin_amdgcn_s_setprio(0);
  }

  if (seg == 3) {
#pragma unroll
    for (int m = 0; m < 4; m++)
#pragma unroll
      for (int nn = 0; nn < 4; nn++)
#pragma unroll
        for (int j = 0; j < 4; j++) {
          int row = rb + wr + m * 16 + g4 + j;
          int col = cb + wc + nn * 16 + l15;
          Bfin[(long)row * 1024 + 512 + col] = f2b(0.3f * acc[m][nn][j]);
        }
    return;
  }
  if (seg == 2) {
#pragma unroll
    for (int m = 0; m < 4; m++)
#pragma unroll
      for (int nn = 0; nn < 4; nn++) {
        int col = cb + wc + nn * 16 + l15;
        float bsv = (col < 512) ? b0[col] : b1[col - 512];
        unsigned r[4];
#pragma unroll
        for (int j = 0; j < 4; j++) {
          union { float f; unsigned u; } v; v.f = acc[m][nn][j] + bsv;
          r[j] = v.u + 0x7fffu + ((v.u >> 16) & 1u);
        }
        unsigned lo = (r[0] >> 16) | (r[1] & 0xffff0000u);
        unsigned hi = (r[2] >> 16) | (r[3] & 0xffff0000u);
        int row0 = rb + wr + m * 16 + g4;
        int bb = row0 >> 9, s = row0 & 511;
        if (col < 512) {
          int hh = col >> 6, d = col & 63;
          *(uint2*)(Yvt_l + (((long)(bb * 8 + hh) * 64 + d) << 9) + s) = make_uint2(lo, hi);
        } else {
          int c2 = col - 512, hg = c2 >> 7, dg = c2 & 127;
          *(uint2*)(Yvt_g + (((long)(bb * 4 + hg) * 128 + dg) << 9) + s) = make_uint2(lo, hi);
        }
      }
    return;
  }
  unsigned short* Yo = (seg == 0) ? Yq : Yk_;
#pragma unroll
  for (int m = 0; m < 4; m++)
#pragma unroll
    for (int nn = 0; nn < 4; nn++)
#pragma unroll
      for (int j = 0; j < 4; j++) {
        int row = rb + wr + m * 16 + g4 + j;
        int col = cb + wc + nn * 16 + l15;
        float v = acc[m][nn][j] + ((col < 512) ? b0[col] : b1[col - 512]);
        Yo[(long)row * 1024 + col] = f2b(v);
      }
}

// ============================ final GEMM (R11 proven) ============================
__global__ __launch_bounds__(256) void gemm_fin_kern(
    const unsigned short* __restrict__ A, const unsigned short* __restrict__ Bw,
    const float* __restrict__ bias0, float* __restrict__ outf) {
  __shared__ unsigned short lsA[128 * 32];
  __shared__ unsigned short lsB[128 * 32];
  const int t = threadIdx.x;
  const int lane = t & 63, w = t >> 6;
  const int l15 = lane & 15, g = lane >> 4, g4 = g * 4;
  const int gs8 = (g ^ ((l15 >> 1) & 3)) * 8;
  int n = blockIdx.x;
  int x = n >> 3, c = n & 7;
  const int rb = (c * 16 + (x & 15)) * 128;
  const int cb = (x >> 4) * 128;
  const int wr = (w >> 1) * 64, wc = (w & 1) * 64;
  const int r0 = t >> 2, r1 = 64 + (t >> 2);
  const int k0i = ((t & 3) ^ ((t >> 3) & 3)) * 8;

  const unsigned short* pa0 = A + (long)(rb + r0) * 1024 + k0i;
  const unsigned short* pa1 = A + (long)(rb + r1) * 1024 + k0i;
  const unsigned short* pb0 = Bw + (long)(cb + r0) * 1024 + k0i;
  const unsigned short* pb1 = Bw + (long)(cb + r1) * 1024 + k0i;
  unsigned short* dA0 = lsA + w * 512;
  unsigned short* dA1 = lsA + 2048 + w * 512;
  unsigned short* dB0 = lsB + w * 512;
  unsigned short* dB1 = lsB + 2048 + w * 512;

  f4 acc[4][4] = {};
  for (int k0 = 0; k0 < 1024; k0 += 32) {
    __syncthreads();
    gload_lds16(pa0 + k0, dA0);
    gload_lds16(pa1 + k0, dA1);
    gload_lds16(pb0 + k0, dB0);
    gload_lds16(pb1 + k0, dB1);
    __syncthreads();
    bh8 af[4], bf[4];
#pragma unroll
    for (int m = 0; m < 4; m++) af[m] = *(const bh8*)(lsA + (wr + m * 16 + l15) * 32 + gs8);
#pragma unroll
    for (int nn = 0; nn < 4; nn++) bf[nn] = *(const bh8*)(lsB + (wc + nn * 16 + l15) * 32 + gs8);
    __builtin_amdgcn_s_setprio(1);
#pragma unroll
    for (int m = 0; m < 4; m++)
#pragma unroll
      for (int nn = 0; nn < 4; nn++)
        acc[m][nn] = mfma16(af[m], bf[nn], acc[m][nn]);
    __builtin_amdgcn_s_setprio(0);
  }
#pragma unroll
  for (int m = 0; m < 4; m++)
#pragma unroll
    for (int nn = 0; nn < 4; nn++)
#pragma unroll
      for (int j = 0; j < 4; j++) {
        int row = rb + wr + m * 16 + g4 + j;
        int col = cb + wc + nn * 16 + l15;
        outf[(long)row * 512 + col] = acc[m][nn][j] + bias0[col];
      }
}

// ============================ merged attention ============================
// 6144 blocks, 2:1 interleave: n%3<2 -> local (id=grp*2+r), n%3==2 -> glob (id=grp).
// Local body = R7-proven v6; glob body = R7-proven v2 (buf stride 524).
__global__ __launch_bounds__(512, 4) void attn_kern(
    const unsigned short* __restrict__ Yq, const unsigned short* __restrict__ Yk,
    const unsigned short* __restrict__ Yvt_l, const unsigned short* __restrict__ Yvt_g,
    const unsigned short* __restrict__ relk, unsigned short* __restrict__ outC) {
  __shared__ unsigned short kv[2][8192];
  __shared__ unsigned short buf[32 * 524];
  __shared__ float redbuf[8][32];

  const int t = threadIdx.x, lane = t & 63, w = t >> 6;
  const int l15 = lane & 15, g = lane >> 4, g8 = g * 8;
  const int n = blockIdx.x;
  const int grp = n / 3, r3 = n - grp * 3;

  if (r3 < 2) {
    // ==================== LOCAL ====================
    int ln = grp * 2 + r3;
    int bid = (ln & 7) * 512 + (ln >> 3);
    const int qt = bid & 15;
    const int h = (bid >> 4) & 7;
    const int b = bid >> 7;
    const int qb = qt * 32;
    const long base = ((long)(b * 512)) * 1024 + h * 64;
    const long vbase = ((long)(b * 8 + h)) * 64 * 512;

#define STAGE_K(ROFF, BUF) { \
    const int c_ = t & 7; \
    _Pragma("unroll") \
    for (int it = 0; it < 2; it++) { \
      int rr = it * 64 + (t >> 3); \
      gload_lds16(Yk + base + (long)((ROFF) + rr) * 1024 + ((c_ ^ (rr & 7)) * 8), \
                  kv[BUF] + it * 4096 + w * 512); \
    } }
#define STAGE_V(COFF, BUF) { \
    const int c_ = t & 15; \
    _Pragma("unroll") \
    for (int it = 0; it < 2; it++) { \
      int dd_ = it * 32 + (t >> 4); \
      gload_lds16(Yvt_l + vbase + (long)dd_ * 512 + (COFF) + ((c_ ^ (dd_ & 15)) * 8), \
                  kv[BUF] + it * 4096 + w * 512); \
    } }
#define QK(CH) { \
    int rl = w * 16 + l15; \
    const unsigned short* kb_ = kv[(CH) & 1]; \
    bh8 k0 = *(const bh8*)(kb_ + rl * 64 + ((g ^ (rl & 7)) * 8)); \
    bh8 k1 = *(const bh8*)(kb_ + rl * 64 + (((g + 4) ^ (rl & 7)) * 8)); \
    _Pragma("unroll") \
    for (int mm = 0; mm < 2; mm++) { \
      f4 a = {}; \
      a = mfma16(qf[mm][0], k0, a); \
      a = mfma16(qf[mm][1], k1, a); \
      sc[mm][CH] = a; \
    } }
#define GATHER(CH) { \
    _Pragma("unroll") \
    for (int mm = 0; mm < 2; mm++) \
    _Pragma("unroll") \
    for (int j = 0; j < 4; j++) { \
      int lr = mm * 16 + g * 4 + j; \
      int rowb = lr * 524; \
      int idx = rowb + 256 - (qb + lr) + (CH) * 128 + w * 16 + l15; \
      idx = idx < rowb ? rowb : idx; \
      idx = idx > rowb + 512 ? rowb + 512 : idx; \
      float p = exp2f(fmaf(sc[mm][CH][j], 0.18033688011112042f, b2f(buf[idx]))); \
      sc[mm][CH][j] = p; \
      rs[mm][j] += p; \
    } }

    STAGE_K(0, 0);

    bh8 qf[2][2];
#pragma unroll
    for (int mm = 0; mm < 2; mm++) {
      const unsigned short* qp = Yq + base + (long)(qb + mm * 16 + l15) * 1024 + g8;
      qf[mm][0] = *(const bh8*)(qp);
      qf[mm][1] = *(const bh8*)(qp + 32);
    }

    for (int tt = w; tt < 33; tt += 8) {
      int ri = tt * 16 + l15; if (ri > 512) ri = 512;
      const unsigned short* rp = relk + ri * 64 + g8;
      bh8 rf0 = *(const bh8*)(rp), rf1 = *(const bh8*)(rp + 32);
      int col = tt * 16 + l15;
#pragma unroll
      for (int mm = 0; mm < 2; mm++) {
        f4 a = {};
        a = mfma16(qf[mm][0], rf0, a);
        a = mfma16(qf[mm][1], rf1, a);
        if (col < 524) {
#pragma unroll
          for (int j = 0; j < 4; j++)
            buf[(mm * 16 + g * 4 + j) * 524 + col] = f2b(a[j] * 1.4426950408889634f);
        }
      }
    }
    __syncthreads();

    f4 sc[2][4];
    float rs[2][4] = {};

#pragma unroll
    for (int c = 0; c < 4; c++) {
      if (c < 3) { STAGE_K((c + 1) * 128, (c + 1) & 1); }
      else       { STAGE_V(0, 0); }
      __builtin_amdgcn_s_setprio(1);
      QK(c);
      __builtin_amdgcn_s_setprio(0);
      GATHER(c);
      __syncthreads();
    }

#pragma unroll
    for (int mm = 0; mm < 2; mm++)
#pragma unroll
      for (int j = 0; j < 4; j++) {
        int lr = mm * 16 + g * 4 + j;
        float s = rs[mm][j];
        for (int d = 1; d < 16; d <<= 1) s += __shfl_xor(s, d, 64);
        if (l15 == 0) redbuf[w][lr] = s;
      }
#pragma unroll
    for (int mm = 0; mm < 2; mm++)
#pragma unroll
      for (int ch = 0; ch < 4; ch++) {
        int col = ch * 128 + w * 16 + l15;
#pragma unroll
        for (int j = 0; j < 4; j++)
          buf[(mm * 16 + g * 4 + j) * 524 + col] = f2b(sc[mm][ch][j]);
      }
    __syncthreads();

    const int mmw = w >> 2, dt = w & 3;
    const int dd = dt * 16 + l15;
    float rinvj[4];
#pragma unroll
    for (int j = 0; j < 4; j++) {
      int lr = mmw * 16 + g * 4 + j;
      float s = 0.f;
#pragma unroll
      for (int ww = 0; ww < 8; ww++) s += redbuf[ww][lr];
      rinvj[j] = __builtin_amdgcn_rcpf(s);
    }

    f4 accO = {};
#pragma unroll
    for (int d = 0; d < 4; d++) {
      if (d < 3) { STAGE_V((d + 1) * 128, (d + 1) & 1); }
      const unsigned short* vb_ = kv[d & 1];
      __builtin_amdgcn_s_setprio(1);
#pragma unroll
      for (int ks2 = 0; ks2 < 4; ks2++) {
        union { uint2 u[2]; bh8 v; } pa;
        const unsigned short* pp = buf + (mmw * 16 + l15) * 524 + (d * 4 + ks2) * 32 + g8;
        pa.u[0] = *(const uint2*)(pp);
        pa.u[1] = *(const uint2*)(pp + 4);
        bh8 vv = *(const bh8*)(vb_ + dd * 128 + (((ks2 * 4 + g) ^ (dd & 15)) * 8));
        accO = mfma16(pa.v, vv, accO);
      }
      __builtin_amdgcn_s_setprio(0);
      if (d < 3) __syncthreads();
    }
#pragma unroll
    for (int j = 0; j < 4; j++) {
      int row = qb + mmw * 16 + g * 4 + j;
      outC[((long)(b * 512 + row)) * 1024 + h * 64 + dt * 16 + l15] = f2b(accO[j] * rinvj[j]);
    }
#undef STAGE_K
#undef STAGE_V
#undef QK
#undef GATHER
  } else {
    // ==================== GLOBAL ====================
    int gn = grp;
    int bid = (gn & 7) * 256 + (gn >> 3);
    const int qt = bid & 15;
    const int hg = (bid >> 4) & 3;
    const int b = bid >> 6;
    const int qb = qt * 32;
    const long base = ((long)(b * 512)) * 1024 + 512 + hg * 128;

    bh8 qf[2][4];
#pragma unroll
    for (int mm = 0; mm < 2; mm++) {
      const unsigned short* qp = Yq + base + (long)(qb + mm * 16 + l15) * 1024 + g8;
#pragma unroll
      for (int ks = 0; ks < 4; ks++) qf[mm][ks] = *(const bh8*)(qp + ks * 32);
    }

    f4 sc[2][4];
    __builtin_amdgcn_s_setprio(1);
#pragma unroll
    for (int ct = 0; ct < 4; ct++) {
      int r = w * 64 + ct * 16 + l15;
      const unsigned short* kp = Yk + base + (long)r * 1024 + g8;
      bh8 kf[4];
#pragma unroll
      for (int ks = 0; ks < 4; ks++) kf[ks] = *(const bh8*)(kp + ks * 32);
#pragma unroll
      for (int mm = 0; mm < 2; mm++) {
        f4 a = {};
#pragma unroll
        for (int ks = 0; ks < 4; ks++) a = mfma16(qf[mm][ks], kf[ks], a);
        sc[mm][ct] = a;
      }
    }
    __builtin_amdgcn_s_setprio(0);

#pragma unroll
    for (int mm = 0; mm < 2; mm++) {
#pragma unroll
      for (int j = 0; j < 4; j++) {
        int lr = mm * 16 + g * 4 + j;
        float s = 0.f;
#pragma unroll
        for (int ct = 0; ct < 4; ct++) {
          float p = exp2f(sc[mm][ct][j] * 0.12751745334f);
          sc[mm][ct][j] = p;
          s += p;
        }
        for (int d = 1; d < 16; d <<= 1) s += __shfl_xor(s, d, 64);
        if (l15 == 0) redbuf[w][lr] = s;
      }
    }
#pragma unroll
    for (int mm = 0; mm < 2; mm++)
#pragma unroll
      for (int ct = 0; ct < 4; ct++) {
        int col = w * 64 + ct * 16 + l15;
#pragma unroll
        for (int j = 0; j < 4; j++)
          buf[(mm * 16 + g * 4 + j) * 524 + col] = f2b(sc[mm][ct][j]);
      }
    __syncthreads();

    float rinv[2][4];
#pragma unroll
    for (int mm = 0; mm < 2; mm++)
#pragma unroll
      for (int j = 0; j < 4; j++) {
        int lr = mm * 16 + g * 4 + j;
        float s = 0.f;
#pragma unroll
        for (int ww = 0; ww < 8; ww++) s += redbuf[ww][lr];
        rinv[mm][j] = __builtin_amdgcn_rcpf(s);
      }

    f4 accO[2] = {};
    const unsigned short* vr = Yvt_g + ((long)(b * 4 + hg) * 128 + w * 16 + l15) * 512;
    __builtin_amdgcn_s_setprio(1);
#pragma unroll
    for (int ks = 0; ks < 16; ks++) {
      bh8 vb = *(const bh8*)(vr + ks * 32 + g8);
#pragma unroll
      for (int mm = 0; mm < 2; mm++) {
        union { uint2 u[2]; bh8 v; } pa;
        const unsigned short* pp = buf + (mm * 16 + l15) * 524 + ks * 32 + g8;
        pa.u[0] = *(const uint2*)(pp);
        pa.u[1] = *(const uint2*)(pp + 4);
        accO[mm] = mfma16(pa.v, vb, accO[mm]);
      }
    }
    __builtin_amdgcn_s_setprio(0);
#pragma unroll
    for (int mm = 0; mm < 2; mm++)
#pragma unroll
      for (int j = 0; j < 4; j++) {
        int row = qb + mm * 16 + g * 4 + j;
        outC[((long)(b * 512 + row)) * 1024 + 512 + hg * 128 + w * 16 + l15] = f2b(accO[mm][j] * rinv[mm][j]);
      }
  }
}

// ============================ launch ============================
extern "C" void kernel_launch(void* const* d_in, const int* in_sizes, int n_in,
                              void* d_out, int out_size, void* d_ws, size_t ws_size,
                              hipStream_t stream) {
  const float* query = (const float*)d_in[0];
  const float* key   = (const float*)d_in[1];
  const float* value = (const float*)d_in[2];
  const float* wq = (const float*)d_in[3];   const float* bq = (const float*)d_in[4];
  const float* wk = (const float*)d_in[5];   const float* bk = (const float*)d_in[6];
  const float* wv = (const float*)d_in[7];   const float* bv = (const float*)d_in[8];
  const float* wo = (const float*)d_in[9];   const float* bo = (const float*)d_in[10];
  const float* rel_k = (const float*)d_in[11];
  const float* g_in_w = (const float*)d_in[12];  const float* g_in_b = (const float*)d_in[13];
  const float* g_out_w = (const float*)d_in[14]; const float* g_out_b = (const float*)d_in[15];

  unsigned short* p = (unsigned short*)d_ws;
  unsigned short* Xq = p;            p += 8388608;   // CAT spans Xq+Xk
  unsigned short* Xk = p;            p += 8388608;
  unsigned short* Xv = p;            p += 8388608;
  unsigned short* Yq = p;            p += 16777216;  // [16384][1024]
  unsigned short* Yk = p;            p += 16777216;
  unsigned short* Yvt_l = p;         p += 8388608;   // [b][h][64][512]
  unsigned short* Yvt_g = p;         p += 8388608;   // [b][hg][128][512]
  unsigned short* Wq = p;            p += 524288;
  unsigned short* Wk = p;            p += 524288;
  unsigned short* Wv = p;            p += 524288;
  unsigned short* Wo_ = p;           p += 262144;
  unsigned short* WgoT = p;          p += 262144;
  unsigned short* Bfin = p;          p += 524288;    // [512][1024]
  unsigned short* Rk = p;            p += 32832;
  float* bias2 = (float*)p;          p += 1024;
  unsigned short* CAT = Xq;                          // [16384][1024]

  prep_all_kern<<<10531, 256, 0, stream>>>(query, key, value,
                                           wq, wk, wv, g_in_w, g_out_w, wo, rel_k,
                                           g_out_b, bo,
                                           Xq, Xk, Xv, Wq, Wk, Wv, Wo_, WgoT, Bfin, Rk, bias2);

  gemm3_kern<<<3088, 256, 0, stream>>>(Xq, Xk, Xv, Wq, Wk, Wv, bq, bk, bv, g_in_b,
                                       Yq, Yk, Yvt_l, Yvt_g, Wo_, WgoT, Bfin);

  attn_kern<<<6144, 512, 0, stream>>>(Yq, Yk, Yvt_l, Yvt_g, Rk, CAT);

  gemm_fin_kern<<<512, 256, 0, stream>>>(CAT, Bfin, bias2, (float*)d_out);
}

// Round 13
// 313.408 us; speedup vs baseline: 1.1522x; 1.0887x over previous
//
#include <hip/hip_runtime.h>

typedef __attribute__((ext_vector_type(8))) short bh8;
typedef __attribute__((ext_vector_type(4))) float f4;

#define DEVI static __device__ __forceinline__

DEVI unsigned short f2b(float f) {
  union { float f; unsigned u; } v; v.f = f;
  unsigned r = v.u + 0x7fffu + ((v.u >> 16) & 1u);
  return (unsigned short)(r >> 16);
}
DEVI float b2f(unsigned short h) {
  union { unsigned u; float f; } v; v.u = ((unsigned)h) << 16;
  return v.f;
}
DEVI f4 mfma16(bh8 a, bh8 b, f4 c) {
  return __builtin_amdgcn_mfma_f32_16x16x32_bf16(a, b, c, 0, 0, 0);
}
DEVI void gload_lds16(const unsigned short* g, unsigned short* l) {
  __builtin_amdgcn_global_load_lds(
      (const __attribute__((address_space(1))) void*)(g),
      (__attribute__((address_space(3))) void*)(l), 16, 0, 0);
}

// ============================ merged prep ============================
__global__ __launch_bounds__(256) void prep_all_kern(
    const float* __restrict__ q, const float* __restrict__ k, const float* __restrict__ v,
    const float* __restrict__ wq, const float* __restrict__ wk, const float* __restrict__ wv,
    const float* __restrict__ g_in_w, const float* __restrict__ g_out_w,
    const float* __restrict__ wo, const float* __restrict__ rel_k,
    const float* __restrict__ bgo, const float* __restrict__ bo,
    unsigned short* __restrict__ xq, unsigned short* __restrict__ xk, unsigned short* __restrict__ xv,
    unsigned short* __restrict__ Wq, unsigned short* __restrict__ Wk, unsigned short* __restrict__ Wv,
    unsigned short* __restrict__ Wo_, unsigned short* __restrict__ WgoT,
    unsigned short* __restrict__ Bfin, unsigned short* __restrict__ Rk,
    float* __restrict__ bias2) {
  if (blockIdx.x < 8192) {
    long i = ((long)blockIdx.x * 256 + threadIdx.x) * 4;
    float4 a = *(const float4*)(q + i);
    float4 b = *(const float4*)(k + i);
    float4 c = *(const float4*)(v + i);
    union { unsigned short s[4]; uint2 u; } pa, pb, pc;
    pa.s[0] = f2b(a.x); pa.s[1] = f2b(a.y); pa.s[2] = f2b(a.z); pa.s[3] = f2b(a.w);
    pb.s[0] = f2b(b.x); pb.s[1] = f2b(b.y); pb.s[2] = f2b(b.z); pb.s[3] = f2b(b.w);
    pc.s[0] = f2b(c.x); pc.s[1] = f2b(c.y); pc.s[2] = f2b(c.z); pc.s[3] = f2b(c.w);
    *(uint2*)(xq + i) = pa.u;
    *(uint2*)(xk + i) = pb.u;
    *(uint2*)(xv + i) = pc.u;
    return;
  }
  int bw = blockIdx.x - 8192;
  if (bw >= 2337) {
    int o = (bw - 2337) * 256 + threadIdx.x;
    if (o < 512) {
      const float* r = wo + (long)o * 512;
      float s = 0.f;
#pragma unroll 4
      for (int m = 0; m < 512; m += 4) {
        float4 a = *(const float4*)(r + m);
        float4 b = *(const float4*)(bgo + m);
        s += a.x * b.x + a.y * b.y + a.z * b.z + a.w * b.w;
      }
      bias2[o] = bo[o] + 0.3f * s;
    }
    return;
  }
  long i = ((long)bw * 256 + threadIdx.x) * 4;
  if (i >= 2392128L) return;
  if (i >= 2097152L && i < 2359296L) {  // WgoT scatter
    long off = i - 2097152L;
    int ii = (int)(off >> 9), p = (int)(off & 511);
    union { unsigned short s[4]; uint2 u; } w;
#pragma unroll
    for (int tt = 0; tt < 4; tt++) w.s[tt] = f2b(g_out_w[(p + tt) * 512 + ii]);
    *(uint2*)(WgoT + off) = w.u;
    return;
  }
  const float* src; unsigned short* dst; long off; float sc = 1.0f;
  if (i < 524288L)        { dst = Wq;  off = i; src = (i < 262144L) ? wq + i : g_in_w + (i - 262144L); }
  else if (i < 1048576L)  { long j = i - 524288L;  dst = Wk;  off = j; src = (j < 262144L) ? wk + j : g_in_w + j; }
  else if (i < 1572864L)  { long j = i - 1048576L; dst = Wv;  off = j; src = (j < 262144L) ? wv + j : g_in_w + 262144L + j; }
  else if (i < 1835008L)  { long j = i - 1572864L; dst = Wo_; off = j; src = wo + j; }
  else if (i < 2097152L)  { long j = i - 1835008L; int col = (int)(j >> 9), kk = (int)(j & 511);
                            dst = Bfin; off = (long)col * 1024 + kk; src = wo + j; sc = 0.7f; }
  else                    { long j = i - 2359296L; dst = Rk;  off = j; src = rel_k + j; }
  float4 f = *(const float4*)src;
  union { unsigned short s[4]; uint2 u; } p;
  p.s[0] = f2b(f.x * sc); p.s[1] = f2b(f.y * sc); p.s[2] = f2b(f.z * sc); p.s[3] = f2b(f.w * sc);
  *(uint2*)(dst + off) = p.u;
}

// ============================ merged projection GEMM (R11 proven) ============================
__global__ __launch_bounds__(256) void gemm3_kern(
    const unsigned short* __restrict__ Xq, const unsigned short* __restrict__ Xk,
    const unsigned short* __restrict__ Xv,
    const unsigned short* __restrict__ Wq, const unsigned short* __restrict__ Wk,
    const unsigned short* __restrict__ Wv,
    const float* __restrict__ bq, const float* __restrict__ bk, const float* __restrict__ bv,
    const float* __restrict__ g_in_b,
    unsigned short* __restrict__ Yq, unsigned short* __restrict__ Yk_,
    unsigned short* __restrict__ Yvt_l, unsigned short* __restrict__ Yvt_g,
    const unsigned short* __restrict__ Wo_, const unsigned short* __restrict__ WgoT,
    unsigned short* __restrict__ Bfin) {
  __shared__ unsigned short lsA[128 * 32];
  __shared__ unsigned short lsB[128 * 32];
  const int t = threadIdx.x;
  const int lane = t & 63, w = t >> 6;
  const int l15 = lane & 15, g = lane >> 4, g4 = g * 4;
  const int gs8 = (g ^ ((l15 >> 1) & 3)) * 8;
  const int n = blockIdx.x;

  const unsigned short *Ap, *Bp;
  const float *b0 = nullptr, *b1 = nullptr;
  int seg, rb, cb;
  if (n < 3072) {
    seg = n >> 10;
    int m = n & 1023;
    int x = m >> 3, c = m & 7;
    rb = (c * 16 + (x & 15)) * 128;
    cb = (x >> 4) * 128;
    Ap = (seg == 0) ? Xq : (seg == 1) ? Xk : Xv;
    Bp = (seg == 0) ? Wq : (seg == 1) ? Wk : Wv;
    b0 = (seg == 0) ? bq : (seg == 1) ? bk : bv;
    b1 = g_in_b + seg * 512;
  } else {
    seg = 3;
    int m2 = n - 3072;
    rb = (m2 & 3) * 128; cb = (m2 >> 2) * 128;
    Ap = Wo_; Bp = WgoT;
  }

  const int wr = (w >> 1) * 64, wc = (w & 1) * 64;
  const int r0 = t >> 2, r1 = 64 + (t >> 2);
  const int k0i = ((t & 3) ^ ((t >> 3) & 3)) * 8;

  const unsigned short* pa0 = Ap + (long)(rb + r0) * 512 + k0i;
  const unsigned short* pa1 = Ap + (long)(rb + r1) * 512 + k0i;
  const unsigned short* pb0 = Bp + (long)(cb + r0) * 512 + k0i;
  const unsigned short* pb1 = Bp + (long)(cb + r1) * 512 + k0i;
  unsigned short* dA0 = lsA + w * 512;
  unsigned short* dA1 = lsA + 2048 + w * 512;
  unsigned short* dB0 = lsB + w * 512;
  unsigned short* dB1 = lsB + 2048 + w * 512;

  f4 acc[4][4] = {};
  for (int k0 = 0; k0 < 512; k0 += 32) {
    __syncthreads();
    gload_lds16(pa0 + k0, dA0);
    gload_lds16(pa1 + k0, dA1);
    gload_lds16(pb0 + k0, dB0);
    gload_lds16(pb1 + k0, dB1);
    __syncthreads();
    bh8 af[4], bf[4];
#pragma unroll
    for (int m = 0; m < 4; m++) af[m] = *(const bh8*)(lsA + (wr + m * 16 + l15) * 32 + gs8);
#pragma unroll
    for (int nn = 0; nn < 4; nn++) bf[nn] = *(const bh8*)(lsB + (wc + nn * 16 + l15) * 32 + gs8);
    __builtin_amdgcn_s_setprio(1);
#pragma unroll
    for (int m = 0; m < 4; m++)
#pragma unroll
      for (int nn = 0; nn < 4; nn++)
        acc[m][nn] = mfma16(af[m], bf[nn], acc[m][nn]);
    __builtin_amdgcn_s_setprio(0);
  }

  if (seg == 3) {
#pragma unroll
    for (int m = 0; m < 4; m++)
#pragma unroll
      for (int nn = 0; nn < 4; nn++)
#pragma unroll
        for (int j = 0; j < 4; j++) {
          int row = rb + wr + m * 16 + g4 + j;
          int col = cb + wc + nn * 16 + l15;
          Bfin[(long)row * 1024 + 512 + col] = f2b(0.3f * acc[m][nn][j]);
        }
    return;
  }
  if (seg == 2) {
#pragma unroll
    for (int m = 0; m < 4; m++)
#pragma unroll
      for (int nn = 0; nn < 4; nn++) {
        int col = cb + wc + nn * 16 + l15;
        float bsv = (col < 512) ? b0[col] : b1[col - 512];
        unsigned r[4];
#pragma unroll
        for (int j = 0; j < 4; j++) {
          union { float f; unsigned u; } v; v.f = acc[m][nn][j] + bsv;
          r[j] = v.u + 0x7fffu + ((v.u >> 16) & 1u);
        }
        unsigned lo = (r[0] >> 16) | (r[1] & 0xffff0000u);
        unsigned hi = (r[2] >> 16) | (r[3] & 0xffff0000u);
        int row0 = rb + wr + m * 16 + g4;
        int bb = row0 >> 9, s = row0 & 511;
        if (col < 512) {
          int hh = col >> 6, d = col & 63;
          *(uint2*)(Yvt_l + (((long)(bb * 8 + hh) * 64 + d) << 9) + s) = make_uint2(lo, hi);
        } else {
          int c2 = col - 512, hg = c2 >> 7, dg = c2 & 127;
          *(uint2*)(Yvt_g + (((long)(bb * 4 + hg) * 128 + dg) << 9) + s) = make_uint2(lo, hi);
        }
      }
    return;
  }
  unsigned short* Yo = (seg == 0) ? Yq : Yk_;
#pragma unroll
  for (int m = 0; m < 4; m++)
#pragma unroll
    for (int nn = 0; nn < 4; nn++)
#pragma unroll
      for (int j = 0; j < 4; j++) {
        int row = rb + wr + m * 16 + g4 + j;
        int col = cb + wc + nn * 16 + l15;
        float v = acc[m][nn][j] + ((col < 512) ? b0[col] : b1[col - 512]);
        Yo[(long)row * 1024 + col] = f2b(v);
      }
}

// ============================ final GEMM (R11 proven) ============================
__global__ __launch_bounds__(256) void gemm_fin_kern(
    const unsigned short* __restrict__ A, const unsigned short* __restrict__ Bw,
    const float* __restrict__ bias0, float* __restrict__ outf) {
  __shared__ unsigned short lsA[128 * 32];
  __shared__ unsigned short lsB[128 * 32];
  const int t = threadIdx.x;
  const int lane = t & 63, w = t >> 6;
  const int l15 = lane & 15, g = lane >> 4, g4 = g * 4;
  const int gs8 = (g ^ ((l15 >> 1) & 3)) * 8;
  int n = blockIdx.x;
  int x = n >> 3, c = n & 7;
  const int rb = (c * 16 + (x & 15)) * 128;
  const int cb = (x >> 4) * 128;
  const int wr = (w >> 1) * 64, wc = (w & 1) * 64;
  const int r0 = t >> 2, r1 = 64 + (t >> 2);
  const int k0i = ((t & 3) ^ ((t >> 3) & 3)) * 8;

  const unsigned short* pa0 = A + (long)(rb + r0) * 1024 + k0i;
  const unsigned short* pa1 = A + (long)(rb + r1) * 1024 + k0i;
  const unsigned short* pb0 = Bw + (long)(cb + r0) * 1024 + k0i;
  const unsigned short* pb1 = Bw + (long)(cb + r1) * 1024 + k0i;
  unsigned short* dA0 = lsA + w * 512;
  unsigned short* dA1 = lsA + 2048 + w * 512;
  unsigned short* dB0 = lsB + w * 512;
  unsigned short* dB1 = lsB + 2048 + w * 512;

  f4 acc[4][4] = {};
  for (int k0 = 0; k0 < 1024; k0 += 32) {
    __syncthreads();
    gload_lds16(pa0 + k0, dA0);
    gload_lds16(pa1 + k0, dA1);
    gload_lds16(pb0 + k0, dB0);
    gload_lds16(pb1 + k0, dB1);
    __syncthreads();
    bh8 af[4], bf[4];
#pragma unroll
    for (int m = 0; m < 4; m++) af[m] = *(const bh8*)(lsA + (wr + m * 16 + l15) * 32 + gs8);
#pragma unroll
    for (int nn = 0; nn < 4; nn++) bf[nn] = *(const bh8*)(lsB + (wc + nn * 16 + l15) * 32 + gs8);
    __builtin_amdgcn_s_setprio(1);
#pragma unroll
    for (int m = 0; m < 4; m++)
#pragma unroll
      for (int nn = 0; nn < 4; nn++)
        acc[m][nn] = mfma16(af[m], bf[nn], acc[m][nn]);
    __builtin_amdgcn_s_setprio(0);
  }
#pragma unroll
  for (int m = 0; m < 4; m++)
#pragma unroll
    for (int nn = 0; nn < 4; nn++)
#pragma unroll
      for (int j = 0; j < 4; j++) {
        int row = rb + wr + m * 16 + g4 + j;
        int col = cb + wc + nn * 16 + l15;
        outf[(long)row * 512 + col] = acc[m][nn][j] + bias0[col];
      }
}

// ============================ local attention v6 (R7 proven, standalone) ============================
__global__ __launch_bounds__(512, 4) void attn_local_kern(
    const unsigned short* __restrict__ Yq, const unsigned short* __restrict__ Yk,
    const unsigned short* __restrict__ Yvt, const unsigned short* __restrict__ relk,
    unsigned short* __restrict__ outC) {
  __shared__ unsigned short kv[2][8192];
  __shared__ unsigned short buf[32 * 524];
  __shared__ float redbuf[8][32];

  const int t = threadIdx.x, lane = t & 63, w = t >> 6;
  const int l15 = lane & 15, g = lane >> 4, g8 = g * 8;
  int n = blockIdx.x;
  int bid = (n & 7) * 512 + (n >> 3);
  const int qt = bid & 15;
  const int h = (bid >> 4) & 7;
  const int b = bid >> 7;
  const int qb = qt * 32;
  const long base = ((long)(b * 512)) * 1024 + h * 64;
  const long vbase = ((long)(b * 8 + h)) * 64 * 512;

#define STAGE_K(ROFF, BUF) { \
    const int c_ = t & 7; \
    _Pragma("unroll") \
    for (int it = 0; it < 2; it++) { \
      int rr = it * 64 + (t >> 3); \
      gload_lds16(Yk + base + (long)((ROFF) + rr) * 1024 + ((c_ ^ (rr & 7)) * 8), \
                  kv[BUF] + it * 4096 + w * 512); \
    } }
#define STAGE_V(COFF, BUF) { \
    const int c_ = t & 15; \
    _Pragma("unroll") \
    for (int it = 0; it < 2; it++) { \
      int dd_ = it * 32 + (t >> 4); \
      gload_lds16(Yvt + vbase + (long)dd_ * 512 + (COFF) + ((c_ ^ (dd_ & 15)) * 8), \
                  kv[BUF] + it * 4096 + w * 512); \
    } }
#define QK(CH) { \
    int rl = w * 16 + l15; \
    const unsigned short* kb_ = kv[(CH) & 1]; \
    bh8 k0 = *(const bh8*)(kb_ + rl * 64 + ((g ^ (rl & 7)) * 8)); \
    bh8 k1 = *(const bh8*)(kb_ + rl * 64 + (((g + 4) ^ (rl & 7)) * 8)); \
    _Pragma("unroll") \
    for (int mm = 0; mm < 2; mm++) { \
      f4 a = {}; \
      a = mfma16(qf[mm][0], k0, a); \
      a = mfma16(qf[mm][1], k1, a); \
      sc[mm][CH] = a; \
    } }
#define GATHER(CH) { \
    _Pragma("unroll") \
    for (int mm = 0; mm < 2; mm++) \
    _Pragma("unroll") \
    for (int j = 0; j < 4; j++) { \
      int lr = mm * 16 + g * 4 + j; \
      int rowb = lr * 524; \
      int idx = rowb + 256 - (qb + lr) + (CH) * 128 + w * 16 + l15; \
      idx = idx < rowb ? rowb : idx; \
      idx = idx > rowb + 512 ? rowb + 512 : idx; \
      float p = exp2f(fmaf(sc[mm][CH][j], 0.18033688011112042f, b2f(buf[idx]))); \
      sc[mm][CH][j] = p; \
      rs[mm][j] += p; \
    } }

  STAGE_K(0, 0);

  bh8 qf[2][2];
#pragma unroll
  for (int mm = 0; mm < 2; mm++) {
    const unsigned short* qp = Yq + base + (long)(qb + mm * 16 + l15) * 1024 + g8;
    qf[mm][0] = *(const bh8*)(qp);
    qf[mm][1] = *(const bh8*)(qp + 32);
  }

  for (int tt = w; tt < 33; tt += 8) {
    int ri = tt * 16 + l15; if (ri > 512) ri = 512;
    const unsigned short* rp = relk + ri * 64 + g8;
    bh8 rf0 = *(const bh8*)(rp), rf1 = *(const bh8*)(rp + 32);
    int col = tt * 16 + l15;
#pragma unroll
    for (int mm = 0; mm < 2; mm++) {
      f4 a = {};
      a = mfma16(qf[mm][0], rf0, a);
      a = mfma16(qf[mm][1], rf1, a);
      if (col < 524) {
#pragma unroll
        for (int j = 0; j < 4; j++)
          buf[(mm * 16 + g * 4 + j) * 524 + col] = f2b(a[j] * 1.4426950408889634f);
      }
    }
  }
  __syncthreads();

  f4 sc[2][4];
  float rs[2][4] = {};

#pragma unroll
  for (int c = 0; c < 4; c++) {
    if (c < 3) { STAGE_K((c + 1) * 128, (c + 1) & 1); }
    else       { STAGE_V(0, 0); }
    __builtin_amdgcn_s_setprio(1);
    QK(c);
    __builtin_amdgcn_s_setprio(0);
    GATHER(c);
    __syncthreads();
  }

#pragma unroll
  for (int mm = 0; mm < 2; mm++)
#pragma unroll
    for (int j = 0; j < 4; j++) {
      int lr = mm * 16 + g * 4 + j;
      float s = rs[mm][j];
      for (int d = 1; d < 16; d <<= 1) s += __shfl_xor(s, d, 64);
      if (l15 == 0) redbuf[w][lr] = s;
    }
#pragma unroll
  for (int mm = 0; mm < 2; mm++)
#pragma unroll
    for (int ch = 0; ch < 4; ch++) {
      int col = ch * 128 + w * 16 + l15;
#pragma unroll
      for (int j = 0; j < 4; j++)
        buf[(mm * 16 + g * 4 + j) * 524 + col] = f2b(sc[mm][ch][j]);
    }
  __syncthreads();

  const int mmw = w >> 2, dt = w & 3;
  const int dd = dt * 16 + l15;
  float rinvj[4];
#pragma unroll
  for (int j = 0; j < 4; j++) {
    int lr = mmw * 16 + g * 4 + j;
    float s = 0.f;
#pragma unroll
    for (int ww = 0; ww < 8; ww++) s += redbuf[ww][lr];
    rinvj[j] = __builtin_amdgcn_rcpf(s);
  }

  f4 accO = {};
#pragma unroll
  for (int d = 0; d < 4; d++) {
    if (d < 3) { STAGE_V((d + 1) * 128, (d + 1) & 1); }
    const unsigned short* vb_ = kv[d & 1];
    __builtin_amdgcn_s_setprio(1);
#pragma unroll
    for (int ks2 = 0; ks2 < 4; ks2++) {
      union { uint2 u[2]; bh8 v; } pa;
      const unsigned short* pp = buf + (mmw * 16 + l15) * 524 + (d * 4 + ks2) * 32 + g8;
      pa.u[0] = *(const uint2*)(pp);
      pa.u[1] = *(const uint2*)(pp + 4);
      bh8 vv = *(const bh8*)(vb_ + dd * 128 + (((ks2 * 4 + g) ^ (dd & 15)) * 8));
      accO = mfma16(pa.v, vv, accO);
    }
    __builtin_amdgcn_s_setprio(0);
    if (d < 3) __syncthreads();
  }
#pragma unroll
  for (int j = 0; j < 4; j++) {
    int row = qb + mmw * 16 + g * 4 + j;
    outC[((long)(b * 512 + row)) * 1024 + h * 64 + dt * 16 + l15] = f2b(accO[j] * rinvj[j]);
  }
#undef STAGE_K
#undef STAGE_V
#undef QK
#undef GATHER
}

// ============================ global attention v3 (LDS-staged) ============================
// K [512][128] in 8 chunks [64][128] (16KB); V [128][512] in 8 chunks [128][64].
// Double-buffered kv, stage-next under MFMA-current. Ascending-k accumulation
// (bitwise-identical to v2). Wave roles: QK: rows (w&3)*16+l15, mm=w>>2;
// PV: d-col w*16+l15, both mm.
__global__ __launch_bounds__(512, 4) void attn_glob_kern(
    const unsigned short* __restrict__ Yq, const unsigned short* __restrict__ Yk,
    const unsigned short* __restrict__ Yvt, unsigned short* __restrict__ outC) {
  __shared__ unsigned short kv[2][8192];
  __shared__ unsigned short buf[32 * 520];
  __shared__ float redbuf[8][32];

  const int t = threadIdx.x, lane = t & 63, w = t >> 6;
  const int l15 = lane & 15, g = lane >> 4, g8 = g * 8;
  int n = blockIdx.x;
  int bid = (n & 7) * 256 + (n >> 3);
  const int qt = bid & 15;
  const int hg = (bid >> 4) & 3;
  const int b = bid >> 6;
  const int qb = qt * 32;
  const long base = ((long)(b * 512)) * 1024 + 512 + hg * 128;
  const long vgbase = ((long)(b * 4 + hg)) * 128 * 512;

  // K chunk [64 rows][128 d]: slot s=it*512+t -> r=it*32+(t>>4), c=t&15;
  // slot c holds global d-chunk c^(r&15).
#define STAGE_GK(KC, BUF) { \
    const int c_ = t & 15; \
    _Pragma("unroll") \
    for (int it = 0; it < 2; it++) { \
      int rr = it * 32 + (t >> 4); \
      gload_lds16(Yk + base + (long)((KC) * 64 + rr) * 1024 + ((c_ ^ (rr & 15)) * 8), \
                  kv[BUF] + it * 4096 + w * 512); \
    } }
  // V chunk [128 d][64 k]: slot s -> d=it*64+(t>>3), c=t&7; holds k-chunk c^(d&7).
#define STAGE_GV(KC, BUF) { \
    const int c_ = t & 7; \
    _Pragma("unroll") \
    for (int it = 0; it < 2; it++) { \
      int dd_ = it * 64 + (t >> 3); \
      gload_lds16(Yvt + vgbase + (long)dd_ * 512 + (KC) * 64 + ((c_ ^ (dd_ & 7)) * 8), \
                  kv[BUF] + it * 4096 + w * 512); \
    } }

  const int mmq = w >> 2, wq4 = w & 3;

  STAGE_GK(0, 0);

  bh8 qf[4];
  {
    const unsigned short* qp = Yq + base + (long)(qb + mmq * 16 + l15) * 1024 + g8;
#pragma unroll
    for (int ks = 0; ks < 4; ks++) qf[ks] = *(const bh8*)(qp + ks * 32);
  }
  __syncthreads();  // K0 staged

  f4 sc8[8];
#pragma unroll
  for (int kc = 0; kc < 8; kc++) {
    if (kc < 7) { STAGE_GK(kc + 1, (kc + 1) & 1); }
    else        { STAGE_GV(0, 0); }
    const unsigned short* kb_ = kv[kc & 1];
    const int rl = wq4 * 16 + l15;
    __builtin_amdgcn_s_setprio(1);
    f4 a = {};
#pragma unroll
    for (int ks = 0; ks < 4; ks++) {
      bh8 kf = *(const bh8*)(kb_ + rl * 128 + (((ks * 4 + g) ^ (rl & 15)) * 8));
      a = mfma16(qf[ks], kf, a);
    }
    sc8[kc] = a;
    __builtin_amdgcn_s_setprio(0);
    __syncthreads();
  }

  // softmax partials: row lr = mmq*16+g*4+j; cols wq4*16+l15 within each chunk
#pragma unroll
  for (int j = 0; j < 4; j++) {
    int lr = mmq * 16 + g * 4 + j;
    float s = 0.f;
#pragma unroll
    for (int kc = 0; kc < 8; kc++) {
      float p = exp2f(sc8[kc][j] * 0.12751745334f);  // 1/sqrt(128)*log2(e)
      sc8[kc][j] = p;
      s += p;
    }
    for (int d = 1; d < 16; d <<= 1) s += __shfl_xor(s, d, 64);
    if (l15 == 0) redbuf[w][lr] = s;
  }
  __syncthreads();  // redbuf ready (kv[0]=V0 already staged & drained)

  // probs -> buf; rinv for both mm
#pragma unroll
  for (int kc = 0; kc < 8; kc++) {
    int col = kc * 64 + wq4 * 16 + l15;
#pragma unroll
    for (int j = 0; j < 4; j++)
      buf[(mmq * 16 + g * 4 + j) * 520 + col] = f2b(sc8[kc][j]);
  }
  float rinv[2][4];
#pragma unroll
  for (int mm = 0; mm < 2; mm++)
#pragma unroll
    for (int j = 0; j < 4; j++) {
      int lr = mm * 16 + g * 4 + j;
      float s = redbuf[mm * 4 + 0][lr] + redbuf[mm * 4 + 1][lr] +
                redbuf[mm * 4 + 2][lr] + redbuf[mm * 4 + 3][lr];
      rinv[mm][j] = __builtin_amdgcn_rcpf(s);
    }
  __syncthreads();  // probs visible

  // PV: wave w owns d-col dd = w*16+l15, both mm
  const int dd = w * 16 + l15;
  f4 accO[2] = {};
#pragma unroll
  for (int kc = 0; kc < 8; kc++) {
    if (kc < 7) { STAGE_GV(kc + 1, (kc + 1) & 1); }
    const unsigned short* vb_ = kv[kc & 1];
    __builtin_amdgcn_s_setprio(1);
#pragma unroll
    for (int ks2 = 0; ks2 < 2; ks2++) {
      bh8 vv = *(const bh8*)(vb_ + dd * 64 + (((ks2 * 4 + g) ^ (dd & 7)) * 8));
#pragma unroll
      for (int mm = 0; mm < 2; mm++) {
        union { uint2 u[2]; bh8 v; } pa;
        const unsigned short* pp = buf + (mm * 16 + l15) * 520 + kc * 64 + ks2 * 32 + g8;
        pa.u[0] = *(const uint2*)(pp);
        pa.u[1] = *(const uint2*)(pp + 4);
        accO[mm] = mfma16(pa.v, vv, accO[mm]);
      }
    }
    __builtin_amdgcn_s_setprio(0);
    if (kc < 7) __syncthreads();
  }
#pragma unroll
  for (int mm = 0; mm < 2; mm++)
#pragma unroll
    for (int j = 0; j < 4; j++) {
      int row = qb + mm * 16 + g * 4 + j;
      outC[((long)(b * 512 + row)) * 1024 + 512 + hg * 128 + w * 16 + l15] = f2b(accO[mm][j] * rinv[mm][j]);
    }
#undef STAGE_GK
#undef STAGE_GV
}

// ============================ launch ============================
extern "C" void kernel_launch(void* const* d_in, const int* in_sizes, int n_in,
                              void* d_out, int out_size, void* d_ws, size_t ws_size,
                              hipStream_t stream) {
  const float* query = (const float*)d_in[0];
  const float* key   = (const float*)d_in[1];
  const float* value = (const float*)d_in[2];
  const float* wq = (const float*)d_in[3];   const float* bq = (const float*)d_in[4];
  const float* wk = (const float*)d_in[5];   const float* bk = (const float*)d_in[6];
  const float* wv = (const float*)d_in[7];   const float* bv = (const float*)d_in[8];
  const float* wo = (const float*)d_in[9];   const float* bo = (const float*)d_in[10];
  const float* rel_k = (const float*)d_in[11];
  const float* g_in_w = (const float*)d_in[12];  const float* g_in_b = (const float*)d_in[13];
  const float* g_out_w = (const float*)d_in[14]; const float* g_out_b = (const float*)d_in[15];

  unsigned short* p = (unsigned short*)d_ws;
  unsigned short* Xq = p;            p += 8388608;   // CAT spans Xq+Xk
  unsigned short* Xk = p;            p += 8388608;
  unsigned short* Xv = p;            p += 8388608;
  unsigned short* Yq = p;            p += 16777216;  // [16384][1024]
  unsigned short* Yk = p;            p += 16777216;
  unsigned short* Yvt_l = p;         p += 8388608;   // [b][h][64][512]
  unsigned short* Yvt_g = p;         p += 8388608;   // [b][hg][128][512]
  unsigned short* Wq = p;            p += 524288;
  unsigned short* Wk = p;            p += 524288;
  unsigned short* Wv = p;            p += 524288;
  unsigned short* Wo_ = p;           p += 262144;
  unsigned short* WgoT = p;          p += 262144;
  unsigned short* Bfin = p;          p += 524288;    // [512][1024]
  unsigned short* Rk = p;            p += 32832;
  float* bias2 = (float*)p;          p += 1024;
  unsigned short* CAT = Xq;                          // [16384][1024]

  prep_all_kern<<<10531, 256, 0, stream>>>(query, key, value,
                                           wq, wk, wv, g_in_w, g_out_w, wo, rel_k,
                                           g_out_b, bo,
                                           Xq, Xk, Xv, Wq, Wk, Wv, Wo_, WgoT, Bfin, Rk, bias2);

  gemm3_kern<<<3088, 256, 0, stream>>>(Xq, Xk, Xv, Wq, Wk, Wv, bq, bk, bv, g_in_b,
                                       Yq, Yk, Yvt_l, Yvt_g, Wo_, WgoT, Bfin);

  attn_local_kern<<<4096, 512, 0, stream>>>(Yq, Yk, Yvt_l, Rk, CAT);
  attn_glob_kern<<<2048, 512, 0, stream>>>(Yq, Yk, Yvt_g, CAT);

  gemm_fin_kern<<<512, 256, 0, stream>>>(CAT, Bfin, bias2, (float*)d_out);
}

// Round 14
// 299.428 us; speedup vs baseline: 1.2060x; 1.0467x over previous
//
#include <hip/hip_runtime.h>

typedef __attribute__((ext_vector_type(8))) short bh8;
typedef __attribute__((ext_vector_type(4))) float f4;

#define DEVI static __device__ __forceinline__

DEVI unsigned short f2b(float f) {
  union { float f; unsigned u; } v; v.f = f;
  unsigned r = v.u + 0x7fffu + ((v.u >> 16) & 1u);
  return (unsigned short)(r >> 16);
}
DEVI float b2f(unsigned short h) {
  union { unsigned u; float f; } v; v.u = ((unsigned)h) << 16;
  return v.f;
}
DEVI f4 mfma16(bh8 a, bh8 b, f4 c) {
  return __builtin_amdgcn_mfma_f32_16x16x32_bf16(a, b, c, 0, 0, 0);
}
DEVI void gload_lds16(const unsigned short* g, unsigned short* l) {
  __builtin_amdgcn_global_load_lds(
      (const __attribute__((address_space(1))) void*)(g),
      (__attribute__((address_space(3))) void*)(l), 16, 0, 0);
}

// ============================ merged prep ============================
__global__ __launch_bounds__(256) void prep_all_kern(
    const float* __restrict__ q, const float* __restrict__ k, const float* __restrict__ v,
    const float* __restrict__ wq, const float* __restrict__ wk, const float* __restrict__ wv,
    const float* __restrict__ g_in_w, const float* __restrict__ g_out_w,
    const float* __restrict__ wo, const float* __restrict__ rel_k,
    const float* __restrict__ bgo, const float* __restrict__ bo,
    unsigned short* __restrict__ xq, unsigned short* __restrict__ xk, unsigned short* __restrict__ xv,
    unsigned short* __restrict__ Wq, unsigned short* __restrict__ Wk, unsigned short* __restrict__ Wv,
    unsigned short* __restrict__ Wo_, unsigned short* __restrict__ WgoT,
    unsigned short* __restrict__ Bfin, unsigned short* __restrict__ Rk,
    float* __restrict__ bias2) {
  if (blockIdx.x < 8192) {
    long i = ((long)blockIdx.x * 256 + threadIdx.x) * 4;
    float4 a = *(const float4*)(q + i);
    float4 b = *(const float4*)(k + i);
    float4 c = *(const float4*)(v + i);
    union { unsigned short s[4]; uint2 u; } pa, pb, pc;
    pa.s[0] = f2b(a.x); pa.s[1] = f2b(a.y); pa.s[2] = f2b(a.z); pa.s[3] = f2b(a.w);
    pb.s[0] = f2b(b.x); pb.s[1] = f2b(b.y); pb.s[2] = f2b(b.z); pb.s[3] = f2b(b.w);
    pc.s[0] = f2b(c.x); pc.s[1] = f2b(c.y); pc.s[2] = f2b(c.z); pc.s[3] = f2b(c.w);
    *(uint2*)(xq + i) = pa.u;
    *(uint2*)(xk + i) = pb.u;
    *(uint2*)(xv + i) = pc.u;
    return;
  }
  int bw = blockIdx.x - 8192;
  if (bw >= 2337) {
    int o = (bw - 2337) * 256 + threadIdx.x;
    if (o < 512) {
      const float* r = wo + (long)o * 512;
      float s = 0.f;
#pragma unroll 4
      for (int m = 0; m < 512; m += 4) {
        float4 a = *(const float4*)(r + m);
        float4 b = *(const float4*)(bgo + m);
        s += a.x * b.x + a.y * b.y + a.z * b.z + a.w * b.w;
      }
      bias2[o] = bo[o] + 0.3f * s;
    }
    return;
  }
  long i = ((long)bw * 256 + threadIdx.x) * 4;
  if (i >= 2392128L) return;
  if (i >= 2097152L && i < 2359296L) {  // WgoT scatter
    long off = i - 2097152L;
    int ii = (int)(off >> 9), p = (int)(off & 511);
    union { unsigned short s[4]; uint2 u; } w;
#pragma unroll
    for (int tt = 0; tt < 4; tt++) w.s[tt] = f2b(g_out_w[(p + tt) * 512 + ii]);
    *(uint2*)(WgoT + off) = w.u;
    return;
  }
  const float* src; unsigned short* dst; long off; float sc = 1.0f;
  if (i < 524288L)        { dst = Wq;  off = i; src = (i < 262144L) ? wq + i : g_in_w + (i - 262144L); }
  else if (i < 1048576L)  { long j = i - 524288L;  dst = Wk;  off = j; src = (j < 262144L) ? wk + j : g_in_w + j; }
  else if (i < 1572864L)  { long j = i - 1048576L; dst = Wv;  off = j; src = (j < 262144L) ? wv + j : g_in_w + 262144L + j; }
  else if (i < 1835008L)  { long j = i - 1572864L; dst = Wo_; off = j; src = wo + j; }
  else if (i < 2097152L)  { long j = i - 1835008L; int col = (int)(j >> 9), kk = (int)(j & 511);
                            dst = Bfin; off = (long)col * 1024 + kk; src = wo + j; sc = 0.7f; }
  else                    { long j = i - 2359296L; dst = Rk;  off = j; src = rel_k + j; }
  float4 f = *(const float4*)src;
  union { unsigned short s[4]; uint2 u; } p;
  p.s[0] = f2b(f.x * sc); p.s[1] = f2b(f.y * sc); p.s[2] = f2b(f.z * sc); p.s[3] = f2b(f.w * sc);
  *(uint2*)(dst + off) = p.u;
}

// ============================ merged projection GEMM (BK=64) ============================
// Blocks [0,1024) Q, [1024,2048) K, [2048,3072) V, [3072,3088) W2.
// BK=64: 8 k-iters (half the barriers of BK=32). LDS 32KB. 3-bit chunk-XOR
// swizzle both sides: slot chunk c of row r holds global chunk c^(r&7);
// read chunk (kh*4+g)^(r&7). Per-acc k-order ascending -> bitwise-identical.
__global__ __launch_bounds__(256) void gemm3_kern(
    const unsigned short* __restrict__ Xq, const unsigned short* __restrict__ Xk,
    const unsigned short* __restrict__ Xv,
    const unsigned short* __restrict__ Wq, const unsigned short* __restrict__ Wk,
    const unsigned short* __restrict__ Wv,
    const float* __restrict__ bq, const float* __restrict__ bk, const float* __restrict__ bv,
    const float* __restrict__ g_in_b,
    unsigned short* __restrict__ Yq, unsigned short* __restrict__ Yk_,
    unsigned short* __restrict__ Yvt_l, unsigned short* __restrict__ Yvt_g,
    const unsigned short* __restrict__ Wo_, const unsigned short* __restrict__ WgoT,
    unsigned short* __restrict__ Bfin) {
  __shared__ unsigned short lsA[128 * 64];
  __shared__ unsigned short lsB[128 * 64];
  const int t = threadIdx.x;
  const int lane = t & 63, w = t >> 6;
  const int l15 = lane & 15, g = lane >> 4, g4 = g * 4;
  const int n = blockIdx.x;

  const unsigned short *Ap, *Bp;
  const float *b0 = nullptr, *b1 = nullptr;
  int seg, rb, cb;
  if (n < 3072) {
    seg = n >> 10;
    int m = n & 1023;
    int x = m >> 3, c = m & 7;
    rb = (c * 16 + (x & 15)) * 128;
    cb = (x >> 4) * 128;
    Ap = (seg == 0) ? Xq : (seg == 1) ? Xk : Xv;
    Bp = (seg == 0) ? Wq : (seg == 1) ? Wk : Wv;
    b0 = (seg == 0) ? bq : (seg == 1) ? bk : bv;
    b1 = g_in_b + seg * 512;
  } else {
    seg = 3;
    int m2 = n - 3072;
    rb = (m2 & 3) * 128; cb = (m2 >> 2) * 128;
    Ap = Wo_; Bp = WgoT;
  }

  const int wr = (w >> 1) * 64, wc = (w & 1) * 64;
  // staging: pass p: thread t -> row (t>>3)+p*32, chunk t&7; key (t>>3)&7
  // (pass-invariant since p*32 % 8 == 0).
  const int tr = t >> 3;
  const int kci = ((t & 7) ^ (tr & 7)) * 8;
  const unsigned short* pa = Ap + (long)(rb + tr) * 512 + kci;
  const unsigned short* pb = Bp + (long)(cb + tr) * 512 + kci;

  f4 acc[4][4] = {};
  for (int k0 = 0; k0 < 512; k0 += 64) {
    __syncthreads();
#pragma unroll
    for (int p = 0; p < 4; p++) {
      gload_lds16(pa + k0 + (long)p * 32 * 512, lsA + p * 2048 + w * 512);
      gload_lds16(pb + k0 + (long)p * 32 * 512, lsB + p * 2048 + w * 512);
    }
    __syncthreads();
    bh8 af[2][4], bf[2][4];
#pragma unroll
    for (int kh = 0; kh < 2; kh++) {
#pragma unroll
      for (int m = 0; m < 4; m++) {
        int rl = wr + m * 16 + l15;
        af[kh][m] = *(const bh8*)(lsA + rl * 64 + (((kh * 4 + g) ^ (rl & 7)) * 8));
      }
#pragma unroll
      for (int nn = 0; nn < 4; nn++) {
        int rl = wc + nn * 16 + l15;
        bf[kh][nn] = *(const bh8*)(lsB + rl * 64 + (((kh * 4 + g) ^ (rl & 7)) * 8));
      }
    }
    __builtin_amdgcn_s_setprio(1);
#pragma unroll
    for (int m = 0; m < 4; m++)
#pragma unroll
      for (int nn = 0; nn < 4; nn++) {
        acc[m][nn] = mfma16(af[0][m], bf[0][nn], acc[m][nn]);
        acc[m][nn] = mfma16(af[1][m], bf[1][nn], acc[m][nn]);
      }
    __builtin_amdgcn_s_setprio(0);
  }

  if (seg == 3) {
#pragma unroll
    for (int m = 0; m < 4; m++)
#pragma unroll
      for (int nn = 0; nn < 4; nn++)
#pragma unroll
        for (int j = 0; j < 4; j++) {
          int row = rb + wr + m * 16 + g4 + j;
          int col = cb + wc + nn * 16 + l15;
          Bfin[(long)row * 1024 + 512 + col] = f2b(0.3f * acc[m][nn][j]);
        }
    return;
  }
  if (seg == 2) {
#pragma unroll
    for (int m = 0; m < 4; m++)
#pragma unroll
      for (int nn = 0; nn < 4; nn++) {
        int col = cb + wc + nn * 16 + l15;
        float bsv = (col < 512) ? b0[col] : b1[col - 512];
        unsigned r[4];
#pragma unroll
        for (int j = 0; j < 4; j++) {
          union { float f; unsigned u; } v; v.f = acc[m][nn][j] + bsv;
          r[j] = v.u + 0x7fffu + ((v.u >> 16) & 1u);
        }
        unsigned lo = (r[0] >> 16) | (r[1] & 0xffff0000u);
        unsigned hi = (r[2] >> 16) | (r[3] & 0xffff0000u);
        int row0 = rb + wr + m * 16 + g4;
        int bb = row0 >> 9, s = row0 & 511;
        if (col < 512) {
          int hh = col >> 6, d = col & 63;
          *(uint2*)(Yvt_l + (((long)(bb * 8 + hh) * 64 + d) << 9) + s) = make_uint2(lo, hi);
        } else {
          int c2 = col - 512, hg = c2 >> 7, dg = c2 & 127;
          *(uint2*)(Yvt_g + (((long)(bb * 4 + hg) * 128 + dg) << 9) + s) = make_uint2(lo, hi);
        }
      }
    return;
  }
  unsigned short* Yo = (seg == 0) ? Yq : Yk_;
#pragma unroll
  for (int m = 0; m < 4; m++)
#pragma unroll
    for (int nn = 0; nn < 4; nn++)
#pragma unroll
      for (int j = 0; j < 4; j++) {
        int row = rb + wr + m * 16 + g4 + j;
        int col = cb + wc + nn * 16 + l15;
        float v = acc[m][nn][j] + ((col < 512) ? b0[col] : b1[col - 512]);
        Yo[(long)row * 1024 + col] = f2b(v);
      }
}

// ============================ final GEMM (BK=64) ============================
// out = CAT[16384][1024] @ Bfin[512][1024]^T + bias2 -> f32. 16 k-iters.
__global__ __launch_bounds__(256) void gemm_fin_kern(
    const unsigned short* __restrict__ A, const unsigned short* __restrict__ Bw,
    const float* __restrict__ bias0, float* __restrict__ outf) {
  __shared__ unsigned short lsA[128 * 64];
  __shared__ unsigned short lsB[128 * 64];
  const int t = threadIdx.x;
  const int lane = t & 63, w = t >> 6;
  const int l15 = lane & 15, g = lane >> 4, g4 = g * 4;
  int n = blockIdx.x;
  int x = n >> 3, c = n & 7;
  const int rb = (c * 16 + (x & 15)) * 128;
  const int cb = (x >> 4) * 128;
  const int wr = (w >> 1) * 64, wc = (w & 1) * 64;
  const int tr = t >> 3;
  const int kci = ((t & 7) ^ (tr & 7)) * 8;

  const unsigned short* pa = A + (long)(rb + tr) * 1024 + kci;
  const unsigned short* pb = Bw + (long)(cb + tr) * 1024 + kci;

  f4 acc[4][4] = {};
  for (int k0 = 0; k0 < 1024; k0 += 64) {
    __syncthreads();
#pragma unroll
    for (int p = 0; p < 4; p++) {
      gload_lds16(pa + k0 + (long)p * 32 * 1024, lsA + p * 2048 + w * 512);
      gload_lds16(pb + k0 + (long)p * 32 * 1024, lsB + p * 2048 + w * 512);
    }
    __syncthreads();
    bh8 af[2][4], bf[2][4];
#pragma unroll
    for (int kh = 0; kh < 2; kh++) {
#pragma unroll
      for (int m = 0; m < 4; m++) {
        int rl = wr + m * 16 + l15;
        af[kh][m] = *(const bh8*)(lsA + rl * 64 + (((kh * 4 + g) ^ (rl & 7)) * 8));
      }
#pragma unroll
      for (int nn = 0; nn < 4; nn++) {
        int rl = wc + nn * 16 + l15;
        bf[kh][nn] = *(const bh8*)(lsB + rl * 64 + (((kh * 4 + g) ^ (rl & 7)) * 8));
      }
    }
    __builtin_amdgcn_s_setprio(1);
#pragma unroll
    for (int m = 0; m < 4; m++)
#pragma unroll
      for (int nn = 0; nn < 4; nn++) {
        acc[m][nn] = mfma16(af[0][m], bf[0][nn], acc[m][nn]);
        acc[m][nn] = mfma16(af[1][m], bf[1][nn], acc[m][nn]);
      }
    __builtin_amdgcn_s_setprio(0);
  }
#pragma unroll
  for (int m = 0; m < 4; m++)
#pragma unroll
    for (int nn = 0; nn < 4; nn++)
#pragma unroll
      for (int j = 0; j < 4; j++) {
        int row = rb + wr + m * 16 + g4 + j;
        int col = cb + wc + nn * 16 + l15;
        outf[(long)row * 512 + col] = acc[m][nn][j] + bias0[col];
      }
}

// ============================ local attention v6 (R7 proven) ============================
__global__ __launch_bounds__(512, 4) void attn_local_kern(
    const unsigned short* __restrict__ Yq, const unsigned short* __restrict__ Yk,
    const unsigned short* __restrict__ Yvt, const unsigned short* __restrict__ relk,
    unsigned short* __restrict__ outC) {
  __shared__ unsigned short kv[2][8192];
  __shared__ unsigned short buf[32 * 524];
  __shared__ float redbuf[8][32];

  const int t = threadIdx.x, lane = t & 63, w = t >> 6;
  const int l15 = lane & 15, g = lane >> 4, g8 = g * 8;
  int n = blockIdx.x;
  int bid = (n & 7) * 512 + (n >> 3);
  const int qt = bid & 15;
  const int h = (bid >> 4) & 7;
  const int b = bid >> 7;
  const int qb = qt * 32;
  const long base = ((long)(b * 512)) * 1024 + h * 64;
  const long vbase = ((long)(b * 8 + h)) * 64 * 512;

#define STAGE_K(ROFF, BUF) { \
    const int c_ = t & 7; \
    _Pragma("unroll") \
    for (int it = 0; it < 2; it++) { \
      int rr = it * 64 + (t >> 3); \
      gload_lds16(Yk + base + (long)((ROFF) + rr) * 1024 + ((c_ ^ (rr & 7)) * 8), \
                  kv[BUF] + it * 4096 + w * 512); \
    } }
#define STAGE_V(COFF, BUF) { \
    const int c_ = t & 15; \
    _Pragma("unroll") \
    for (int it = 0; it < 2; it++) { \
      int dd_ = it * 32 + (t >> 4); \
      gload_lds16(Yvt + vbase + (long)dd_ * 512 + (COFF) + ((c_ ^ (dd_ & 15)) * 8), \
                  kv[BUF] + it * 4096 + w * 512); \
    } }
#define QK(CH) { \
    int rl = w * 16 + l15; \
    const unsigned short* kb_ = kv[(CH) & 1]; \
    bh8 k0 = *(const bh8*)(kb_ + rl * 64 + ((g ^ (rl & 7)) * 8)); \
    bh8 k1 = *(const bh8*)(kb_ + rl * 64 + (((g + 4) ^ (rl & 7)) * 8)); \
    _Pragma("unroll") \
    for (int mm = 0; mm < 2; mm++) { \
      f4 a = {}; \
      a = mfma16(qf[mm][0], k0, a); \
      a = mfma16(qf[mm][1], k1, a); \
      sc[mm][CH] = a; \
    } }
#define GATHER(CH) { \
    _Pragma("unroll") \
    for (int mm = 0; mm < 2; mm++) \
    _Pragma("unroll") \
    for (int j = 0; j < 4; j++) { \
      int lr = mm * 16 + g * 4 + j; \
      int rowb = lr * 524; \
      int idx = rowb + 256 - (qb + lr) + (CH) * 128 + w * 16 + l15; \
      idx = idx < rowb ? rowb : idx; \
      idx = idx > rowb + 512 ? rowb + 512 : idx; \
      float p = exp2f(fmaf(sc[mm][CH][j], 0.18033688011112042f, b2f(buf[idx]))); \
      sc[mm][CH][j] = p; \
      rs[mm][j] += p; \
    } }

  STAGE_K(0, 0);

  bh8 qf[2][2];
#pragma unroll
  for (int mm = 0; mm < 2; mm++) {
    const unsigned short* qp = Yq + base + (long)(qb + mm * 16 + l15) * 1024 + g8;
    qf[mm][0] = *(const bh8*)(qp);
    qf[mm][1] = *(const bh8*)(qp + 32);
  }

  for (int tt = w; tt < 33; tt += 8) {
    int ri = tt * 16 + l15; if (ri > 512) ri = 512;
    const unsigned short* rp = relk + ri * 64 + g8;
    bh8 rf0 = *(const bh8*)(rp), rf1 = *(const bh8*)(rp + 32);
    int col = tt * 16 + l15;
#pragma unroll
    for (int mm = 0; mm < 2; mm++) {
      f4 a = {};
      a = mfma16(qf[mm][0], rf0, a);
      a = mfma16(qf[mm][1], rf1, a);
      if (col < 524) {
#pragma unroll
        for (int j = 0; j < 4; j++)
          buf[(mm * 16 + g * 4 + j) * 524 + col] = f2b(a[j] * 1.4426950408889634f);
      }
    }
  }
  __syncthreads();

  f4 sc[2][4];
  float rs[2][4] = {};

#pragma unroll
  for (int c = 0; c < 4; c++) {
    if (c < 3) { STAGE_K((c + 1) * 128, (c + 1) & 1); }
    else       { STAGE_V(0, 0); }
    __builtin_amdgcn_s_setprio(1);
    QK(c);
    __builtin_amdgcn_s_setprio(0);
    GATHER(c);
    __syncthreads();
  }

#pragma unroll
  for (int mm = 0; mm < 2; mm++)
#pragma unroll
    for (int j = 0; j < 4; j++) {
      int lr = mm * 16 + g * 4 + j;
      float s = rs[mm][j];
      for (int d = 1; d < 16; d <<= 1) s += __shfl_xor(s, d, 64);
      if (l15 == 0) redbuf[w][lr] = s;
    }
#pragma unroll
  for (int mm = 0; mm < 2; mm++)
#pragma unroll
    for (int ch = 0; ch < 4; ch++) {
      int col = ch * 128 + w * 16 + l15;
#pragma unroll
      for (int j = 0; j < 4; j++)
        buf[(mm * 16 + g * 4 + j) * 524 + col] = f2b(sc[mm][ch][j]);
    }
  __syncthreads();

  const int mmw = w >> 2, dt = w & 3;
  const int dd = dt * 16 + l15;
  float rinvj[4];
#pragma unroll
  for (int j = 0; j < 4; j++) {
    int lr = mmw * 16 + g * 4 + j;
    float s = 0.f;
#pragma unroll
    for (int ww = 0; ww < 8; ww++) s += redbuf[ww][lr];
    rinvj[j] = __builtin_amdgcn_rcpf(s);
  }

  f4 accO = {};
#pragma unroll
  for (int d = 0; d < 4; d++) {
    if (d < 3) { STAGE_V((d + 1) * 128, (d + 1) & 1); }
    const unsigned short* vb_ = kv[d & 1];
    __builtin_amdgcn_s_setprio(1);
#pragma unroll
    for (int ks2 = 0; ks2 < 4; ks2++) {
      union { uint2 u[2]; bh8 v; } pa;
      const unsigned short* pp = buf + (mmw * 16 + l15) * 524 + (d * 4 + ks2) * 32 + g8;
      pa.u[0] = *(const uint2*)(pp);
      pa.u[1] = *(const uint2*)(pp + 4);
      bh8 vv = *(const bh8*)(vb_ + dd * 128 + (((ks2 * 4 + g) ^ (dd & 15)) * 8));
      accO = mfma16(pa.v, vv, accO);
    }
    __builtin_amdgcn_s_setprio(0);
    if (d < 3) __syncthreads();
  }
#pragma unroll
  for (int j = 0; j < 4; j++) {
    int row = qb + mmw * 16 + g * 4 + j;
    outC[((long)(b * 512 + row)) * 1024 + h * 64 + dt * 16 + l15] = f2b(accO[j] * rinvj[j]);
  }
#undef STAGE_K
#undef STAGE_V
#undef QK
#undef GATHER
}

// ============================ global attention v3 (R13 proven) ============================
__global__ __launch_bounds__(512, 4) void attn_glob_kern(
    const unsigned short* __restrict__ Yq, const unsigned short* __restrict__ Yk,
    const unsigned short* __restrict__ Yvt, unsigned short* __restrict__ outC) {
  __shared__ unsigned short kv[2][8192];
  __shared__ unsigned short buf[32 * 520];
  __shared__ float redbuf[8][32];

  const int t = threadIdx.x, lane = t & 63, w = t >> 6;
  const int l15 = lane & 15, g = lane >> 4, g8 = g * 8;
  int n = blockIdx.x;
  int bid = (n & 7) * 256 + (n >> 3);
  const int qt = bid & 15;
  const int hg = (bid >> 4) & 3;
  const int b = bid >> 6;
  const int qb = qt * 32;
  const long base = ((long)(b * 512)) * 1024 + 512 + hg * 128;
  const long vgbase = ((long)(b * 4 + hg)) * 128 * 512;

#define STAGE_GK(KC, BUF) { \
    const int c_ = t & 15; \
    _Pragma("unroll") \
    for (int it = 0; it < 2; it++) { \
      int rr = it * 32 + (t >> 4); \
      gload_lds16(Yk + base + (long)((KC) * 64 + rr) * 1024 + ((c_ ^ (rr & 15)) * 8), \
                  kv[BUF] + it * 4096 + w * 512); \
    } }
#define STAGE_GV(KC, BUF) { \
    const int c_ = t & 7; \
    _Pragma("unroll") \
    for (int it = 0; it < 2; it++) { \
      int dd_ = it * 64 + (t >> 3); \
      gload_lds16(Yvt + vgbase + (long)dd_ * 512 + (KC) * 64 + ((c_ ^ (dd_ & 7)) * 8), \
                  kv[BUF] + it * 4096 + w * 512); \
    } }

  const int mmq = w >> 2, wq4 = w & 3;

  STAGE_GK(0, 0);

  bh8 qf[4];
  {
    const unsigned short* qp = Yq + base + (long)(qb + mmq * 16 + l15) * 1024 + g8;
#pragma unroll
    for (int ks = 0; ks < 4; ks++) qf[ks] = *(const bh8*)(qp + ks * 32);
  }
  __syncthreads();  // K0 staged

  f4 sc8[8];
#pragma unroll
  for (int kc = 0; kc < 8; kc++) {
    if (kc < 7) { STAGE_GK(kc + 1, (kc + 1) & 1); }
    else        { STAGE_GV(0, 0); }
    const unsigned short* kb_ = kv[kc & 1];
    const int rl = wq4 * 16 + l15;
    __builtin_amdgcn_s_setprio(1);
    f4 a = {};
#pragma unroll
    for (int ks = 0; ks < 4; ks++) {
      bh8 kf = *(const bh8*)(kb_ + rl * 128 + (((ks * 4 + g) ^ (rl & 15)) * 8));
      a = mfma16(qf[ks], kf, a);
    }
    sc8[kc] = a;
    __builtin_amdgcn_s_setprio(0);
    __syncthreads();
  }

#pragma unroll
  for (int j = 0; j < 4; j++) {
    int lr = mmq * 16 + g * 4 + j;
    float s = 0.f;
#pragma unroll
    for (int kc = 0; kc < 8; kc++) {
      float p = exp2f(sc8[kc][j] * 0.12751745334f);  // 1/sqrt(128)*log2(e)
      sc8[kc][j] = p;
      s += p;
    }
    for (int d = 1; d < 16; d <<= 1) s += __shfl_xor(s, d, 64);
    if (l15 == 0) redbuf[w][lr] = s;
  }
  __syncthreads();

#pragma unroll
  for (int kc = 0; kc < 8; kc++) {
    int col = kc * 64 + wq4 * 16 + l15;
#pragma unroll
    for (int j = 0; j < 4; j++)
      buf[(mmq * 16 + g * 4 + j) * 520 + col] = f2b(sc8[kc][j]);
  }
  float rinv[2][4];
#pragma unroll
  for (int mm = 0; mm < 2; mm++)
#pragma unroll
    for (int j = 0; j < 4; j++) {
      int lr = mm * 16 + g * 4 + j;
      float s = redbuf[mm * 4 + 0][lr] + redbuf[mm * 4 + 1][lr] +
                redbuf[mm * 4 + 2][lr] + redbuf[mm * 4 + 3][lr];
      rinv[mm][j] = __builtin_amdgcn_rcpf(s);
    }
  __syncthreads();

  const int dd = w * 16 + l15;
  f4 accO[2] = {};
#pragma unroll
  for (int kc = 0; kc < 8; kc++) {
    if (kc < 7) { STAGE_GV(kc + 1, (kc + 1) & 1); }
    const unsigned short* vb_ = kv[kc & 1];
    __builtin_amdgcn_s_setprio(1);
#pragma unroll
    for (int ks2 = 0; ks2 < 2; ks2++) {
      bh8 vv = *(const bh8*)(vb_ + dd * 64 + (((ks2 * 4 + g) ^ (dd & 7)) * 8));
#pragma unroll
      for (int mm = 0; mm < 2; mm++) {
        union { uint2 u[2]; bh8 v; } pa;
        const unsigned short* pp = buf + (mm * 16 + l15) * 520 + kc * 64 + ks2 * 32 + g8;
        pa.u[0] = *(const uint2*)(pp);
        pa.u[1] = *(const uint2*)(pp + 4);
        accO[mm] = mfma16(pa.v, vv, accO[mm]);
      }
    }
    __builtin_amdgcn_s_setprio(0);
    if (kc < 7) __syncthreads();
  }
#pragma unroll
  for (int mm = 0; mm < 2; mm++)
#pragma unroll
    for (int j = 0; j < 4; j++) {
      int row = qb + mm * 16 + g * 4 + j;
      outC[((long)(b * 512 + row)) * 1024 + 512 + hg * 128 + w * 16 + l15] = f2b(accO[mm][j] * rinv[mm][j]);
    }
#undef STAGE_GK
#undef STAGE_GV
}

// ============================ launch ============================
extern "C" void kernel_launch(void* const* d_in, const int* in_sizes, int n_in,
                              void* d_out, int out_size, void* d_ws, size_t ws_size,
                              hipStream_t stream) {
  const float* query = (const float*)d_in[0];
  const float* key   = (const float*)d_in[1];
  const float* value = (const float*)d_in[2];
  const float* wq = (const float*)d_in[3];   const float* bq = (const float*)d_in[4];
  const float* wk = (const float*)d_in[5];   const float* bk = (const float*)d_in[6];
  const float* wv = (const float*)d_in[7];   const float* bv = (const float*)d_in[8];
  const float* wo = (const float*)d_in[9];   const float* bo = (const float*)d_in[10];
  const float* rel_k = (const float*)d_in[11];
  const float* g_in_w = (const float*)d_in[12];  const float* g_in_b = (const float*)d_in[13];
  const float* g_out_w = (const float*)d_in[14]; const float* g_out_b = (const float*)d_in[15];

  unsigned short* p = (unsigned short*)d_ws;
  unsigned short* Xq = p;            p += 8388608;   // CAT spans Xq+Xk
  unsigned short* Xk = p;            p += 8388608;
  unsigned short* Xv = p;            p += 8388608;
  unsigned short* Yq = p;            p += 16777216;  // [16384][1024]
  unsigned short* Yk = p;            p += 16777216;
  unsigned short* Yvt_l = p;         p += 8388608;   // [b][h][64][512]
  unsigned short* Yvt_g = p;         p += 8388608;   // [b][hg][128][512]
  unsigned short* Wq = p;            p += 524288;
  unsigned short* Wk = p;            p += 524288;
  unsigned short* Wv = p;            p += 524288;
  unsigned short* Wo_ = p;           p += 262144;
  unsigned short* WgoT = p;          p += 262144;
  unsigned short* Bfin = p;          p += 524288;    // [512][1024]
  unsigned short* Rk = p;            p += 32832;
  float* bias2 = (float*)p;          p += 1024;
  unsigned short* CAT = Xq;                          // [16384][1024]

  prep_all_kern<<<10531, 256, 0, stream>>>(query, key, value,
                                           wq, wk, wv, g_in_w, g_out_w, wo, rel_k,
                                           g_out_b, bo,
                                           Xq, Xk, Xv, Wq, Wk, Wv, Wo_, WgoT, Bfin, Rk, bias2);

  gemm3_kern<<<3088, 256, 0, stream>>>(Xq, Xk, Xv, Wq, Wk, Wv, bq, bk, bv, g_in_b,
                                       Yq, Yk, Yvt_l, Yvt_g, Wo_, WgoT, Bfin);

  attn_local_kern<<<4096, 512, 0, stream>>>(Yq, Yk, Yvt_l, Rk, CAT);
  attn_glob_kern<<<2048, 512, 0, stream>>>(Yq, Yk, Yvt_g, CAT);

  gemm_fin_kern<<<512, 256, 0, stream>>>(CAT, Bfin, bias2, (float*)d_out);
}